// Round 11
// baseline (410.998 us; speedup 1.0000x reference)
//
#include <hip/hip_runtime.h>
#include <hip/hip_bf16.h>

#define NN 100000
#define NE 1600000
#define D 128
#define NGRP 8
#define GSZ (NN / NGRP)          // 12500, exact
#define EPT 8                    // edges per thread in hist8/part2
#define NBLK ((NE + 2047) / 2048)   // 782 blocks for hist8/part2
#define NWAVES (NBLK * 4)        // 3128 waves
#define NSUB 32                  // sub-blocks per group in nhist/scatter2
#define WSTRIDE 136              // LDS row stride (u16): 272B -> conflict-free b128

typedef unsigned short u16;
typedef unsigned int u32;
typedef unsigned long long u64;
typedef __attribute__((ext_vector_type(8))) short bf16x8;
typedef __attribute__((ext_vector_type(4))) float f32x4;
typedef __attribute__((ext_vector_type(8))) u16 u16x8;

__device__ inline u16 f2b(float f) {
  union { float f; u32 u; } v; v.f = f;
  u32 u = v.u;
  return (u16)((u + 0x7fffu + ((u >> 16) & 1u)) >> 16);
}
__device__ inline float b2f(u16 h) {
  union { u32 u; float f; } v; v.u = ((u32)h) << 16; return v.f;
}

// ---------------- per-wave 8-bucket histogram + x->bf16 convert -------------
__global__ __launch_bounds__(256) void k_hist8(const int* __restrict__ dst,
    int* __restrict__ hw, const float* __restrict__ xin, u16* __restrict__ xb) {
  const int t = threadIdx.x, lane = t & 63, wid = t >> 6;
  const int eb = blockIdx.x * (256 * EPT);
  const int wv = blockIdx.x * 4 + wid;
  int c0=0,c1=0,c2=0,c3=0,c4=0,c5=0,c6=0,c7=0;
  #pragma unroll
  for (int r = 0; r < EPT; ++r) {
    int e = eb + r * 256 + t;
    bool v = e < NE;
    int q = v ? __builtin_nontemporal_load(&dst[e]) / GSZ : 8;
    c0 += __popcll(__ballot(q == 0)); c1 += __popcll(__ballot(q == 1));
    c2 += __popcll(__ballot(q == 2)); c3 += __popcll(__ballot(q == 3));
    c4 += __popcll(__ballot(q == 4)); c5 += __popcll(__ballot(q == 5));
    c6 += __popcll(__ballot(q == 6)); c7 += __popcll(__ballot(q == 7));
    if (v) {
      const f32x4* p = reinterpret_cast<const f32x4*>(xin) + (size_t)e * 2;
      f32x4 a = __builtin_nontemporal_load(p);
      f32x4 b = __builtin_nontemporal_load(p + 1);
      u16x8 o;
      o[0] = f2b(a[0]); o[1] = f2b(a[1]); o[2] = f2b(a[2]); o[3] = f2b(a[3]);
      o[4] = f2b(b[0]); o[5] = f2b(b[1]); o[6] = f2b(b[2]); o[7] = f2b(b[3]);
      __builtin_nontemporal_store(o, reinterpret_cast<u16x8*>(xb + (size_t)e * 8));
    }
  }
  if (lane == 0) {
    hw[0 * NWAVES + wv] = c0; hw[1 * NWAVES + wv] = c1;
    hw[2 * NWAVES + wv] = c2; hw[3 * NWAVES + wv] = c3;
    hw[4 * NWAVES + wv] = c4; hw[5 * NWAVES + wv] = c5;
    hw[6 * NWAVES + wv] = c6; hw[7 * NWAVES + wv] = c7;
  }
}

// ---------------- single-block exclusive scan (in place) --------------------
__global__ void k_hscan(int* __restrict__ a, int n) {
  __shared__ int s[256];
  int t = threadIdx.x;
  int per = (n + 255) / 256;
  int lo = t * per, hi = lo + per; if (hi > n) hi = n;
  int sum = 0;
  for (int i = lo; i < hi; ++i) sum += a[i];
  s[t] = sum; __syncthreads();
  for (int off = 1; off < 256; off <<= 1) {
    int u = (t >= off) ? s[t - off] : 0;
    __syncthreads(); s[t] += u; __syncthreads();
  }
  int run = s[t] - sum;
  for (int i = lo; i < hi; ++i) { int v = a[i]; a[i] = run; run += v; }
}

// ---------------- deterministic bucket write (ballot ranks, no atomics) -----
// entry packed u32: (d_local << 17) | src   (14 + 17 bits)
__global__ __launch_bounds__(256) void k_part2(const int* __restrict__ src,
    const int* __restrict__ dst, const int* __restrict__ hw,
    u32* __restrict__ bkt) {
  const int t = threadIdx.x, lane = t & 63, wid = t >> 6;
  const int eb = blockIdx.x * (256 * EPT);
  const int wv = blockIdx.x * 4 + wid;
  int q[EPT]; u32 pk[EPT];
  #pragma unroll
  for (int r = 0; r < EPT; ++r) {
    int e = eb + r * 256 + t;
    bool v = e < NE;
    int d = v ? __builtin_nontemporal_load(&dst[e]) : 0;
    int s = v ? __builtin_nontemporal_load(&src[e]) : 0;
    q[r] = v ? d / GSZ : 8;
    pk[r] = v ? (((u32)(d - q[r] * GSZ) << 17) | (u32)s) : 0;
  }
  u64 below = (lane == 63) ? 0x7fffffffffffffffull : ((1ull << lane) - 1);
  int base[NGRP];
  #pragma unroll
  for (int b = 0; b < NGRP; ++b) base[b] = hw[b * NWAVES + wv];
  #pragma unroll
  for (int b = 0; b < NGRP; ++b) {
    int run = 0;
    #pragma unroll
    for (int r = 0; r < EPT; ++r) {
      u64 m = __ballot(q[r] == b);
      if (q[r] == b) {
        int pos = base[b] + run + __popcll(m & below);
        if (pos < NE)
          bkt[pos] = pk[r];
      }
      run += __popcll(m);
    }
  }
}

// ---------------- per-sub-block node histogram in LDS -----------------------
__global__ __launch_bounds__(256) void k_nhist(const u32* __restrict__ bkt,
    const int* __restrict__ hw, u16* __restrict__ ncnt) {
  __shared__ int h[GSZ];
  const int g = blockIdx.x & (NGRP - 1);
  const int sub = blockIdx.x >> 3;
  const int t = threadIdx.x;
  const int start = hw[g * NWAVES];
  const int end = (g < NGRP - 1) ? hw[(g + 1) * NWAVES] : NE;
  const int cnt = end - start;
  const int chunk = (cnt + NSUB - 1) / NSUB;
  int lo = start + sub * chunk;
  int hi = lo + chunk; if (hi > end) hi = end;
  for (int i = t; i < GSZ; i += 256) h[i] = 0;
  __syncthreads();
  for (int i = lo + t; i < hi; i += 256) {
    int dl = (int)(__builtin_nontemporal_load(&bkt[i]) >> 17);
    atomicAdd(&h[dl], 1);
  }
  __syncthreads();
  u16* outp = ncnt + ((size_t)g * NSUB + sub) * GSZ;
  for (int i = t; i < GSZ; i += 256) outp[i] = (u16)h[i];
}

// ---------------- per-node scan over sub-blocks -> offsets + deg ------------
__global__ __launch_bounds__(256) void k_nscan(u16* __restrict__ ncnt,
    int* __restrict__ deg) {
  const int g = blockIdx.x & (NGRP - 1);
  const int seg = blockIdx.x >> 3;
  int d = seg * 256 + threadIdx.x;
  if (d >= GSZ) return;
  int run = 0;
  #pragma unroll
  for (int s = 0; s < NSUB; ++s) {
    size_t idx = ((size_t)g * NSUB + s) * GSZ + d;
    int v = ncnt[idx];
    ncnt[idx] = (u16)run;
    run += v;
  }
  deg[g * GSZ + d] = run;
}

__global__ void k_scan1(const int* __restrict__ deg, int* __restrict__ incl,
                        int* __restrict__ bsum) {
  __shared__ int s[256];
  int t = threadIdx.x;
  int i = blockIdx.x * 256 + t;
  int v = (i < NN) ? deg[i] : 0;
  s[t] = v; __syncthreads();
  for (int off = 1; off < 256; off <<= 1) {
    int u = (t >= off) ? s[t - off] : 0;
    __syncthreads();
    s[t] += u; __syncthreads();
  }
  if (i < NN) incl[i] = s[t];
  if (t == 255) bsum[blockIdx.x] = s[255];
}

__global__ void k_scan2(int* __restrict__ bsum, int nb) {
  __shared__ int s[512];
  int t = threadIdx.x;
  int v = (t < nb) ? bsum[t] : 0;
  s[t] = v; __syncthreads();
  for (int off = 1; off < 512; off <<= 1) {
    int u = (t >= off) ? s[t - off] : 0;
    __syncthreads();
    s[t] += u; __syncthreads();
  }
  if (t < nb) bsum[t] = s[t] - v;  // exclusive block offsets
}

__global__ void k_scan3(const int* __restrict__ incl, const int* __restrict__ deg,
                        const int* __restrict__ bsum, int* __restrict__ rowstart) {
  int i = blockIdx.x * 256 + threadIdx.x;
  if (i < NN) {
    int ex = incl[i] - deg[i] + bsum[blockIdx.x];
    rowstart[i] = ex;
    if (i == NN - 1) rowstart[NN] = ex + deg[i];
  }
}

// ---------------- scatter: LDS cursors, XCD-resident col slice --------------
__global__ __launch_bounds__(256) void k_scatter2(const u32* __restrict__ bkt,
    const int* __restrict__ hw, const u16* __restrict__ ncnt,
    const int* __restrict__ rowstart, int* __restrict__ col) {
  __shared__ int cur[GSZ];
  const int g = blockIdx.x & (NGRP - 1);
  const int sub = blockIdx.x >> 3;
  const int t = threadIdx.x;
  const int start = hw[g * NWAVES];
  const int end = (g < NGRP - 1) ? hw[(g + 1) * NWAVES] : NE;
  const int cnt = end - start;
  const int chunk = (cnt + NSUB - 1) / NSUB;
  int lo = start + sub * chunk;
  int hi = lo + chunk; if (hi > end) hi = end;
  const u16* nof = ncnt + ((size_t)g * NSUB + sub) * GSZ;
  for (int i = t; i < GSZ; i += 256)
    cur[i] = rowstart[g * GSZ + i] + (int)nof[i];
  __syncthreads();
  for (int i = lo + t; i < hi; i += 256) {
    u32 v = __builtin_nontemporal_load(&bkt[i]);
    int dl = (int)(v >> 17), s = (int)(v & 0x1ffffu);
    int pos = atomicAdd(&cur[dl], 1);
    col[pos] = s;
  }
}

// ---------------- W (k-major [k][n]) -> Wt (n-major [n][k]) bf16, 4 mats ----
__global__ void k_cvt_wt4(const float* __restrict__ W0, const float* __restrict__ W1,
                          const float* __restrict__ W2, const float* __restrict__ W3,
                          u16* __restrict__ T0, u16* __restrict__ T1,
                          u16* __restrict__ T2, u16* __restrict__ T3) {
  const float* W = blockIdx.y == 0 ? W0 : blockIdx.y == 1 ? W1 : blockIdx.y == 2 ? W2 : W3;
  u16* T = blockIdx.y == 0 ? T0 : blockIdx.y == 1 ? T1 : blockIdx.y == 2 ? T2 : T3;
  int n = blockIdx.x, k = threadIdx.x;
  T[n * D + k] = f2b(W[k * D + n]);
}

// ---------------- feature-sliced mean aggregation ---------------------------
// slice = bid & 3 -> 32 features (64B = 1 line per row-slice). With round-robin
// block->XCD dispatch, XCD g only sees slice g&3: gather working set/XCD drops
// 25.6MB -> 6.4MB (R10 counters: 177MB fetch == 8 XCDs x distinct rows).
// Wave = 16 nodes (quad per node, lane&3 = 16B feature chunk); serial edges,
// 2-deep unroll -> 32 rows in flight/wave; NO shuffles (lane owns its feats).
__global__ __launch_bounds__(256) void k_agg_s(const u16* __restrict__ feat,
    const int* __restrict__ rowstart, const int* __restrict__ col,
    u16* __restrict__ out) {
  int wid = threadIdx.x >> 6, lane = threadIdx.x & 63;
  int slice = blockIdx.x & 3;
  int node = (blockIdx.x >> 2) * 64 + wid * 16 + (lane >> 2);
  if (node >= NN) return;
  int b = rowstart[node], e = rowstart[node + 1];
  const u16* fp = feat + slice * 32 + (lane & 3) * 8;
  float a[8] = {};
  int j = b;
  for (; j + 1 < e; j += 2) {
    int s0 = col[j], s1 = col[j + 1];
    u16x8 v0 = *reinterpret_cast<const u16x8*>(fp + (size_t)s0 * D);
    u16x8 v1 = *reinterpret_cast<const u16x8*>(fp + (size_t)s1 * D);
    #pragma unroll
    for (int t = 0; t < 8; ++t) a[t] += b2f(v0[t]) + b2f(v1[t]);
  }
  if (j < e) {
    int s0 = col[j];
    u16x8 v0 = *reinterpret_cast<const u16x8*>(fp + (size_t)s0 * D);
    #pragma unroll
    for (int t = 0; t < 8; ++t) a[t] += b2f(v0[t]);
  }
  float inv = (e > b) ? 1.f / (float)(e - b) : 0.f;
  u16x8 o;
  #pragma unroll
  for (int t = 0; t < 8; ++t) o[t] = f2b(a[t] * inv);
  *reinterpret_cast<u16x8*>(&out[(size_t)node * D + slice * 32 + (lane & 3) * 8]) = o;
}

// ---------------- fused dual GEMM via MFMA, weights staged in LDS -----------
__global__ __launch_bounds__(256) void k_gemm_mfma(
    const u16* __restrict__ A, const u16* __restrict__ B,
    const u16* __restrict__ Wt1, const u16* __restrict__ Wt2,
    const float* __restrict__ bias, u16* __restrict__ Cout)
{
  __shared__ u16 wlds[128 * WSTRIDE];
  const int t = threadIdx.x;
  const int wid = t >> 6, lane = t & 63;
  const int l15 = lane & 15, g = lane >> 4;
  const int rbase = blockIdx.x * 128 + wid * 32;

  int r0 = rbase + l15, r1 = r0 + 16;
  size_t a0 = (size_t)(r0 < NN ? r0 : NN - 1) * D + g * 8;
  size_t a1 = (size_t)(r1 < NN ? r1 : NN - 1) * D + g * 8;

  f32x4 acc0[8] = {}, acc1[8] = {};

  #pragma unroll
  for (int phase = 0; phase < 2; ++phase) {
    const u16* Act = phase ? B : A;
    const u16* Wt  = phase ? Wt2 : Wt1;
    #pragma unroll
    for (int q = 0; q < 8; ++q) {
      int i = q * 256 + t;           // 16B chunk id, 2048 total
      int n = i >> 4, kc = i & 15;
      *reinterpret_cast<u16x8*>(&wlds[n * WSTRIDE + kc * 8]) =
          *reinterpret_cast<const u16x8*>(&Wt[n * D + kc * 8]);
    }
    __syncthreads();
    #pragma unroll
    for (int kb = 0; kb < 4; ++kb) {
      bf16x8 af0 = *reinterpret_cast<const bf16x8*>(&Act[a0 + kb * 32]);
      bf16x8 af1 = *reinterpret_cast<const bf16x8*>(&Act[a1 + kb * 32]);
      #pragma unroll
      for (int c = 0; c < 8; ++c) {
        bf16x8 wf = *reinterpret_cast<const bf16x8*>(
            &wlds[(c * 16 + l15) * WSTRIDE + kb * 32 + g * 8]);
        acc0[c] = __builtin_amdgcn_mfma_f32_16x16x32_bf16(af0, wf, acc0[c], 0, 0, 0);
        acc1[c] = __builtin_amdgcn_mfma_f32_16x16x32_bf16(af1, wf, acc1[c], 0, 0, 0);
      }
    }
    __syncthreads();   // all waves done reading before restage
  }

  #pragma unroll
  for (int c = 0; c < 8; ++c) {
    float bv = bias[c * 16 + l15];
    #pragma unroll
    for (int r = 0; r < 4; ++r) {
      int row0 = rbase + g * 4 + r;
      if (row0 < NN) {
        float v = fmaxf(acc0[c][r] + bv, 0.f);
        Cout[(size_t)row0 * D + c * 16 + l15] = f2b(v);
      }
      int row1 = row0 + 16;
      if (row1 < NN) {
        float v = fmaxf(acc1[c][r] + bv, 0.f);
        Cout[(size_t)row1 * D + c * 16 + l15] = f2b(v);
      }
    }
  }
}

// ---------------- layer-2 GEMM (LDS weights) + fused layer-3 projection -----
__global__ __launch_bounds__(256) void k_gemm2_zr(
    const u16* __restrict__ A, const u16* __restrict__ B,
    const u16* __restrict__ Wt1, const u16* __restrict__ Wt2,
    const float* __restrict__ bias,
    const float* __restrict__ Wl3, const float* __restrict__ Wr3,
    const float* __restrict__ b3,
    float* __restrict__ z, float* __restrict__ r)
{
  __shared__ u16 wlds[128 * WSTRIDE];
  const int t = threadIdx.x;
  const int wid = t >> 6, lane = t & 63;
  const int l15 = lane & 15, g = lane >> 4;
  const int rbase = blockIdx.x * 128 + wid * 32;

  int r0 = rbase + l15, r1 = r0 + 16;
  size_t a0 = (size_t)(r0 < NN ? r0 : NN - 1) * D + g * 8;
  size_t a1 = (size_t)(r1 < NN ? r1 : NN - 1) * D + g * 8;

  f32x4 acc0[8] = {}, acc1[8] = {};

  #pragma unroll
  for (int phase = 0; phase < 2; ++phase) {
    const u16* Act = phase ? B : A;
    const u16* Wt  = phase ? Wt2 : Wt1;
    #pragma unroll
    for (int q = 0; q < 8; ++q) {
      int i = q * 256 + t;
      int n = i >> 4, kc = i & 15;
      *reinterpret_cast<u16x8*>(&wlds[n * WSTRIDE + kc * 8]) =
          *reinterpret_cast<const u16x8*>(&Wt[n * D + kc * 8]);
    }
    __syncthreads();
    #pragma unroll
    for (int kb = 0; kb < 4; ++kb) {
      bf16x8 af0 = *reinterpret_cast<const bf16x8*>(&Act[a0 + kb * 32]);
      bf16x8 af1 = *reinterpret_cast<const bf16x8*>(&Act[a1 + kb * 32]);
      #pragma unroll
      for (int c = 0; c < 8; ++c) {
        bf16x8 wf = *reinterpret_cast<const bf16x8*>(
            &wlds[(c * 16 + l15) * WSTRIDE + kb * 32 + g * 8]);
        acc0[c] = __builtin_amdgcn_mfma_f32_16x16x32_bf16(af0, wf, acc0[c], 0, 0, 0);
        acc1[c] = __builtin_amdgcn_mfma_f32_16x16x32_bf16(af1, wf, acc1[c], 0, 0, 0);
      }
    }
    __syncthreads();
  }

  float wl[8], wr[8], bv[8];
  #pragma unroll
  for (int c = 0; c < 8; ++c) {
    wl[c] = Wl3[c * 16 + l15];
    wr[c] = Wr3[c * 16 + l15];
    bv[c] = bias[c * 16 + l15];
  }
  float bb3 = b3[0];
  #pragma unroll
  for (int rf = 0; rf < 2; ++rf) {
    #pragma unroll
    for (int rr = 0; rr < 4; ++rr) {
      float pz = 0.f, pr = 0.f;
      #pragma unroll
      for (int c = 0; c < 8; ++c) {
        float v = fmaxf((rf ? acc1[c][rr] : acc0[c][rr]) + bv[c], 0.f);
        pz += v * wl[c];
        pr += v * wr[c];
      }
      pz += __shfl_xor(pz, 1, 64); pr += __shfl_xor(pr, 1, 64);
      pz += __shfl_xor(pz, 2, 64); pr += __shfl_xor(pr, 2, 64);
      pz += __shfl_xor(pz, 4, 64); pr += __shfl_xor(pr, 4, 64);
      pz += __shfl_xor(pz, 8, 64); pr += __shfl_xor(pr, 8, 64);
      int row = rbase + rf * 16 + g * 4 + rr;
      if (l15 == 0 && row < NN) {
        z[row] = pz;
        r[row] = pr + bb3;
      }
    }
  }
}

// ---------------- final: out = r + mean(z over neighbors), 16 lanes/node ----
__global__ __launch_bounds__(256) void k_out(const float* __restrict__ z,
    const float* __restrict__ r, const int* __restrict__ rowstart,
    const int* __restrict__ col, float* __restrict__ out) {
  int t = threadIdx.x;
  int sub = t & 15;
  int node = blockIdx.x * 16 + (t >> 4);
  if (node >= NN) return;
  int b = rowstart[node], e = rowstart[node + 1];
  float s = 0.f;
  for (int j = b + sub; j < e; j += 16) s += z[col[j]];
  s += __shfl_xor(s, 1, 64);
  s += __shfl_xor(s, 2, 64);
  s += __shfl_xor(s, 4, 64);
  s += __shfl_xor(s, 8, 64);
  if (sub == 0) {
    float inv = (e > b) ? 1.f / (float)(e - b) : 0.f;
    out[node] = r[node] + s * inv;
  }
}

extern "C" void kernel_launch(void* const* d_in, const int* in_sizes, int n_in,
                              void* d_out, int out_size, void* d_ws, size_t ws_size,
                              hipStream_t stream) {
  const float* x   = (const float*)d_in[0];
  const int*   ei  = (const int*)d_in[1];
  const float* Wl1 = (const float*)d_in[2];
  const float* Wr1 = (const float*)d_in[3];
  const float* b1  = (const float*)d_in[4];
  const float* Wl2 = (const float*)d_in[5];
  const float* Wr2 = (const float*)d_in[6];
  const float* b2  = (const float*)d_in[7];
  const float* Wl3 = (const float*)d_in[8];
  const float* Wr3 = (const float*)d_in[9];
  const float* b3  = (const float*)d_in[10];
  const int* srcv = ei;
  const int* dstv = ei + NE;
  float* out = (float*)d_out;

  char* ws = (char*)d_ws;
  size_t off = 0;
  auto alloc = [&](size_t bytes) {
    size_t o = off;
    off += (bytes + 255) & ~(size_t)255;
    return o;
  };
  int* deg      = (int*)(ws + alloc((size_t)NN * 4));
  int* incl     = (int*)(ws + alloc((size_t)NN * 4));
  int* rowstart = (int*)(ws + alloc((size_t)(NN + 1) * 4));
  int* col      = (int*)(ws + alloc((size_t)NE * 4));
  int* bsum     = (int*)(ws + alloc(512 * 4));
  int* hw       = (int*)(ws + alloc((size_t)NGRP * NWAVES * 4));
  u32* bkt  = (u32*)(ws + alloc((size_t)NE * 4));
  u16* ncnt = (u16*)(ws + alloc((size_t)NGRP * NSUB * GSZ * 2));
  u16* xb   = (u16*)(ws + alloc((size_t)NN * D * 2));
  u16* Ab   = (u16*)(ws + alloc((size_t)NN * D * 2));
  u16* H1b  = (u16*)(ws + alloc((size_t)NN * D * 2));
  u16* Wt1l = (u16*)(ws + alloc((size_t)D * D * 2));
  u16* Wt1r = (u16*)(ws + alloc((size_t)D * D * 2));
  u16* Wt2l = (u16*)(ws + alloc((size_t)D * D * 2));
  u16* Wt2r = (u16*)(ws + alloc((size_t)D * D * 2));
  float* z  = (float*)(ws + alloc((size_t)NN * 4));
  float* r  = (float*)(ws + alloc((size_t)NN * 4));

  const int nb_nodes = (NN + 255) / 256;     // 391
  const int nb_gemm  = (NN + 127) / 128;     // 782
  const int nb_agg   = 4 * ((NN + 63) / 64); // 4 slices x 1563
  const int nb_out   = (NN + 15) / 16;       // 6250
  const int nb_sub   = NGRP * NSUB;          // 256
  const int nb_nscan = NGRP * ((GSZ + 255) / 256);  // 8*49

  // atomic-free CSR build (+ x->bf16 fused into hist pass)
  k_hist8<<<NBLK, 256, 0, stream>>>(dstv, hw, x, xb);
  k_hscan<<<1, 256, 0, stream>>>(hw, NGRP * NWAVES);
  k_part2<<<NBLK, 256, 0, stream>>>(srcv, dstv, hw, bkt);
  k_nhist<<<nb_sub, 256, 0, stream>>>(bkt, hw, ncnt);
  k_nscan<<<nb_nscan, 256, 0, stream>>>(ncnt, deg);
  k_scan1<<<nb_nodes, 256, 0, stream>>>(deg, incl, bsum);
  k_scan2<<<1, 512, 0, stream>>>(bsum, nb_nodes);
  k_scan3<<<nb_nodes, 256, 0, stream>>>(incl, deg, bsum, rowstart);
  k_scatter2<<<nb_sub, 256, 0, stream>>>(bkt, hw, ncnt, rowstart, col);

  // weight prep (transposed bf16)
  k_cvt_wt4<<<dim3(D, 4), D, 0, stream>>>(Wl1, Wr1, Wl2, Wr2, Wt1l, Wt1r, Wt2l, Wt2r);

  // layer 1
  k_agg_s<<<nb_agg, 256, 0, stream>>>(xb, rowstart, col, Ab);
  k_gemm_mfma<<<nb_gemm, 256, 0, stream>>>(Ab, xb, Wt1l, Wt1r, b1, H1b);
  // layer 2 + fused layer-3 projection
  k_agg_s<<<nb_agg, 256, 0, stream>>>(H1b, rowstart, col, Ab);
  k_gemm2_zr<<<nb_gemm, 256, 0, stream>>>(Ab, H1b, Wt2l, Wt2r, b2, Wl3, Wr3, b3, z, r);
  // final
  k_out<<<nb_out, 256, 0, stream>>>(z, r, rowstart, col, out);
}

// Round 12
// 356.771 us; speedup vs baseline: 1.1520x; 1.1520x over previous
//
#include <hip/hip_runtime.h>
#include <hip/hip_bf16.h>

#define NN 100000
#define NE 1600000
#define D 128
#define NGRP 8
#define GSZ (NN / NGRP)          // 12500, exact
#define EPT 8                    // edges per thread in hist8/part2
#define NBLK ((NE + 2047) / 2048)   // 782 blocks for hist8/part2
#define NWAVES (NBLK * 4)        // 3128 waves
#define NSUB 32                  // sub-blocks per group in nhist/scatter2
#define WSTRIDE 136              // LDS row stride (u16): 272B -> conflict-free b128

typedef unsigned short u16;
typedef unsigned int u32;
typedef unsigned long long u64;
typedef __attribute__((ext_vector_type(8))) short bf16x8;
typedef __attribute__((ext_vector_type(4))) float f32x4;
typedef __attribute__((ext_vector_type(8))) u16 u16x8;

__device__ inline u16 f2b(float f) {
  union { float f; u32 u; } v; v.f = f;
  u32 u = v.u;
  return (u16)((u + 0x7fffu + ((u >> 16) & 1u)) >> 16);
}
__device__ inline float b2f(u16 h) {
  union { u32 u; float f; } v; v.u = ((u32)h) << 16; return v.f;
}

// ---------------- per-wave 8-bucket histogram + x->bf16 convert -------------
__global__ __launch_bounds__(256) void k_hist8(const int* __restrict__ dst,
    int* __restrict__ hw, const float* __restrict__ xin, u16* __restrict__ xb) {
  const int t = threadIdx.x, lane = t & 63, wid = t >> 6;
  const int eb = blockIdx.x * (256 * EPT);
  const int wv = blockIdx.x * 4 + wid;
  int c0=0,c1=0,c2=0,c3=0,c4=0,c5=0,c6=0,c7=0;
  #pragma unroll
  for (int r = 0; r < EPT; ++r) {
    int e = eb + r * 256 + t;
    bool v = e < NE;
    int q = v ? __builtin_nontemporal_load(&dst[e]) / GSZ : 8;
    c0 += __popcll(__ballot(q == 0)); c1 += __popcll(__ballot(q == 1));
    c2 += __popcll(__ballot(q == 2)); c3 += __popcll(__ballot(q == 3));
    c4 += __popcll(__ballot(q == 4)); c5 += __popcll(__ballot(q == 5));
    c6 += __popcll(__ballot(q == 6)); c7 += __popcll(__ballot(q == 7));
    if (v) {
      const f32x4* p = reinterpret_cast<const f32x4*>(xin) + (size_t)e * 2;
      f32x4 a = __builtin_nontemporal_load(p);
      f32x4 b = __builtin_nontemporal_load(p + 1);
      u16x8 o;
      o[0] = f2b(a[0]); o[1] = f2b(a[1]); o[2] = f2b(a[2]); o[3] = f2b(a[3]);
      o[4] = f2b(b[0]); o[5] = f2b(b[1]); o[6] = f2b(b[2]); o[7] = f2b(b[3]);
      __builtin_nontemporal_store(o, reinterpret_cast<u16x8*>(xb + (size_t)e * 8));
    }
  }
  if (lane == 0) {
    hw[0 * NWAVES + wv] = c0; hw[1 * NWAVES + wv] = c1;
    hw[2 * NWAVES + wv] = c2; hw[3 * NWAVES + wv] = c3;
    hw[4 * NWAVES + wv] = c4; hw[5 * NWAVES + wv] = c5;
    hw[6 * NWAVES + wv] = c6; hw[7 * NWAVES + wv] = c7;
  }
}

// ---------------- single-block exclusive scan (in place) --------------------
__global__ void k_hscan(int* __restrict__ a, int n) {
  __shared__ int s[256];
  int t = threadIdx.x;
  int per = (n + 255) / 256;
  int lo = t * per, hi = lo + per; if (hi > n) hi = n;
  int sum = 0;
  for (int i = lo; i < hi; ++i) sum += a[i];
  s[t] = sum; __syncthreads();
  for (int off = 1; off < 256; off <<= 1) {
    int u = (t >= off) ? s[t - off] : 0;
    __syncthreads(); s[t] += u; __syncthreads();
  }
  int run = s[t] - sum;
  for (int i = lo; i < hi; ++i) { int v = a[i]; a[i] = run; run += v; }
}

// ---------------- deterministic bucket write (ballot ranks, no atomics) -----
// entry packed u32: (d_local << 17) | src   (14 + 17 bits)
__global__ __launch_bounds__(256) void k_part2(const int* __restrict__ src,
    const int* __restrict__ dst, const int* __restrict__ hw,
    u32* __restrict__ bkt) {
  const int t = threadIdx.x, lane = t & 63, wid = t >> 6;
  const int eb = blockIdx.x * (256 * EPT);
  const int wv = blockIdx.x * 4 + wid;
  int q[EPT]; u32 pk[EPT];
  #pragma unroll
  for (int r = 0; r < EPT; ++r) {
    int e = eb + r * 256 + t;
    bool v = e < NE;
    int d = v ? __builtin_nontemporal_load(&dst[e]) : 0;
    int s = v ? __builtin_nontemporal_load(&src[e]) : 0;
    q[r] = v ? d / GSZ : 8;
    pk[r] = v ? (((u32)(d - q[r] * GSZ) << 17) | (u32)s) : 0;
  }
  u64 below = (lane == 63) ? 0x7fffffffffffffffull : ((1ull << lane) - 1);
  int base[NGRP];
  #pragma unroll
  for (int b = 0; b < NGRP; ++b) base[b] = hw[b * NWAVES + wv];
  #pragma unroll
  for (int b = 0; b < NGRP; ++b) {
    int run = 0;
    #pragma unroll
    for (int r = 0; r < EPT; ++r) {
      u64 m = __ballot(q[r] == b);
      if (q[r] == b) {
        int pos = base[b] + run + __popcll(m & below);
        if (pos < NE)
          bkt[pos] = pk[r];
      }
      run += __popcll(m);
    }
  }
}

// ---------------- per-sub-block node histogram in LDS -----------------------
__global__ __launch_bounds__(256) void k_nhist(const u32* __restrict__ bkt,
    const int* __restrict__ hw, u16* __restrict__ ncnt) {
  __shared__ int h[GSZ];
  const int g = blockIdx.x & (NGRP - 1);
  const int sub = blockIdx.x >> 3;
  const int t = threadIdx.x;
  const int start = hw[g * NWAVES];
  const int end = (g < NGRP - 1) ? hw[(g + 1) * NWAVES] : NE;
  const int cnt = end - start;
  const int chunk = (cnt + NSUB - 1) / NSUB;
  int lo = start + sub * chunk;
  int hi = lo + chunk; if (hi > end) hi = end;
  for (int i = t; i < GSZ; i += 256) h[i] = 0;
  __syncthreads();
  for (int i = lo + t; i < hi; i += 256) {
    int dl = (int)(__builtin_nontemporal_load(&bkt[i]) >> 17);
    atomicAdd(&h[dl], 1);
  }
  __syncthreads();
  u16* outp = ncnt + ((size_t)g * NSUB + sub) * GSZ;
  for (int i = t; i < GSZ; i += 256) outp[i] = (u16)h[i];
}

// ---------------- per-node scan over sub-blocks -> offsets + deg ------------
__global__ __launch_bounds__(256) void k_nscan(u16* __restrict__ ncnt,
    int* __restrict__ deg) {
  const int g = blockIdx.x & (NGRP - 1);
  const int seg = blockIdx.x >> 3;
  int d = seg * 256 + threadIdx.x;
  if (d >= GSZ) return;
  int run = 0;
  #pragma unroll
  for (int s = 0; s < NSUB; ++s) {
    size_t idx = ((size_t)g * NSUB + s) * GSZ + d;
    int v = ncnt[idx];
    ncnt[idx] = (u16)run;
    run += v;
  }
  deg[g * GSZ + d] = run;
}

// ---------------- per-group rowstart: base from bucket bounds + local scan --
// replaces scan1+scan2+scan3: global offset of group g's slice IS the bucket
// start hw[g*NWAVES]; within-group offset = exclusive scan of deg over GSZ.
__global__ void k_gscan(const int* __restrict__ deg, const int* __restrict__ hw,
                        int* __restrict__ rowstart) {
  __shared__ int s[256];
  const int g = blockIdx.x;
  const int t = threadIdx.x;
  const int base = hw[g * NWAVES];
  const int per = (GSZ + 255) / 256;       // 49
  int lo = t * per, hi = lo + per; if (hi > GSZ) hi = GSZ;
  int sum = 0;
  for (int i = lo; i < hi; ++i) sum += deg[g * GSZ + i];
  s[t] = sum; __syncthreads();
  for (int off = 1; off < 256; off <<= 1) {
    int u = (t >= off) ? s[t - off] : 0;
    __syncthreads(); s[t] += u; __syncthreads();
  }
  int run = base + s[t] - sum;
  for (int i = lo; i < hi; ++i) {
    int v = deg[g * GSZ + i];
    rowstart[g * GSZ + i] = run;
    run += v;
  }
  if (g == NGRP - 1 && t == 255) rowstart[NN] = NE;
}

// ---------------- scatter: LDS cursors, XCD-resident col slice --------------
__global__ __launch_bounds__(256) void k_scatter2(const u32* __restrict__ bkt,
    const int* __restrict__ hw, const u16* __restrict__ ncnt,
    const int* __restrict__ rowstart, int* __restrict__ col) {
  __shared__ int cur[GSZ];
  const int g = blockIdx.x & (NGRP - 1);
  const int sub = blockIdx.x >> 3;
  const int t = threadIdx.x;
  const int start = hw[g * NWAVES];
  const int end = (g < NGRP - 1) ? hw[(g + 1) * NWAVES] : NE;
  const int cnt = end - start;
  const int chunk = (cnt + NSUB - 1) / NSUB;
  int lo = start + sub * chunk;
  int hi = lo + chunk; if (hi > end) hi = end;
  const u16* nof = ncnt + ((size_t)g * NSUB + sub) * GSZ;
  for (int i = t; i < GSZ; i += 256)
    cur[i] = rowstart[g * GSZ + i] + (int)nof[i];
  __syncthreads();
  for (int i = lo + t; i < hi; i += 256) {
    u32 v = __builtin_nontemporal_load(&bkt[i]);
    int dl = (int)(v >> 17), s = (int)(v & 0x1ffffu);
    int pos = atomicAdd(&cur[dl], 1);
    col[pos] = s;
  }
}

// ---------------- W (k-major [k][n]) -> Wt (n-major [n][k]) bf16, 4 mats ----
__global__ void k_cvt_wt4(const float* __restrict__ W0, const float* __restrict__ W1,
                          const float* __restrict__ W2, const float* __restrict__ W3,
                          u16* __restrict__ T0, u16* __restrict__ T1,
                          u16* __restrict__ T2, u16* __restrict__ T3) {
  const float* W = blockIdx.y == 0 ? W0 : blockIdx.y == 1 ? W1 : blockIdx.y == 2 ? W2 : W3;
  u16* T = blockIdx.y == 0 ? T0 : blockIdx.y == 1 ? T1 : blockIdx.y == 2 ? T2 : T3;
  int n = blockIdx.x, k = threadIdx.x;
  T[n * D + k] = f2b(W[k * D + n]);
}

// ---------------- line-aligned 2-slice mean aggregation ---------------------
// slice = bid & 1 -> 64 features = 128B = EXACTLY one cache line per row-slice
// (R11 lesson: 64B slices fetch 128B lines with a dead half -> 2x traffic).
// With mod-8 block->XCD round-robin, XCD g only touches slice g&1: per-XCD
// working set = 100K fully-useful lines = 12.8MB (vs 22MB full-row).
// Wave = ONE node: 8 edge-slots x 8 feature-chunks -> 8-16 rows in flight,
// 3-shuffle reduce, no staging arrays (~24 VGPR).
__global__ __launch_bounds__(256) void k_agg_s2(const u16* __restrict__ feat,
    const int* __restrict__ rowstart, const int* __restrict__ col,
    u16* __restrict__ out) {
  int wid = threadIdx.x >> 6, lane = threadIdx.x & 63;
  int slice = blockIdx.x & 1;
  int node = (blockIdx.x >> 1) * 4 + wid;
  if (node >= NN) return;
  int b = rowstart[node], e = rowstart[node + 1];
  int slot = lane >> 3;      // edge slot 0..7
  int ch = lane & 7;         // 16B chunk within the 128B slice
  const u16* fp = feat + slice * 64 + ch * 8;
  float a[8] = {};
  int j = b;
  for (; j + 15 < e; j += 16) {        // 16 rows in flight
    int s0 = col[j + slot];
    int s1 = col[j + 8 + slot];
    u16x8 v0 = *reinterpret_cast<const u16x8*>(fp + (size_t)s0 * D);
    u16x8 v1 = *reinterpret_cast<const u16x8*>(fp + (size_t)s1 * D);
    #pragma unroll
    for (int t = 0; t < 8; ++t) a[t] += b2f(v0[t]) + b2f(v1[t]);
  }
  if (j + 7 < e) {                     // 8-edge step
    int s0 = col[j + slot];
    u16x8 v0 = *reinterpret_cast<const u16x8*>(fp + (size_t)s0 * D);
    #pragma unroll
    for (int t = 0; t < 8; ++t) a[t] += b2f(v0[t]);
    j += 8;
  }
  if (j + slot < e) {                  // masked tail 1..7 edges
    int s0 = col[j + slot];
    u16x8 v0 = *reinterpret_cast<const u16x8*>(fp + (size_t)s0 * D);
    #pragma unroll
    for (int t = 0; t < 8; ++t) a[t] += b2f(v0[t]);
  }
  #pragma unroll
  for (int t = 0; t < 8; ++t) {        // reduce 8 slots
    a[t] += __shfl_xor(a[t], 8, 64);
    a[t] += __shfl_xor(a[t], 16, 64);
    a[t] += __shfl_xor(a[t], 32, 64);
  }
  if (slot == 0) {
    float inv = (e > b) ? 1.f / (float)(e - b) : 0.f;
    u16x8 o;
    #pragma unroll
    for (int t = 0; t < 8; ++t) o[t] = f2b(a[t] * inv);
    *reinterpret_cast<u16x8*>(&out[(size_t)node * D + slice * 64 + ch * 8]) = o;
  }
}

// ---------------- fused dual GEMM via MFMA, weights staged in LDS -----------
__global__ __launch_bounds__(256) void k_gemm_mfma(
    const u16* __restrict__ A, const u16* __restrict__ B,
    const u16* __restrict__ Wt1, const u16* __restrict__ Wt2,
    const float* __restrict__ bias, u16* __restrict__ Cout)
{
  __shared__ u16 wlds[128 * WSTRIDE];
  const int t = threadIdx.x;
  const int wid = t >> 6, lane = t & 63;
  const int l15 = lane & 15, g = lane >> 4;
  const int rbase = blockIdx.x * 128 + wid * 32;

  int r0 = rbase + l15, r1 = r0 + 16;
  size_t a0 = (size_t)(r0 < NN ? r0 : NN - 1) * D + g * 8;
  size_t a1 = (size_t)(r1 < NN ? r1 : NN - 1) * D + g * 8;

  f32x4 acc0[8] = {}, acc1[8] = {};

  #pragma unroll
  for (int phase = 0; phase < 2; ++phase) {
    const u16* Act = phase ? B : A;
    const u16* Wt  = phase ? Wt2 : Wt1;
    #pragma unroll
    for (int q = 0; q < 8; ++q) {
      int i = q * 256 + t;           // 16B chunk id, 2048 total
      int n = i >> 4, kc = i & 15;
      *reinterpret_cast<u16x8*>(&wlds[n * WSTRIDE + kc * 8]) =
          *reinterpret_cast<const u16x8*>(&Wt[n * D + kc * 8]);
    }
    __syncthreads();
    #pragma unroll
    for (int kb = 0; kb < 4; ++kb) {
      bf16x8 af0 = *reinterpret_cast<const bf16x8*>(&Act[a0 + kb * 32]);
      bf16x8 af1 = *reinterpret_cast<const bf16x8*>(&Act[a1 + kb * 32]);
      #pragma unroll
      for (int c = 0; c < 8; ++c) {
        bf16x8 wf = *reinterpret_cast<const bf16x8*>(
            &wlds[(c * 16 + l15) * WSTRIDE + kb * 32 + g * 8]);
        acc0[c] = __builtin_amdgcn_mfma_f32_16x16x32_bf16(af0, wf, acc0[c], 0, 0, 0);
        acc1[c] = __builtin_amdgcn_mfma_f32_16x16x32_bf16(af1, wf, acc1[c], 0, 0, 0);
      }
    }
    __syncthreads();   // all waves done reading before restage
  }

  #pragma unroll
  for (int c = 0; c < 8; ++c) {
    float bv = bias[c * 16 + l15];
    #pragma unroll
    for (int r = 0; r < 4; ++r) {
      int row0 = rbase + g * 4 + r;
      if (row0 < NN) {
        float v = fmaxf(acc0[c][r] + bv, 0.f);
        Cout[(size_t)row0 * D + c * 16 + l15] = f2b(v);
      }
      int row1 = row0 + 16;
      if (row1 < NN) {
        float v = fmaxf(acc1[c][r] + bv, 0.f);
        Cout[(size_t)row1 * D + c * 16 + l15] = f2b(v);
      }
    }
  }
}

// ---------------- layer-2 GEMM (LDS weights) + fused layer-3 projection -----
__global__ __launch_bounds__(256) void k_gemm2_zr(
    const u16* __restrict__ A, const u16* __restrict__ B,
    const u16* __restrict__ Wt1, const u16* __restrict__ Wt2,
    const float* __restrict__ bias,
    const float* __restrict__ Wl3, const float* __restrict__ Wr3,
    const float* __restrict__ b3,
    float* __restrict__ z, float* __restrict__ r)
{
  __shared__ u16 wlds[128 * WSTRIDE];
  const int t = threadIdx.x;
  const int wid = t >> 6, lane = t & 63;
  const int l15 = lane & 15, g = lane >> 4;
  const int rbase = blockIdx.x * 128 + wid * 32;

  int r0 = rbase + l15, r1 = r0 + 16;
  size_t a0 = (size_t)(r0 < NN ? r0 : NN - 1) * D + g * 8;
  size_t a1 = (size_t)(r1 < NN ? r1 : NN - 1) * D + g * 8;

  f32x4 acc0[8] = {}, acc1[8] = {};

  #pragma unroll
  for (int phase = 0; phase < 2; ++phase) {
    const u16* Act = phase ? B : A;
    const u16* Wt  = phase ? Wt2 : Wt1;
    #pragma unroll
    for (int q = 0; q < 8; ++q) {
      int i = q * 256 + t;
      int n = i >> 4, kc = i & 15;
      *reinterpret_cast<u16x8*>(&wlds[n * WSTRIDE + kc * 8]) =
          *reinterpret_cast<const u16x8*>(&Wt[n * D + kc * 8]);
    }
    __syncthreads();
    #pragma unroll
    for (int kb = 0; kb < 4; ++kb) {
      bf16x8 af0 = *reinterpret_cast<const bf16x8*>(&Act[a0 + kb * 32]);
      bf16x8 af1 = *reinterpret_cast<const bf16x8*>(&Act[a1 + kb * 32]);
      #pragma unroll
      for (int c = 0; c < 8; ++c) {
        bf16x8 wf = *reinterpret_cast<const bf16x8*>(
            &wlds[(c * 16 + l15) * WSTRIDE + kb * 32 + g * 8]);
        acc0[c] = __builtin_amdgcn_mfma_f32_16x16x32_bf16(af0, wf, acc0[c], 0, 0, 0);
        acc1[c] = __builtin_amdgcn_mfma_f32_16x16x32_bf16(af1, wf, acc1[c], 0, 0, 0);
      }
    }
    __syncthreads();
  }

  float wl[8], wr[8], bv[8];
  #pragma unroll
  for (int c = 0; c < 8; ++c) {
    wl[c] = Wl3[c * 16 + l15];
    wr[c] = Wr3[c * 16 + l15];
    bv[c] = bias[c * 16 + l15];
  }
  float bb3 = b3[0];
  #pragma unroll
  for (int rf = 0; rf < 2; ++rf) {
    #pragma unroll
    for (int rr = 0; rr < 4; ++rr) {
      float pz = 0.f, pr = 0.f;
      #pragma unroll
      for (int c = 0; c < 8; ++c) {
        float v = fmaxf((rf ? acc1[c][rr] : acc0[c][rr]) + bv[c], 0.f);
        pz += v * wl[c];
        pr += v * wr[c];
      }
      pz += __shfl_xor(pz, 1, 64); pr += __shfl_xor(pr, 1, 64);
      pz += __shfl_xor(pz, 2, 64); pr += __shfl_xor(pr, 2, 64);
      pz += __shfl_xor(pz, 4, 64); pr += __shfl_xor(pr, 4, 64);
      pz += __shfl_xor(pz, 8, 64); pr += __shfl_xor(pr, 8, 64);
      int row = rbase + rf * 16 + g * 4 + rr;
      if (l15 == 0 && row < NN) {
        z[row] = pz;
        r[row] = pr + bb3;
      }
    }
  }
}

// ---------------- final: out = r + mean(z over neighbors), 16 lanes/node ----
__global__ __launch_bounds__(256) void k_out(const float* __restrict__ z,
    const float* __restrict__ r, const int* __restrict__ rowstart,
    const int* __restrict__ col, float* __restrict__ out) {
  int t = threadIdx.x;
  int sub = t & 15;
  int node = blockIdx.x * 16 + (t >> 4);
  if (node >= NN) return;
  int b = rowstart[node], e = rowstart[node + 1];
  float s = 0.f;
  for (int j = b + sub; j < e; j += 16) s += z[col[j]];
  s += __shfl_xor(s, 1, 64);
  s += __shfl_xor(s, 2, 64);
  s += __shfl_xor(s, 4, 64);
  s += __shfl_xor(s, 8, 64);
  if (sub == 0) {
    float inv = (e > b) ? 1.f / (float)(e - b) : 0.f;
    out[node] = r[node] + s * inv;
  }
}

extern "C" void kernel_launch(void* const* d_in, const int* in_sizes, int n_in,
                              void* d_out, int out_size, void* d_ws, size_t ws_size,
                              hipStream_t stream) {
  const float* x   = (const float*)d_in[0];
  const int*   ei  = (const int*)d_in[1];
  const float* Wl1 = (const float*)d_in[2];
  const float* Wr1 = (const float*)d_in[3];
  const float* b1  = (const float*)d_in[4];
  const float* Wl2 = (const float*)d_in[5];
  const float* Wr2 = (const float*)d_in[6];
  const float* b2  = (const float*)d_in[7];
  const float* Wl3 = (const float*)d_in[8];
  const float* Wr3 = (const float*)d_in[9];
  const float* b3  = (const float*)d_in[10];
  const int* srcv = ei;
  const int* dstv = ei + NE;
  float* out = (float*)d_out;

  char* ws = (char*)d_ws;
  size_t off = 0;
  auto alloc = [&](size_t bytes) {
    size_t o = off;
    off += (bytes + 255) & ~(size_t)255;
    return o;
  };
  int* deg      = (int*)(ws + alloc((size_t)NN * 4));
  int* rowstart = (int*)(ws + alloc((size_t)(NN + 1) * 4));
  int* col      = (int*)(ws + alloc((size_t)NE * 4));
  int* hw       = (int*)(ws + alloc((size_t)NGRP * NWAVES * 4));
  u32* bkt  = (u32*)(ws + alloc((size_t)NE * 4));
  u16* ncnt = (u16*)(ws + alloc((size_t)NGRP * NSUB * GSZ * 2));
  u16* xb   = (u16*)(ws + alloc((size_t)NN * D * 2));
  u16* Ab   = (u16*)(ws + alloc((size_t)NN * D * 2));
  u16* H1b  = (u16*)(ws + alloc((size_t)NN * D * 2));
  u16* Wt1l = (u16*)(ws + alloc((size_t)D * D * 2));
  u16* Wt1r = (u16*)(ws + alloc((size_t)D * D * 2));
  u16* Wt2l = (u16*)(ws + alloc((size_t)D * D * 2));
  u16* Wt2r = (u16*)(ws + alloc((size_t)D * D * 2));
  float* z  = (float*)(ws + alloc((size_t)NN * 4));
  float* r  = (float*)(ws + alloc((size_t)NN * 4));

  const int nb_gemm  = (NN + 127) / 128;       // 782
  const int nb_agg   = 2 * ((NN + 3) / 4);     // 2 slices x 25000
  const int nb_out   = (NN + 15) / 16;         // 6250
  const int nb_sub   = NGRP * NSUB;            // 256
  const int nb_nscan = NGRP * ((GSZ + 255) / 256);  // 8*49

  // atomic-free CSR build (+ x->bf16 fused into hist pass)
  k_hist8<<<NBLK, 256, 0, stream>>>(dstv, hw, x, xb);
  k_hscan<<<1, 256, 0, stream>>>(hw, NGRP * NWAVES);
  k_part2<<<NBLK, 256, 0, stream>>>(srcv, dstv, hw, bkt);
  k_nhist<<<nb_sub, 256, 0, stream>>>(bkt, hw, ncnt);
  k_nscan<<<nb_nscan, 256, 0, stream>>>(ncnt, deg);
  k_gscan<<<NGRP, 256, 0, stream>>>(deg, hw, rowstart);
  k_scatter2<<<nb_sub, 256, 0, stream>>>(bkt, hw, ncnt, rowstart, col);

  // weight prep (transposed bf16)
  k_cvt_wt4<<<dim3(D, 4), D, 0, stream>>>(Wl1, Wr1, Wl2, Wr2, Wt1l, Wt1r, Wt2l, Wt2r);

  // layer 1
  k_agg_s2<<<nb_agg, 256, 0, stream>>>(xb, rowstart, col, Ab);
  k_gemm_mfma<<<nb_gemm, 256, 0, stream>>>(Ab, xb, Wt1l, Wt1r, b1, H1b);
  // layer 2 + fused layer-3 projection
  k_agg_s2<<<nb_agg, 256, 0, stream>>>(H1b, rowstart, col, Ab);
  k_gemm2_zr<<<nb_gemm, 256, 0, stream>>>(Ab, H1b, Wt2l, Wt2r, b2, Wl3, Wr3, b3, z, r);
  // final
  k_out<<<nb_out, 256, 0, stream>>>(z, r, rowstart, col, out);
}

// Round 13
// 330.502 us; speedup vs baseline: 1.2436x; 1.0795x over previous
//
#include <hip/hip_runtime.h>
#include <hip/hip_bf16.h>

#define NN 100000
#define NE 1600000
#define D 128
#define NGRP 8
#define GSZ (NN / NGRP)          // 12500, exact
#define EPT 8                    // edges per thread in hist8/part2
#define NBLK ((NE + 2047) / 2048)   // 782 blocks for hist8/part2
#define NWAVES (NBLK * 4)        // 3128 waves
#define NSUB 32                  // sub-blocks per group in nhist/scatter2
#define WSTRIDE 136              // LDS row stride (u16): 272B -> conflict-free b128

typedef unsigned short u16;
typedef unsigned int u32;
typedef unsigned long long u64;
typedef unsigned char u8;
typedef __attribute__((ext_vector_type(8))) short bf16x8;
typedef __attribute__((ext_vector_type(4))) float f32x4;
typedef __attribute__((ext_vector_type(2))) float f32x2;
typedef __attribute__((ext_vector_type(8))) u16 u16x8;
typedef __attribute__((ext_vector_type(4))) u32 u32x4;
typedef __attribute__((ext_vector_type(2))) u32 u32x2;

__device__ inline u16 f2b(float f) {
  union { float f; u32 u; } v; v.f = f;
  u32 u = v.u;
  return (u16)((u + 0x7fffu + ((u >> 16) & 1u)) >> 16);
}
__device__ inline float b2f(u16 h) {
  union { u32 u; float f; } v; v.u = ((u32)h) << 16; return v.f;
}
// accumulate 16 fp8 (one u32x4) into 16 f32 accumulators via HW packed cvt
__device__ inline void acc16(float* a, u32x4 v) {
  #pragma unroll
  for (int w = 0; w < 4; ++w) {
    f32x2 lo = __builtin_amdgcn_cvt_pk_f32_fp8(v[w], false);
    f32x2 hi = __builtin_amdgcn_cvt_pk_f32_fp8(v[w], true);
    a[w * 4 + 0] += lo[0]; a[w * 4 + 1] += lo[1];
    a[w * 4 + 2] += hi[0]; a[w * 4 + 3] += hi[1];
  }
}

// ---------------- hist + x->bf16 + x->fp8 convert (1.6M-element streams) ----
__global__ __launch_bounds__(256) void k_hist8(const int* __restrict__ dst,
    int* __restrict__ hw, const float* __restrict__ xin, u16* __restrict__ xb,
    u8* __restrict__ xq) {
  const int t = threadIdx.x, lane = t & 63, wid = t >> 6;
  const int eb = blockIdx.x * (256 * EPT);
  const int wv = blockIdx.x * 4 + wid;
  int c0=0,c1=0,c2=0,c3=0,c4=0,c5=0,c6=0,c7=0;
  #pragma unroll
  for (int r = 0; r < EPT; ++r) {
    int e = eb + r * 256 + t;
    bool v = e < NE;
    int q = v ? __builtin_nontemporal_load(&dst[e]) / GSZ : 8;
    c0 += __popcll(__ballot(q == 0)); c1 += __popcll(__ballot(q == 1));
    c2 += __popcll(__ballot(q == 2)); c3 += __popcll(__ballot(q == 3));
    c4 += __popcll(__ballot(q == 4)); c5 += __popcll(__ballot(q == 5));
    c6 += __popcll(__ballot(q == 6)); c7 += __popcll(__ballot(q == 7));
    if (v) {
      const f32x4* p = reinterpret_cast<const f32x4*>(xin) + (size_t)e * 2;
      f32x4 a = __builtin_nontemporal_load(p);
      f32x4 b = __builtin_nontemporal_load(p + 1);
      u16x8 o;
      o[0] = f2b(a[0]); o[1] = f2b(a[1]); o[2] = f2b(a[2]); o[3] = f2b(a[3]);
      o[4] = f2b(b[0]); o[5] = f2b(b[1]); o[6] = f2b(b[2]); o[7] = f2b(b[3]);
      __builtin_nontemporal_store(o, reinterpret_cast<u16x8*>(xb + (size_t)e * 8));
      int qlo = __builtin_amdgcn_cvt_pk_fp8_f32(a[0], a[1], 0, false);
      qlo = __builtin_amdgcn_cvt_pk_fp8_f32(a[2], a[3], qlo, true);
      int qhi = __builtin_amdgcn_cvt_pk_fp8_f32(b[0], b[1], 0, false);
      qhi = __builtin_amdgcn_cvt_pk_fp8_f32(b[2], b[3], qhi, true);
      u32x2 qo; qo[0] = (u32)qlo; qo[1] = (u32)qhi;
      __builtin_nontemporal_store(qo, reinterpret_cast<u32x2*>(xq + (size_t)e * 8));
    }
  }
  if (lane == 0) {
    hw[0 * NWAVES + wv] = c0; hw[1 * NWAVES + wv] = c1;
    hw[2 * NWAVES + wv] = c2; hw[3 * NWAVES + wv] = c3;
    hw[4 * NWAVES + wv] = c4; hw[5 * NWAVES + wv] = c5;
    hw[6 * NWAVES + wv] = c6; hw[7 * NWAVES + wv] = c7;
  }
}

// ---------------- single-block exclusive scan (in place) --------------------
__global__ void k_hscan(int* __restrict__ a, int n) {
  __shared__ int s[256];
  int t = threadIdx.x;
  int per = (n + 255) / 256;
  int lo = t * per, hi = lo + per; if (hi > n) hi = n;
  int sum = 0;
  for (int i = lo; i < hi; ++i) sum += a[i];
  s[t] = sum; __syncthreads();
  for (int off = 1; off < 256; off <<= 1) {
    int u = (t >= off) ? s[t - off] : 0;
    __syncthreads(); s[t] += u; __syncthreads();
  }
  int run = s[t] - sum;
  for (int i = lo; i < hi; ++i) { int v = a[i]; a[i] = run; run += v; }
}

// ---------------- deterministic bucket write (ballot ranks, no atomics) -----
__global__ __launch_bounds__(256) void k_part2(const int* __restrict__ src,
    const int* __restrict__ dst, const int* __restrict__ hw,
    u32* __restrict__ bkt) {
  const int t = threadIdx.x, lane = t & 63, wid = t >> 6;
  const int eb = blockIdx.x * (256 * EPT);
  const int wv = blockIdx.x * 4 + wid;
  int q[EPT]; u32 pk[EPT];
  #pragma unroll
  for (int r = 0; r < EPT; ++r) {
    int e = eb + r * 256 + t;
    bool v = e < NE;
    int d = v ? __builtin_nontemporal_load(&dst[e]) : 0;
    int s = v ? __builtin_nontemporal_load(&src[e]) : 0;
    q[r] = v ? d / GSZ : 8;
    pk[r] = v ? (((u32)(d - q[r] * GSZ) << 17) | (u32)s) : 0;
  }
  u64 below = (lane == 63) ? 0x7fffffffffffffffull : ((1ull << lane) - 1);
  int base[NGRP];
  #pragma unroll
  for (int b = 0; b < NGRP; ++b) base[b] = hw[b * NWAVES + wv];
  #pragma unroll
  for (int b = 0; b < NGRP; ++b) {
    int run = 0;
    #pragma unroll
    for (int r = 0; r < EPT; ++r) {
      u64 m = __ballot(q[r] == b);
      if (q[r] == b) {
        int pos = base[b] + run + __popcll(m & below);
        if (pos < NE)
          bkt[pos] = pk[r];
      }
      run += __popcll(m);
    }
  }
}

// ---------------- per-sub-block node histogram in LDS -----------------------
__global__ __launch_bounds__(256) void k_nhist(const u32* __restrict__ bkt,
    const int* __restrict__ hw, u16* __restrict__ ncnt) {
  __shared__ int h[GSZ];
  const int g = blockIdx.x & (NGRP - 1);
  const int sub = blockIdx.x >> 3;
  const int t = threadIdx.x;
  const int start = hw[g * NWAVES];
  const int end = (g < NGRP - 1) ? hw[(g + 1) * NWAVES] : NE;
  const int cnt = end - start;
  const int chunk = (cnt + NSUB - 1) / NSUB;
  int lo = start + sub * chunk;
  int hi = lo + chunk; if (hi > end) hi = end;
  for (int i = t; i < GSZ; i += 256) h[i] = 0;
  __syncthreads();
  for (int i = lo + t; i < hi; i += 256) {
    int dl = (int)(__builtin_nontemporal_load(&bkt[i]) >> 17);
    atomicAdd(&h[dl], 1);
  }
  __syncthreads();
  u16* outp = ncnt + ((size_t)g * NSUB + sub) * GSZ;
  for (int i = t; i < GSZ; i += 256) outp[i] = (u16)h[i];
}

// ---------------- per-node scan over sub-blocks -> offsets + deg ------------
__global__ __launch_bounds__(256) void k_nscan(u16* __restrict__ ncnt,
    int* __restrict__ deg) {
  const int g = blockIdx.x & (NGRP - 1);
  const int seg = blockIdx.x >> 3;
  int d = seg * 256 + threadIdx.x;
  if (d >= GSZ) return;
  int run = 0;
  #pragma unroll
  for (int s = 0; s < NSUB; ++s) {
    size_t idx = ((size_t)g * NSUB + s) * GSZ + d;
    int v = ncnt[idx];
    ncnt[idx] = (u16)run;
    run += v;
  }
  deg[g * GSZ + d] = run;
}

// ---------------- per-group rowstart: bucket base + local scan --------------
__global__ void k_gscan(const int* __restrict__ deg, const int* __restrict__ hw,
                        int* __restrict__ rowstart) {
  __shared__ int s[256];
  const int g = blockIdx.x;
  const int t = threadIdx.x;
  const int base = hw[g * NWAVES];
  const int per = (GSZ + 255) / 256;       // 49
  int lo = t * per, hi = lo + per; if (hi > GSZ) hi = GSZ;
  int sum = 0;
  for (int i = lo; i < hi; ++i) sum += deg[g * GSZ + i];
  s[t] = sum; __syncthreads();
  for (int off = 1; off < 256; off <<= 1) {
    int u = (t >= off) ? s[t - off] : 0;
    __syncthreads(); s[t] += u; __syncthreads();
  }
  int run = base + s[t] - sum;
  for (int i = lo; i < hi; ++i) {
    int v = deg[g * GSZ + i];
    rowstart[g * GSZ + i] = run;
    run += v;
  }
  if (g == NGRP - 1 && t == 255) rowstart[NN] = NE;
}

// ---------------- scatter: LDS cursors, XCD-resident col slice --------------
__global__ __launch_bounds__(256) void k_scatter2(const u32* __restrict__ bkt,
    const int* __restrict__ hw, const u16* __restrict__ ncnt,
    const int* __restrict__ rowstart, int* __restrict__ col) {
  __shared__ int cur[GSZ];
  const int g = blockIdx.x & (NGRP - 1);
  const int sub = blockIdx.x >> 3;
  const int t = threadIdx.x;
  const int start = hw[g * NWAVES];
  const int end = (g < NGRP - 1) ? hw[(g + 1) * NWAVES] : NE;
  const int cnt = end - start;
  const int chunk = (cnt + NSUB - 1) / NSUB;
  int lo = start + sub * chunk;
  int hi = lo + chunk; if (hi > end) hi = end;
  const u16* nof = ncnt + ((size_t)g * NSUB + sub) * GSZ;
  for (int i = t; i < GSZ; i += 256)
    cur[i] = rowstart[g * GSZ + i] + (int)nof[i];
  __syncthreads();
  for (int i = lo + t; i < hi; i += 256) {
    u32 v = __builtin_nontemporal_load(&bkt[i]);
    int dl = (int)(v >> 17), s = (int)(v & 0x1ffffu);
    int pos = atomicAdd(&cur[dl], 1);
    col[pos] = s;
  }
}

// ---------------- W (k-major [k][n]) -> Wt (n-major [n][k]) bf16, 4 mats ----
__global__ void k_cvt_wt4(const float* __restrict__ W0, const float* __restrict__ W1,
                          const float* __restrict__ W2, const float* __restrict__ W3,
                          u16* __restrict__ T0, u16* __restrict__ T1,
                          u16* __restrict__ T2, u16* __restrict__ T3) {
  const float* W = blockIdx.y == 0 ? W0 : blockIdx.y == 1 ? W1 : blockIdx.y == 2 ? W2 : W3;
  u16* T = blockIdx.y == 0 ? T0 : blockIdx.y == 1 ? T1 : blockIdx.y == 2 ? T2 : T3;
  int n = blockIdx.x, k = threadIdx.x;
  T[n * D + k] = f2b(W[k * D + n]);
}

// ---------------- fp8 mean aggregation: full row = 128B = ONE cache line ----
// (R12 lesson: bf16 gather pinned at ~3.4TB/s fill on ~177MB; fp8 halves the
// line count with zero slicing overhead.) Wave = 1 node: 8 edge-slots x 8
// feature-chunks (16 fp8 each); 16 rows in flight; 3-shuffle reduce; bf16 out.
__global__ __launch_bounds__(256) void k_agg_q(const u8* __restrict__ feat,
    const int* __restrict__ rowstart, const int* __restrict__ col,
    u16* __restrict__ out) {
  int wid = threadIdx.x >> 6, lane = threadIdx.x & 63;
  int node = blockIdx.x * 4 + wid;
  if (node >= NN) return;
  int b = rowstart[node], e = rowstart[node + 1];
  int slot = lane >> 3, ch = lane & 7;
  const u8* fp = feat + ch * 16;
  float a[16] = {};
  int j = b;
  for (; j + 15 < e; j += 16) {        // 16 rows in flight per wave
    int s0 = col[j + slot], s1 = col[j + 8 + slot];
    u32x4 v0 = *reinterpret_cast<const u32x4*>(fp + (size_t)s0 * D);
    u32x4 v1 = *reinterpret_cast<const u32x4*>(fp + (size_t)s1 * D);
    acc16(a, v0); acc16(a, v1);
  }
  if (j + 7 < e) {
    int s0 = col[j + slot];
    u32x4 v0 = *reinterpret_cast<const u32x4*>(fp + (size_t)s0 * D);
    acc16(a, v0);
    j += 8;
  }
  if (j + slot < e) {                  // masked tail 1..7
    int s0 = col[j + slot];
    u32x4 v0 = *reinterpret_cast<const u32x4*>(fp + (size_t)s0 * D);
    acc16(a, v0);
  }
  #pragma unroll
  for (int t = 0; t < 16; ++t) {       // reduce 8 slots
    a[t] += __shfl_xor(a[t], 8, 64);
    a[t] += __shfl_xor(a[t], 16, 64);
    a[t] += __shfl_xor(a[t], 32, 64);
  }
  if (slot == 0) {
    float inv = (e > b) ? 1.f / (float)(e - b) : 0.f;
    u16x8 o0, o1;
    #pragma unroll
    for (int t = 0; t < 8; ++t) {
      o0[t] = f2b(a[t] * inv);
      o1[t] = f2b(a[8 + t] * inv);
    }
    u16* op = out + (size_t)node * D + ch * 16;
    *reinterpret_cast<u16x8*>(op) = o0;
    *reinterpret_cast<u16x8*>(op + 8) = o1;
  }
}

// ---------------- fused dual GEMM via MFMA; bf16 + fp8 outputs --------------
__global__ __launch_bounds__(256) void k_gemm_mfma(
    const u16* __restrict__ A, const u16* __restrict__ B,
    const u16* __restrict__ Wt1, const u16* __restrict__ Wt2,
    const float* __restrict__ bias, u16* __restrict__ Cout,
    u8* __restrict__ Cq)
{
  __shared__ u16 wlds[128 * WSTRIDE];
  const int t = threadIdx.x;
  const int wid = t >> 6, lane = t & 63;
  const int l15 = lane & 15, g = lane >> 4;
  const int rbase = blockIdx.x * 128 + wid * 32;

  int r0 = rbase + l15, r1 = r0 + 16;
  size_t a0 = (size_t)(r0 < NN ? r0 : NN - 1) * D + g * 8;
  size_t a1 = (size_t)(r1 < NN ? r1 : NN - 1) * D + g * 8;

  f32x4 acc0[8] = {}, acc1[8] = {};

  #pragma unroll
  for (int phase = 0; phase < 2; ++phase) {
    const u16* Act = phase ? B : A;
    const u16* Wt  = phase ? Wt2 : Wt1;
    #pragma unroll
    for (int q = 0; q < 8; ++q) {
      int i = q * 256 + t;
      int n = i >> 4, kc = i & 15;
      *reinterpret_cast<u16x8*>(&wlds[n * WSTRIDE + kc * 8]) =
          *reinterpret_cast<const u16x8*>(&Wt[n * D + kc * 8]);
    }
    __syncthreads();
    #pragma unroll
    for (int kb = 0; kb < 4; ++kb) {
      bf16x8 af0 = *reinterpret_cast<const bf16x8*>(&Act[a0 + kb * 32]);
      bf16x8 af1 = *reinterpret_cast<const bf16x8*>(&Act[a1 + kb * 32]);
      #pragma unroll
      for (int c = 0; c < 8; ++c) {
        bf16x8 wf = *reinterpret_cast<const bf16x8*>(
            &wlds[(c * 16 + l15) * WSTRIDE + kb * 32 + g * 8]);
        acc0[c] = __builtin_amdgcn_mfma_f32_16x16x32_bf16(af0, wf, acc0[c], 0, 0, 0);
        acc1[c] = __builtin_amdgcn_mfma_f32_16x16x32_bf16(af1, wf, acc1[c], 0, 0, 0);
      }
    }
    __syncthreads();
  }

  #pragma unroll
  for (int c = 0; c < 8; ++c) {
    float bv = bias[c * 16 + l15];
    #pragma unroll
    for (int r = 0; r < 4; ++r) {
      int row0 = rbase + g * 4 + r;
      if (row0 < NN) {
        float v = fmaxf(acc0[c][r] + bv, 0.f);
        Cout[(size_t)row0 * D + c * 16 + l15] = f2b(v);
        Cq[(size_t)row0 * D + c * 16 + l15] =
            (u8)((u32)__builtin_amdgcn_cvt_pk_fp8_f32(v, v, 0, false) & 0xffu);
      }
      int row1 = row0 + 16;
      if (row1 < NN) {
        float v = fmaxf(acc1[c][r] + bv, 0.f);
        Cout[(size_t)row1 * D + c * 16 + l15] = f2b(v);
        Cq[(size_t)row1 * D + c * 16 + l15] =
            (u8)((u32)__builtin_amdgcn_cvt_pk_fp8_f32(v, v, 0, false) & 0xffu);
      }
    }
  }
}

// ---------------- layer-2 GEMM (LDS weights) + fused layer-3 projection -----
__global__ __launch_bounds__(256) void k_gemm2_zr(
    const u16* __restrict__ A, const u16* __restrict__ B,
    const u16* __restrict__ Wt1, const u16* __restrict__ Wt2,
    const float* __restrict__ bias,
    const float* __restrict__ Wl3, const float* __restrict__ Wr3,
    const float* __restrict__ b3,
    float* __restrict__ z, float* __restrict__ r)
{
  __shared__ u16 wlds[128 * WSTRIDE];
  const int t = threadIdx.x;
  const int wid = t >> 6, lane = t & 63;
  const int l15 = lane & 15, g = lane >> 4;
  const int rbase = blockIdx.x * 128 + wid * 32;

  int r0 = rbase + l15, r1 = r0 + 16;
  size_t a0 = (size_t)(r0 < NN ? r0 : NN - 1) * D + g * 8;
  size_t a1 = (size_t)(r1 < NN ? r1 : NN - 1) * D + g * 8;

  f32x4 acc0[8] = {}, acc1[8] = {};

  #pragma unroll
  for (int phase = 0; phase < 2; ++phase) {
    const u16* Act = phase ? B : A;
    const u16* Wt  = phase ? Wt2 : Wt1;
    #pragma unroll
    for (int q = 0; q < 8; ++q) {
      int i = q * 256 + t;
      int n = i >> 4, kc = i & 15;
      *reinterpret_cast<u16x8*>(&wlds[n * WSTRIDE + kc * 8]) =
          *reinterpret_cast<const u16x8*>(&Wt[n * D + kc * 8]);
    }
    __syncthreads();
    #pragma unroll
    for (int kb = 0; kb < 4; ++kb) {
      bf16x8 af0 = *reinterpret_cast<const bf16x8*>(&Act[a0 + kb * 32]);
      bf16x8 af1 = *reinterpret_cast<const bf16x8*>(&Act[a1 + kb * 32]);
      #pragma unroll
      for (int c = 0; c < 8; ++c) {
        bf16x8 wf = *reinterpret_cast<const bf16x8*>(
            &wlds[(c * 16 + l15) * WSTRIDE + kb * 32 + g * 8]);
        acc0[c] = __builtin_amdgcn_mfma_f32_16x16x32_bf16(af0, wf, acc0[c], 0, 0, 0);
        acc1[c] = __builtin_amdgcn_mfma_f32_16x16x32_bf16(af1, wf, acc1[c], 0, 0, 0);
      }
    }
    __syncthreads();
  }

  float wl[8], wr[8], bv[8];
  #pragma unroll
  for (int c = 0; c < 8; ++c) {
    wl[c] = Wl3[c * 16 + l15];
    wr[c] = Wr3[c * 16 + l15];
    bv[c] = bias[c * 16 + l15];
  }
  float bb3 = b3[0];
  #pragma unroll
  for (int rf = 0; rf < 2; ++rf) {
    #pragma unroll
    for (int rr = 0; rr < 4; ++rr) {
      float pz = 0.f, pr = 0.f;
      #pragma unroll
      for (int c = 0; c < 8; ++c) {
        float v = fmaxf((rf ? acc1[c][rr] : acc0[c][rr]) + bv[c], 0.f);
        pz += v * wl[c];
        pr += v * wr[c];
      }
      pz += __shfl_xor(pz, 1, 64); pr += __shfl_xor(pr, 1, 64);
      pz += __shfl_xor(pz, 2, 64); pr += __shfl_xor(pr, 2, 64);
      pz += __shfl_xor(pz, 4, 64); pr += __shfl_xor(pr, 4, 64);
      pz += __shfl_xor(pz, 8, 64); pr += __shfl_xor(pr, 8, 64);
      int row = rbase + rf * 16 + g * 4 + rr;
      if (l15 == 0 && row < NN) {
        z[row] = pz;
        r[row] = pr + bb3;
      }
    }
  }
}

// ---------------- final: out = r + mean(z over neighbors), 16 lanes/node ----
__global__ __launch_bounds__(256) void k_out(const float* __restrict__ z,
    const float* __restrict__ r, const int* __restrict__ rowstart,
    const int* __restrict__ col, float* __restrict__ out) {
  int t = threadIdx.x;
  int sub = t & 15;
  int node = blockIdx.x * 16 + (t >> 4);
  if (node >= NN) return;
  int b = rowstart[node], e = rowstart[node + 1];
  float s = 0.f;
  for (int j = b + sub; j < e; j += 16) s += z[col[j]];
  s += __shfl_xor(s, 1, 64);
  s += __shfl_xor(s, 2, 64);
  s += __shfl_xor(s, 4, 64);
  s += __shfl_xor(s, 8, 64);
  if (sub == 0) {
    float inv = (e > b) ? 1.f / (float)(e - b) : 0.f;
    out[node] = r[node] + s * inv;
  }
}

extern "C" void kernel_launch(void* const* d_in, const int* in_sizes, int n_in,
                              void* d_out, int out_size, void* d_ws, size_t ws_size,
                              hipStream_t stream) {
  const float* x   = (const float*)d_in[0];
  const int*   ei  = (const int*)d_in[1];
  const float* Wl1 = (const float*)d_in[2];
  const float* Wr1 = (const float*)d_in[3];
  const float* b1  = (const float*)d_in[4];
  const float* Wl2 = (const float*)d_in[5];
  const float* Wr2 = (const float*)d_in[6];
  const float* b2  = (const float*)d_in[7];
  const float* Wl3 = (const float*)d_in[8];
  const float* Wr3 = (const float*)d_in[9];
  const float* b3  = (const float*)d_in[10];
  const int* srcv = ei;
  const int* dstv = ei + NE;
  float* out = (float*)d_out;

  char* ws = (char*)d_ws;
  size_t off = 0;
  auto alloc = [&](size_t bytes) {
    size_t o = off;
    off += (bytes + 255) & ~(size_t)255;
    return o;
  };
  int* deg      = (int*)(ws + alloc((size_t)NN * 4));
  int* rowstart = (int*)(ws + alloc((size_t)(NN + 1) * 4));
  int* col      = (int*)(ws + alloc((size_t)NE * 4));
  int* hw       = (int*)(ws + alloc((size_t)NGRP * NWAVES * 4));
  u32* bkt  = (u32*)(ws + alloc((size_t)NE * 4));
  u16* ncnt = (u16*)(ws + alloc((size_t)NGRP * NSUB * GSZ * 2));
  u16* xb   = (u16*)(ws + alloc((size_t)NN * D * 2));
  u8*  xq   = (u8*)(ws + alloc((size_t)NN * D));
  u16* Ab   = (u16*)(ws + alloc((size_t)NN * D * 2));
  u16* H1b  = (u16*)(ws + alloc((size_t)NN * D * 2));
  u8*  H1q  = (u8*)(ws + alloc((size_t)NN * D));
  u16* Wt1l = (u16*)(ws + alloc((size_t)D * D * 2));
  u16* Wt1r = (u16*)(ws + alloc((size_t)D * D * 2));
  u16* Wt2l = (u16*)(ws + alloc((size_t)D * D * 2));
  u16* Wt2r = (u16*)(ws + alloc((size_t)D * D * 2));
  float* z  = (float*)(ws + alloc((size_t)NN * 4));
  float* r  = (float*)(ws + alloc((size_t)NN * 4));

  const int nb_gemm  = (NN + 127) / 128;       // 782
  const int nb_agg   = (NN + 3) / 4;           // 25000
  const int nb_out   = (NN + 15) / 16;         // 6250
  const int nb_sub   = NGRP * NSUB;            // 256
  const int nb_nscan = NGRP * ((GSZ + 255) / 256);  // 8*49

  // atomic-free CSR build (+ x->bf16 + x->fp8 fused into hist pass)
  k_hist8<<<NBLK, 256, 0, stream>>>(dstv, hw, x, xb, xq);
  k_hscan<<<1, 256, 0, stream>>>(hw, NGRP * NWAVES);
  k_part2<<<NBLK, 256, 0, stream>>>(srcv, dstv, hw, bkt);
  k_nhist<<<nb_sub, 256, 0, stream>>>(bkt, hw, ncnt);
  k_nscan<<<nb_nscan, 256, 0, stream>>>(ncnt, deg);
  k_gscan<<<NGRP, 256, 0, stream>>>(deg, hw, rowstart);
  k_scatter2<<<nb_sub, 256, 0, stream>>>(bkt, hw, ncnt, rowstart, col);

  // weight prep (transposed bf16)
  k_cvt_wt4<<<dim3(D, 4), D, 0, stream>>>(Wl1, Wr1, Wl2, Wr2, Wt1l, Wt1r, Wt2l, Wt2r);

  // layer 1: gather fp8 x, GEMM in bf16; emit H1 in bf16 + fp8
  k_agg_q<<<nb_agg, 256, 0, stream>>>(xq, rowstart, col, Ab);
  k_gemm_mfma<<<nb_gemm, 256, 0, stream>>>(Ab, xb, Wt1l, Wt1r, b1, H1b, H1q);
  // layer 2 + fused layer-3 projection: gather fp8 H1
  k_agg_q<<<nb_agg, 256, 0, stream>>>(H1q, rowstart, col, Ab);
  k_gemm2_zr<<<nb_gemm, 256, 0, stream>>>(Ab, H1b, Wt2l, Wt2r, b2, Wl3, Wr3, b3, z, r);
  // final
  k_out<<<nb_out, 256, 0, stream>>>(z, r, rowstart, col, out);
}

// Round 14
// 292.064 us; speedup vs baseline: 1.4072x; 1.1316x over previous
//
#include <hip/hip_runtime.h>
#include <hip/hip_bf16.h>

#define NN 100000
#define NE 1600000
#define D 128
#define NGRP 8
#define GSZ (NN / NGRP)          // 12500, exact
#define EPT 8                    // edges per thread in hist8/part2
#define NBLK ((NE + 2047) / 2048)   // 782 blocks for hist8/part2
#define NWAVES (NBLK * 4)        // 3128 waves
#define NSUB 32                  // sub-blocks per group in nhist/scatter2
#define WSTRIDE 136              // LDS row stride (u16): 272B -> conflict-free b128

typedef unsigned short u16;
typedef unsigned int u32;
typedef unsigned long long u64;
typedef unsigned char u8;
typedef __attribute__((ext_vector_type(8))) short bf16x8;
typedef __attribute__((ext_vector_type(4))) float f32x4;
typedef __attribute__((ext_vector_type(2))) float f32x2;
typedef __attribute__((ext_vector_type(8))) u16 u16x8;
typedef __attribute__((ext_vector_type(4))) u32 u32x4;
typedef __attribute__((ext_vector_type(2))) u32 u32x2;

__device__ inline u16 f2b(float f) {
  union { float f; u32 u; } v; v.f = f;
  u32 u = v.u;
  return (u16)((u + 0x7fffu + ((u >> 16) & 1u)) >> 16);
}
__device__ inline float b2f(u16 h) {
  union { u32 u; float f; } v; v.u = ((u32)h) << 16; return v.f;
}
// accumulate 16 fp8 (one u32x4) into 16 f32 accumulators via HW packed cvt
__device__ inline void acc16(float* a, u32x4 v) {
  #pragma unroll
  for (int w = 0; w < 4; ++w) {
    f32x2 lo = __builtin_amdgcn_cvt_pk_f32_fp8(v[w], false);
    f32x2 hi = __builtin_amdgcn_cvt_pk_f32_fp8(v[w], true);
    a[w * 4 + 0] += lo[0]; a[w * 4 + 1] += lo[1];
    a[w * 4 + 2] += hi[0]; a[w * 4 + 3] += hi[1];
  }
}

// ---------------- hist + x->bf16 + x->fp8 convert (1.6M-element streams) ----
__global__ __launch_bounds__(256) void k_hist8(const int* __restrict__ dst,
    int* __restrict__ hw, const float* __restrict__ xin, u16* __restrict__ xb,
    u8* __restrict__ xq) {
  const int t = threadIdx.x, lane = t & 63, wid = t >> 6;
  const int eb = blockIdx.x * (256 * EPT);
  const int wv = blockIdx.x * 4 + wid;
  int c0=0,c1=0,c2=0,c3=0,c4=0,c5=0,c6=0,c7=0;
  #pragma unroll
  for (int r = 0; r < EPT; ++r) {
    int e = eb + r * 256 + t;
    bool v = e < NE;
    int q = v ? __builtin_nontemporal_load(&dst[e]) / GSZ : 8;
    c0 += __popcll(__ballot(q == 0)); c1 += __popcll(__ballot(q == 1));
    c2 += __popcll(__ballot(q == 2)); c3 += __popcll(__ballot(q == 3));
    c4 += __popcll(__ballot(q == 4)); c5 += __popcll(__ballot(q == 5));
    c6 += __popcll(__ballot(q == 6)); c7 += __popcll(__ballot(q == 7));
    if (v) {
      const f32x4* p = reinterpret_cast<const f32x4*>(xin) + (size_t)e * 2;
      f32x4 a = __builtin_nontemporal_load(p);
      f32x4 b = __builtin_nontemporal_load(p + 1);
      u16x8 o;
      o[0] = f2b(a[0]); o[1] = f2b(a[1]); o[2] = f2b(a[2]); o[3] = f2b(a[3]);
      o[4] = f2b(b[0]); o[5] = f2b(b[1]); o[6] = f2b(b[2]); o[7] = f2b(b[3]);
      __builtin_nontemporal_store(o, reinterpret_cast<u16x8*>(xb + (size_t)e * 8));
      int qlo = __builtin_amdgcn_cvt_pk_fp8_f32(a[0], a[1], 0, false);
      qlo = __builtin_amdgcn_cvt_pk_fp8_f32(a[2], a[3], qlo, true);
      int qhi = __builtin_amdgcn_cvt_pk_fp8_f32(b[0], b[1], 0, false);
      qhi = __builtin_amdgcn_cvt_pk_fp8_f32(b[2], b[3], qhi, true);
      u32x2 qo; qo[0] = (u32)qlo; qo[1] = (u32)qhi;
      __builtin_nontemporal_store(qo, reinterpret_cast<u32x2*>(xq + (size_t)e * 8));
    }
  }
  if (lane == 0) {
    hw[0 * NWAVES + wv] = c0; hw[1 * NWAVES + wv] = c1;
    hw[2 * NWAVES + wv] = c2; hw[3 * NWAVES + wv] = c3;
    hw[4 * NWAVES + wv] = c4; hw[5 * NWAVES + wv] = c5;
    hw[6 * NWAVES + wv] = c6; hw[7 * NWAVES + wv] = c7;
  }
}

// ---------------- single-block exclusive scan (in place) --------------------
__global__ void k_hscan(int* __restrict__ a, int n) {
  __shared__ int s[256];
  int t = threadIdx.x;
  int per = (n + 255) / 256;
  int lo = t * per, hi = lo + per; if (hi > n) hi = n;
  int sum = 0;
  for (int i = lo; i < hi; ++i) sum += a[i];
  s[t] = sum; __syncthreads();
  for (int off = 1; off < 256; off <<= 1) {
    int u = (t >= off) ? s[t - off] : 0;
    __syncthreads(); s[t] += u; __syncthreads();
  }
  int run = s[t] - sum;
  for (int i = lo; i < hi; ++i) { int v = a[i]; a[i] = run; run += v; }
}

// ---------------- deterministic bucket write (ballot ranks, no atomics) -----
__global__ __launch_bounds__(256) void k_part2(const int* __restrict__ src,
    const int* __restrict__ dst, const int* __restrict__ hw,
    u32* __restrict__ bkt) {
  const int t = threadIdx.x, lane = t & 63, wid = t >> 6;
  const int eb = blockIdx.x * (256 * EPT);
  const int wv = blockIdx.x * 4 + wid;
  int q[EPT]; u32 pk[EPT];
  #pragma unroll
  for (int r = 0; r < EPT; ++r) {
    int e = eb + r * 256 + t;
    bool v = e < NE;
    int d = v ? __builtin_nontemporal_load(&dst[e]) : 0;
    int s = v ? __builtin_nontemporal_load(&src[e]) : 0;
    q[r] = v ? d / GSZ : 8;
    pk[r] = v ? (((u32)(d - q[r] * GSZ) << 17) | (u32)s) : 0;
  }
  u64 below = (lane == 63) ? 0x7fffffffffffffffull : ((1ull << lane) - 1);
  int base[NGRP];
  #pragma unroll
  for (int b = 0; b < NGRP; ++b) base[b] = hw[b * NWAVES + wv];
  #pragma unroll
  for (int b = 0; b < NGRP; ++b) {
    int run = 0;
    #pragma unroll
    for (int r = 0; r < EPT; ++r) {
      u64 m = __ballot(q[r] == b);
      if (q[r] == b) {
        int pos = base[b] + run + __popcll(m & below);
        if (pos < NE)
          bkt[pos] = pk[r];
      }
      run += __popcll(m);
    }
  }
}

// ---------------- per-sub-block node histogram in LDS -----------------------
__global__ __launch_bounds__(256) void k_nhist(const u32* __restrict__ bkt,
    const int* __restrict__ hw, u16* __restrict__ ncnt) {
  __shared__ int h[GSZ];
  const int g = blockIdx.x & (NGRP - 1);
  const int sub = blockIdx.x >> 3;
  const int t = threadIdx.x;
  const int start = hw[g * NWAVES];
  const int end = (g < NGRP - 1) ? hw[(g + 1) * NWAVES] : NE;
  const int cnt = end - start;
  const int chunk = (cnt + NSUB - 1) / NSUB;
  int lo = start + sub * chunk;
  int hi = lo + chunk; if (hi > end) hi = end;
  for (int i = t; i < GSZ; i += 256) h[i] = 0;
  __syncthreads();
  for (int i = lo + t; i < hi; i += 256) {
    int dl = (int)(__builtin_nontemporal_load(&bkt[i]) >> 17);
    atomicAdd(&h[dl], 1);
  }
  __syncthreads();
  u16* outp = ncnt + ((size_t)g * NSUB + sub) * GSZ;
  for (int i = t; i < GSZ; i += 256) outp[i] = (u16)h[i];
}

// ---------------- per-node scan over sub-blocks -> offsets + deg ------------
__global__ __launch_bounds__(256) void k_nscan(u16* __restrict__ ncnt,
    int* __restrict__ deg) {
  const int g = blockIdx.x & (NGRP - 1);
  const int seg = blockIdx.x >> 3;
  int d = seg * 256 + threadIdx.x;
  if (d >= GSZ) return;
  int run = 0;
  #pragma unroll
  for (int s = 0; s < NSUB; ++s) {
    size_t idx = ((size_t)g * NSUB + s) * GSZ + d;
    int v = ncnt[idx];
    ncnt[idx] = (u16)run;
    run += v;
  }
  deg[g * GSZ + d] = run;
}

// ---------------- per-group rowstart: bucket base + local scan --------------
__global__ void k_gscan(const int* __restrict__ deg, const int* __restrict__ hw,
                        int* __restrict__ rowstart) {
  __shared__ int s[256];
  const int g = blockIdx.x;
  const int t = threadIdx.x;
  const int base = hw[g * NWAVES];
  const int per = (GSZ + 255) / 256;       // 49
  int lo = t * per, hi = lo + per; if (hi > GSZ) hi = GSZ;
  int sum = 0;
  for (int i = lo; i < hi; ++i) sum += deg[g * GSZ + i];
  s[t] = sum; __syncthreads();
  for (int off = 1; off < 256; off <<= 1) {
    int u = (t >= off) ? s[t - off] : 0;
    __syncthreads(); s[t] += u; __syncthreads();
  }
  int run = base + s[t] - sum;
  for (int i = lo; i < hi; ++i) {
    int v = deg[g * GSZ + i];
    rowstart[g * GSZ + i] = run;
    run += v;
  }
  if (g == NGRP - 1 && t == 255) rowstart[NN] = NE;
}

// ---------------- scatter: LDS cursors, XCD-resident col slice --------------
__global__ __launch_bounds__(256) void k_scatter2(const u32* __restrict__ bkt,
    const int* __restrict__ hw, const u16* __restrict__ ncnt,
    const int* __restrict__ rowstart, int* __restrict__ col) {
  __shared__ int cur[GSZ];
  const int g = blockIdx.x & (NGRP - 1);
  const int sub = blockIdx.x >> 3;
  const int t = threadIdx.x;
  const int start = hw[g * NWAVES];
  const int end = (g < NGRP - 1) ? hw[(g + 1) * NWAVES] : NE;
  const int cnt = end - start;
  const int chunk = (cnt + NSUB - 1) / NSUB;
  int lo = start + sub * chunk;
  int hi = lo + chunk; if (hi > end) hi = end;
  const u16* nof = ncnt + ((size_t)g * NSUB + sub) * GSZ;
  for (int i = t; i < GSZ; i += 256)
    cur[i] = rowstart[g * GSZ + i] + (int)nof[i];
  __syncthreads();
  for (int i = lo + t; i < hi; i += 256) {
    u32 v = __builtin_nontemporal_load(&bkt[i]);
    int dl = (int)(v >> 17), s = (int)(v & 0x1ffffu);
    int pos = atomicAdd(&cur[dl], 1);
    col[pos] = s;
  }
}

// ---------------- W (k-major [k][n]) -> Wt (n-major [n][k]) bf16, 4 mats ----
__global__ void k_cvt_wt4(const float* __restrict__ W0, const float* __restrict__ W1,
                          const float* __restrict__ W2, const float* __restrict__ W3,
                          u16* __restrict__ T0, u16* __restrict__ T1,
                          u16* __restrict__ T2, u16* __restrict__ T3) {
  const float* W = blockIdx.y == 0 ? W0 : blockIdx.y == 1 ? W1 : blockIdx.y == 2 ? W2 : W3;
  u16* T = blockIdx.y == 0 ? T0 : blockIdx.y == 1 ? T1 : blockIdx.y == 2 ? T2 : T3;
  int n = blockIdx.x, k = threadIdx.x;
  T[n * D + k] = f2b(W[k * D + n]);
}

// ---------------- fp8 mean aggregation: 8-lane group per node ---------------
// fp8 row = 128B = 8 lanes x 16B -> a group gathers a FULL row per load.
// 8 groups/wave, each walking its own edge list with 2-deep unroll ->
// 16 outstanding 128B gathers per wave (8x R13's 2). No shuffles, no slot
// tails; divergence cost = max(deg over 8 groups) ~ 22 vs mean 16.
__global__ __launch_bounds__(256) void k_agg_q(const u8* __restrict__ feat,
    const int* __restrict__ rowstart, const int* __restrict__ col,
    u16* __restrict__ out) {
  int t = threadIdx.x;
  int node = blockIdx.x * 32 + (t >> 3);   // 32 nodes per block
  if (node >= NN) return;
  int ln = t & 7;                          // lane in group: 16B feature chunk
  int b = rowstart[node], e = rowstart[node + 1];
  const u8* fp = feat + ln * 16;
  float a[16] = {};
  int j = b;
  for (; j + 1 < e; j += 2) {              // 2 rows in flight per group
    int s0 = col[j], s1 = col[j + 1];
    u32x4 v0 = *reinterpret_cast<const u32x4*>(fp + (size_t)s0 * D);
    u32x4 v1 = *reinterpret_cast<const u32x4*>(fp + (size_t)s1 * D);
    acc16(a, v0); acc16(a, v1);
  }
  if (j < e) {
    int s0 = col[j];
    u32x4 v0 = *reinterpret_cast<const u32x4*>(fp + (size_t)s0 * D);
    acc16(a, v0);
  }
  float inv = (e > b) ? 1.f / (float)(e - b) : 0.f;
  u16x8 o0, o1;
  #pragma unroll
  for (int k = 0; k < 8; ++k) {
    o0[k] = f2b(a[k] * inv);
    o1[k] = f2b(a[8 + k] * inv);
  }
  u16* op = out + (size_t)node * D + ln * 16;
  *reinterpret_cast<u16x8*>(op) = o0;
  *reinterpret_cast<u16x8*>(op + 8) = o1;
}

// ---------------- fused dual GEMM via MFMA; bf16 + fp8 outputs --------------
__global__ __launch_bounds__(256) void k_gemm_mfma(
    const u16* __restrict__ A, const u16* __restrict__ B,
    const u16* __restrict__ Wt1, const u16* __restrict__ Wt2,
    const float* __restrict__ bias, u16* __restrict__ Cout,
    u8* __restrict__ Cq)
{
  __shared__ u16 wlds[128 * WSTRIDE];
  const int t = threadIdx.x;
  const int wid = t >> 6, lane = t & 63;
  const int l15 = lane & 15, g = lane >> 4;
  const int rbase = blockIdx.x * 128 + wid * 32;

  int r0 = rbase + l15, r1 = r0 + 16;
  size_t a0 = (size_t)(r0 < NN ? r0 : NN - 1) * D + g * 8;
  size_t a1 = (size_t)(r1 < NN ? r1 : NN - 1) * D + g * 8;

  f32x4 acc0[8] = {}, acc1[8] = {};

  #pragma unroll
  for (int phase = 0; phase < 2; ++phase) {
    const u16* Act = phase ? B : A;
    const u16* Wt  = phase ? Wt2 : Wt1;
    #pragma unroll
    for (int q = 0; q < 8; ++q) {
      int i = q * 256 + t;
      int n = i >> 4, kc = i & 15;
      *reinterpret_cast<u16x8*>(&wlds[n * WSTRIDE + kc * 8]) =
          *reinterpret_cast<const u16x8*>(&Wt[n * D + kc * 8]);
    }
    __syncthreads();
    #pragma unroll
    for (int kb = 0; kb < 4; ++kb) {
      bf16x8 af0 = *reinterpret_cast<const bf16x8*>(&Act[a0 + kb * 32]);
      bf16x8 af1 = *reinterpret_cast<const bf16x8*>(&Act[a1 + kb * 32]);
      #pragma unroll
      for (int c = 0; c < 8; ++c) {
        bf16x8 wf = *reinterpret_cast<const bf16x8*>(
            &wlds[(c * 16 + l15) * WSTRIDE + kb * 32 + g * 8]);
        acc0[c] = __builtin_amdgcn_mfma_f32_16x16x32_bf16(af0, wf, acc0[c], 0, 0, 0);
        acc1[c] = __builtin_amdgcn_mfma_f32_16x16x32_bf16(af1, wf, acc1[c], 0, 0, 0);
      }
    }
    __syncthreads();
  }

  #pragma unroll
  for (int c = 0; c < 8; ++c) {
    float bv = bias[c * 16 + l15];
    #pragma unroll
    for (int r = 0; r < 4; ++r) {
      int row0 = rbase + g * 4 + r;
      if (row0 < NN) {
        float v = fmaxf(acc0[c][r] + bv, 0.f);
        Cout[(size_t)row0 * D + c * 16 + l15] = f2b(v);
        Cq[(size_t)row0 * D + c * 16 + l15] =
            (u8)((u32)__builtin_amdgcn_cvt_pk_fp8_f32(v, v, 0, false) & 0xffu);
      }
      int row1 = row0 + 16;
      if (row1 < NN) {
        float v = fmaxf(acc1[c][r] + bv, 0.f);
        Cout[(size_t)row1 * D + c * 16 + l15] = f2b(v);
        Cq[(size_t)row1 * D + c * 16 + l15] =
            (u8)((u32)__builtin_amdgcn_cvt_pk_fp8_f32(v, v, 0, false) & 0xffu);
      }
    }
  }
}

// ---------------- layer-2 GEMM (LDS weights) + fused layer-3 projection -----
__global__ __launch_bounds__(256) void k_gemm2_zr(
    const u16* __restrict__ A, const u16* __restrict__ B,
    const u16* __restrict__ Wt1, const u16* __restrict__ Wt2,
    const float* __restrict__ bias,
    const float* __restrict__ Wl3, const float* __restrict__ Wr3,
    const float* __restrict__ b3,
    float* __restrict__ z, float* __restrict__ r)
{
  __shared__ u16 wlds[128 * WSTRIDE];
  const int t = threadIdx.x;
  const int wid = t >> 6, lane = t & 63;
  const int l15 = lane & 15, g = lane >> 4;
  const int rbase = blockIdx.x * 128 + wid * 32;

  int r0 = rbase + l15, r1 = r0 + 16;
  size_t a0 = (size_t)(r0 < NN ? r0 : NN - 1) * D + g * 8;
  size_t a1 = (size_t)(r1 < NN ? r1 : NN - 1) * D + g * 8;

  f32x4 acc0[8] = {}, acc1[8] = {};

  #pragma unroll
  for (int phase = 0; phase < 2; ++phase) {
    const u16* Act = phase ? B : A;
    const u16* Wt  = phase ? Wt2 : Wt1;
    #pragma unroll
    for (int q = 0; q < 8; ++q) {
      int i = q * 256 + t;
      int n = i >> 4, kc = i & 15;
      *reinterpret_cast<u16x8*>(&wlds[n * WSTRIDE + kc * 8]) =
          *reinterpret_cast<const u16x8*>(&Wt[n * D + kc * 8]);
    }
    __syncthreads();
    #pragma unroll
    for (int kb = 0; kb < 4; ++kb) {
      bf16x8 af0 = *reinterpret_cast<const bf16x8*>(&Act[a0 + kb * 32]);
      bf16x8 af1 = *reinterpret_cast<const bf16x8*>(&Act[a1 + kb * 32]);
      #pragma unroll
      for (int c = 0; c < 8; ++c) {
        bf16x8 wf = *reinterpret_cast<const bf16x8*>(
            &wlds[(c * 16 + l15) * WSTRIDE + kb * 32 + g * 8]);
        acc0[c] = __builtin_amdgcn_mfma_f32_16x16x32_bf16(af0, wf, acc0[c], 0, 0, 0);
        acc1[c] = __builtin_amdgcn_mfma_f32_16x16x32_bf16(af1, wf, acc1[c], 0, 0, 0);
      }
    }
    __syncthreads();
  }

  float wl[8], wr[8], bv[8];
  #pragma unroll
  for (int c = 0; c < 8; ++c) {
    wl[c] = Wl3[c * 16 + l15];
    wr[c] = Wr3[c * 16 + l15];
    bv[c] = bias[c * 16 + l15];
  }
  float bb3 = b3[0];
  #pragma unroll
  for (int rf = 0; rf < 2; ++rf) {
    #pragma unroll
    for (int rr = 0; rr < 4; ++rr) {
      float pz = 0.f, pr = 0.f;
      #pragma unroll
      for (int c = 0; c < 8; ++c) {
        float v = fmaxf((rf ? acc1[c][rr] : acc0[c][rr]) + bv[c], 0.f);
        pz += v * wl[c];
        pr += v * wr[c];
      }
      pz += __shfl_xor(pz, 1, 64); pr += __shfl_xor(pr, 1, 64);
      pz += __shfl_xor(pz, 2, 64); pr += __shfl_xor(pr, 2, 64);
      pz += __shfl_xor(pz, 4, 64); pr += __shfl_xor(pr, 4, 64);
      pz += __shfl_xor(pz, 8, 64); pr += __shfl_xor(pr, 8, 64);
      int row = rbase + rf * 16 + g * 4 + rr;
      if (l15 == 0 && row < NN) {
        z[row] = pz;
        r[row] = pr + bb3;
      }
    }
  }
}

// ---------------- final: out = r + mean(z over neighbors), 16 lanes/node ----
__global__ __launch_bounds__(256) void k_out(const float* __restrict__ z,
    const float* __restrict__ r, const int* __restrict__ rowstart,
    const int* __restrict__ col, float* __restrict__ out) {
  int t = threadIdx.x;
  int sub = t & 15;
  int node = blockIdx.x * 16 + (t >> 4);
  if (node >= NN) return;
  int b = rowstart[node], e = rowstart[node + 1];
  float s = 0.f;
  for (int j = b + sub; j < e; j += 16) s += z[col[j]];
  s += __shfl_xor(s, 1, 64);
  s += __shfl_xor(s, 2, 64);
  s += __shfl_xor(s, 4, 64);
  s += __shfl_xor(s, 8, 64);
  if (sub == 0) {
    float inv = (e > b) ? 1.f / (float)(e - b) : 0.f;
    out[node] = r[node] + s * inv;
  }
}

extern "C" void kernel_launch(void* const* d_in, const int* in_sizes, int n_in,
                              void* d_out, int out_size, void* d_ws, size_t ws_size,
                              hipStream_t stream) {
  const float* x   = (const float*)d_in[0];
  const int*   ei  = (const int*)d_in[1];
  const float* Wl1 = (const float*)d_in[2];
  const float* Wr1 = (const float*)d_in[3];
  const float* b1  = (const float*)d_in[4];
  const float* Wl2 = (const float*)d_in[5];
  const float* Wr2 = (const float*)d_in[6];
  const float* b2  = (const float*)d_in[7];
  const float* Wl3 = (const float*)d_in[8];
  const float* Wr3 = (const float*)d_in[9];
  const float* b3  = (const float*)d_in[10];
  const int* srcv = ei;
  const int* dstv = ei + NE;
  float* out = (float*)d_out;

  char* ws = (char*)d_ws;
  size_t off = 0;
  auto alloc = [&](size_t bytes) {
    size_t o = off;
    off += (bytes + 255) & ~(size_t)255;
    return o;
  };
  int* deg      = (int*)(ws + alloc((size_t)NN * 4));
  int* rowstart = (int*)(ws + alloc((size_t)(NN + 1) * 4));
  int* col      = (int*)(ws + alloc((size_t)NE * 4));
  int* hw       = (int*)(ws + alloc((size_t)NGRP * NWAVES * 4));
  u32* bkt  = (u32*)(ws + alloc((size_t)NE * 4));
  u16* ncnt = (u16*)(ws + alloc((size_t)NGRP * NSUB * GSZ * 2));
  u16* xb   = (u16*)(ws + alloc((size_t)NN * D * 2));
  u8*  xq   = (u8*)(ws + alloc((size_t)NN * D));
  u16* Ab   = (u16*)(ws + alloc((size_t)NN * D * 2));
  u16* H1b  = (u16*)(ws + alloc((size_t)NN * D * 2));
  u8*  H1q  = (u8*)(ws + alloc((size_t)NN * D));
  u16* Wt1l = (u16*)(ws + alloc((size_t)D * D * 2));
  u16* Wt1r = (u16*)(ws + alloc((size_t)D * D * 2));
  u16* Wt2l = (u16*)(ws + alloc((size_t)D * D * 2));
  u16* Wt2r = (u16*)(ws + alloc((size_t)D * D * 2));
  float* z  = (float*)(ws + alloc((size_t)NN * 4));
  float* r  = (float*)(ws + alloc((size_t)NN * 4));

  const int nb_gemm  = (NN + 127) / 128;       // 782
  const int nb_agg   = (NN + 31) / 32;         // 3125
  const int nb_out   = (NN + 15) / 16;         // 6250
  const int nb_sub   = NGRP * NSUB;            // 256
  const int nb_nscan = NGRP * ((GSZ + 255) / 256);  // 8*49

  // atomic-free CSR build (+ x->bf16 + x->fp8 fused into hist pass)
  k_hist8<<<NBLK, 256, 0, stream>>>(dstv, hw, x, xb, xq);
  k_hscan<<<1, 256, 0, stream>>>(hw, NGRP * NWAVES);
  k_part2<<<NBLK, 256, 0, stream>>>(srcv, dstv, hw, bkt);
  k_nhist<<<nb_sub, 256, 0, stream>>>(bkt, hw, ncnt);
  k_nscan<<<nb_nscan, 256, 0, stream>>>(ncnt, deg);
  k_gscan<<<NGRP, 256, 0, stream>>>(deg, hw, rowstart);
  k_scatter2<<<nb_sub, 256, 0, stream>>>(bkt, hw, ncnt, rowstart, col);

  // weight prep (transposed bf16)
  k_cvt_wt4<<<dim3(D, 4), D, 0, stream>>>(Wl1, Wr1, Wl2, Wr2, Wt1l, Wt1r, Wt2l, Wt2r);

  // layer 1: gather fp8 x, GEMM in bf16; emit H1 in bf16 + fp8
  k_agg_q<<<nb_agg, 256, 0, stream>>>(xq, rowstart, col, Ab);
  k_gemm_mfma<<<nb_gemm, 256, 0, stream>>>(Ab, xb, Wt1l, Wt1r, b1, H1b, H1q);
  // layer 2 + fused layer-3 projection: gather fp8 H1
  k_agg_q<<<nb_agg, 256, 0, stream>>>(H1q, rowstart, col, Ab);
  k_gemm2_zr<<<nb_gemm, 256, 0, stream>>>(Ab, H1b, Wt2l, Wt2r, b2, Wl3, Wr3, b3, z, r);
  // final
  k_out<<<nb_out, 256, 0, stream>>>(z, r, rowstart, col, out);
}

// Round 15
// 263.110 us; speedup vs baseline: 1.5621x; 1.1100x over previous
//
#include <hip/hip_runtime.h>
#include <hip/hip_bf16.h>

#define NN 100000
#define NE 1600000
#define D 128
#define NGRP 8
#define GSZ (NN / NGRP)          // 12500, exact
#define EPT 8                    // edges per thread in hist8/part2
#define NBLK ((NE + 2047) / 2048)   // 782 blocks for hist8/part2
#define NWAVES (NBLK * 4)        // 3128 waves
#define NSUB 32                  // sub-blocks per group in nhist/scatter2
#define WSTRIDE 136              // LDS row stride (u16): 272B -> conflict-free b128

typedef unsigned short u16;
typedef unsigned int u32;
typedef unsigned long long u64;
typedef unsigned char u8;
typedef __attribute__((ext_vector_type(8))) short bf16x8;
typedef __attribute__((ext_vector_type(4))) float f32x4;
typedef __attribute__((ext_vector_type(2))) float f32x2;
typedef __attribute__((ext_vector_type(8))) u16 u16x8;
typedef __attribute__((ext_vector_type(4))) u32 u32x4;
typedef __attribute__((ext_vector_type(2))) u32 u32x2;

__device__ inline u16 f2b(float f) {
  union { float f; u32 u; } v; v.f = f;
  u32 u = v.u;
  return (u16)((u + 0x7fffu + ((u >> 16) & 1u)) >> 16);
}
__device__ inline float b2f(u16 h) {
  union { u32 u; float f; } v; v.u = ((u32)h) << 16; return v.f;
}
// accumulate 16 fp8 (one u32x4) into 16 f32 accumulators via HW packed cvt
__device__ inline void acc16(float* a, u32x4 v) {
  #pragma unroll
  for (int w = 0; w < 4; ++w) {
    f32x2 lo = __builtin_amdgcn_cvt_pk_f32_fp8(v[w], false);
    f32x2 hi = __builtin_amdgcn_cvt_pk_f32_fp8(v[w], true);
    a[w * 4 + 0] += lo[0]; a[w * 4 + 1] += lo[1];
    a[w * 4 + 2] += hi[0]; a[w * 4 + 3] += hi[1];
  }
}

// ---------------- hist + x->bf16 + x->fp8 convert (1.6M-element streams) ----
__global__ __launch_bounds__(256) void k_hist8(const int* __restrict__ dst,
    int* __restrict__ hw, const float* __restrict__ xin, u16* __restrict__ xb,
    u8* __restrict__ xq) {
  const int t = threadIdx.x, lane = t & 63, wid = t >> 6;
  const int eb = blockIdx.x * (256 * EPT);
  const int wv = blockIdx.x * 4 + wid;
  int c0=0,c1=0,c2=0,c3=0,c4=0,c5=0,c6=0,c7=0;
  #pragma unroll
  for (int r = 0; r < EPT; ++r) {
    int e = eb + r * 256 + t;
    bool v = e < NE;
    int q = v ? __builtin_nontemporal_load(&dst[e]) / GSZ : 8;
    c0 += __popcll(__ballot(q == 0)); c1 += __popcll(__ballot(q == 1));
    c2 += __popcll(__ballot(q == 2)); c3 += __popcll(__ballot(q == 3));
    c4 += __popcll(__ballot(q == 4)); c5 += __popcll(__ballot(q == 5));
    c6 += __popcll(__ballot(q == 6)); c7 += __popcll(__ballot(q == 7));
    if (v) {
      const f32x4* p = reinterpret_cast<const f32x4*>(xin) + (size_t)e * 2;
      f32x4 a = __builtin_nontemporal_load(p);
      f32x4 b = __builtin_nontemporal_load(p + 1);
      u16x8 o;
      o[0] = f2b(a[0]); o[1] = f2b(a[1]); o[2] = f2b(a[2]); o[3] = f2b(a[3]);
      o[4] = f2b(b[0]); o[5] = f2b(b[1]); o[6] = f2b(b[2]); o[7] = f2b(b[3]);
      __builtin_nontemporal_store(o, reinterpret_cast<u16x8*>(xb + (size_t)e * 8));
      int qlo = __builtin_amdgcn_cvt_pk_fp8_f32(a[0], a[1], 0, false);
      qlo = __builtin_amdgcn_cvt_pk_fp8_f32(a[2], a[3], qlo, true);
      int qhi = __builtin_amdgcn_cvt_pk_fp8_f32(b[0], b[1], 0, false);
      qhi = __builtin_amdgcn_cvt_pk_fp8_f32(b[2], b[3], qhi, true);
      u32x2 qo; qo[0] = (u32)qlo; qo[1] = (u32)qhi;
      __builtin_nontemporal_store(qo, reinterpret_cast<u32x2*>(xq + (size_t)e * 8));
    }
  }
  if (lane == 0) {
    hw[0 * NWAVES + wv] = c0; hw[1 * NWAVES + wv] = c1;
    hw[2 * NWAVES + wv] = c2; hw[3 * NWAVES + wv] = c3;
    hw[4 * NWAVES + wv] = c4; hw[5 * NWAVES + wv] = c5;
    hw[6 * NWAVES + wv] = c6; hw[7 * NWAVES + wv] = c7;
  }
}

// ---------------- single-block exclusive scan (in place) --------------------
__global__ void k_hscan(int* __restrict__ a, int n) {
  __shared__ int s[256];
  int t = threadIdx.x;
  int per = (n + 255) / 256;
  int lo = t * per, hi = lo + per; if (hi > n) hi = n;
  int sum = 0;
  for (int i = lo; i < hi; ++i) sum += a[i];
  s[t] = sum; __syncthreads();
  for (int off = 1; off < 256; off <<= 1) {
    int u = (t >= off) ? s[t - off] : 0;
    __syncthreads(); s[t] += u; __syncthreads();
  }
  int run = s[t] - sum;
  for (int i = lo; i < hi; ++i) { int v = a[i]; a[i] = run; run += v; }
}

// ---------------- deterministic bucket write (ballot ranks, no atomics) -----
__global__ __launch_bounds__(256) void k_part2(const int* __restrict__ src,
    const int* __restrict__ dst, const int* __restrict__ hw,
    u32* __restrict__ bkt) {
  const int t = threadIdx.x, lane = t & 63, wid = t >> 6;
  const int eb = blockIdx.x * (256 * EPT);
  const int wv = blockIdx.x * 4 + wid;
  int q[EPT]; u32 pk[EPT];
  #pragma unroll
  for (int r = 0; r < EPT; ++r) {
    int e = eb + r * 256 + t;
    bool v = e < NE;
    int d = v ? __builtin_nontemporal_load(&dst[e]) : 0;
    int s = v ? __builtin_nontemporal_load(&src[e]) : 0;
    q[r] = v ? d / GSZ : 8;
    pk[r] = v ? (((u32)(d - q[r] * GSZ) << 17) | (u32)s) : 0;
  }
  u64 below = (lane == 63) ? 0x7fffffffffffffffull : ((1ull << lane) - 1);
  int base[NGRP];
  #pragma unroll
  for (int b = 0; b < NGRP; ++b) base[b] = hw[b * NWAVES + wv];
  #pragma unroll
  for (int b = 0; b < NGRP; ++b) {
    int run = 0;
    #pragma unroll
    for (int r = 0; r < EPT; ++r) {
      u64 m = __ballot(q[r] == b);
      if (q[r] == b) {
        int pos = base[b] + run + __popcll(m & below);
        if (pos < NE)
          bkt[pos] = pk[r];
      }
      run += __popcll(m);
    }
  }
}

// ---------------- per-sub-block node histogram in LDS -----------------------
__global__ __launch_bounds__(256) void k_nhist(const u32* __restrict__ bkt,
    const int* __restrict__ hw, u16* __restrict__ ncnt) {
  __shared__ int h[GSZ];
  const int g = blockIdx.x & (NGRP - 1);
  const int sub = blockIdx.x >> 3;
  const int t = threadIdx.x;
  const int start = hw[g * NWAVES];
  const int end = (g < NGRP - 1) ? hw[(g + 1) * NWAVES] : NE;
  const int cnt = end - start;
  const int chunk = (cnt + NSUB - 1) / NSUB;
  int lo = start + sub * chunk;
  int hi = lo + chunk; if (hi > end) hi = end;
  for (int i = t; i < GSZ; i += 256) h[i] = 0;
  __syncthreads();
  for (int i = lo + t; i < hi; i += 256) {
    int dl = (int)(__builtin_nontemporal_load(&bkt[i]) >> 17);
    atomicAdd(&h[dl], 1);
  }
  __syncthreads();
  u16* outp = ncnt + ((size_t)g * NSUB + sub) * GSZ;
  for (int i = t; i < GSZ; i += 256) outp[i] = (u16)h[i];
}

// ---------------- per-node scan over sub-blocks -> offsets + deg ------------
__global__ __launch_bounds__(256) void k_nscan(u16* __restrict__ ncnt,
    int* __restrict__ deg) {
  const int g = blockIdx.x & (NGRP - 1);
  const int seg = blockIdx.x >> 3;
  int d = seg * 256 + threadIdx.x;
  if (d >= GSZ) return;
  int run = 0;
  #pragma unroll
  for (int s = 0; s < NSUB; ++s) {
    size_t idx = ((size_t)g * NSUB + s) * GSZ + d;
    int v = ncnt[idx];
    ncnt[idx] = (u16)run;
    run += v;
  }
  deg[g * GSZ + d] = run;
}

// ---------------- per-group rowstart: bucket base + local scan --------------
__global__ void k_gscan(const int* __restrict__ deg, const int* __restrict__ hw,
                        int* __restrict__ rowstart) {
  __shared__ int s[256];
  const int g = blockIdx.x;
  const int t = threadIdx.x;
  const int base = hw[g * NWAVES];
  const int per = (GSZ + 255) / 256;       // 49
  int lo = t * per, hi = lo + per; if (hi > GSZ) hi = GSZ;
  int sum = 0;
  for (int i = lo; i < hi; ++i) sum += deg[g * GSZ + i];
  s[t] = sum; __syncthreads();
  for (int off = 1; off < 256; off <<= 1) {
    int u = (t >= off) ? s[t - off] : 0;
    __syncthreads(); s[t] += u; __syncthreads();
  }
  int run = base + s[t] - sum;
  for (int i = lo; i < hi; ++i) {
    int v = deg[g * GSZ + i];
    rowstart[g * GSZ + i] = run;
    run += v;
  }
  if (g == NGRP - 1 && t == 255) rowstart[NN] = NE;
}

// ---------------- scatter: LDS cursors, XCD-resident col slice --------------
__global__ __launch_bounds__(256) void k_scatter2(const u32* __restrict__ bkt,
    const int* __restrict__ hw, const u16* __restrict__ ncnt,
    const int* __restrict__ rowstart, int* __restrict__ col) {
  __shared__ int cur[GSZ];
  const int g = blockIdx.x & (NGRP - 1);
  const int sub = blockIdx.x >> 3;
  const int t = threadIdx.x;
  const int start = hw[g * NWAVES];
  const int end = (g < NGRP - 1) ? hw[(g + 1) * NWAVES] : NE;
  const int cnt = end - start;
  const int chunk = (cnt + NSUB - 1) / NSUB;
  int lo = start + sub * chunk;
  int hi = lo + chunk; if (hi > end) hi = end;
  const u16* nof = ncnt + ((size_t)g * NSUB + sub) * GSZ;
  for (int i = t; i < GSZ; i += 256)
    cur[i] = rowstart[g * GSZ + i] + (int)nof[i];
  __syncthreads();
  for (int i = lo + t; i < hi; i += 256) {
    u32 v = __builtin_nontemporal_load(&bkt[i]);
    int dl = (int)(v >> 17), s = (int)(v & 0x1ffffu);
    int pos = atomicAdd(&cur[dl], 1);
    col[pos] = s;
  }
}

// ---------------- W (k-major [k][n]) -> Wt (n-major [n][k]) bf16, 4 mats ----
__global__ void k_cvt_wt4(const float* __restrict__ W0, const float* __restrict__ W1,
                          const float* __restrict__ W2, const float* __restrict__ W3,
                          u16* __restrict__ T0, u16* __restrict__ T1,
                          u16* __restrict__ T2, u16* __restrict__ T3) {
  const float* W = blockIdx.y == 0 ? W0 : blockIdx.y == 1 ? W1 : blockIdx.y == 2 ? W2 : W3;
  u16* T = blockIdx.y == 0 ? T0 : blockIdx.y == 1 ? T1 : blockIdx.y == 2 ? T2 : T3;
  int n = blockIdx.x, k = threadIdx.x;
  T[n * D + k] = f2b(W[k * D + n]);
}

// ---------------- fp8 mean aggregation: 8-lane group per node ---------------
__global__ __launch_bounds__(256) void k_agg_q(const u8* __restrict__ feat,
    const int* __restrict__ rowstart, const int* __restrict__ col,
    u16* __restrict__ out) {
  int t = threadIdx.x;
  int node = blockIdx.x * 32 + (t >> 3);   // 32 nodes per block
  if (node >= NN) return;
  int ln = t & 7;                          // lane in group: 16B feature chunk
  int b = rowstart[node], e = rowstart[node + 1];
  const u8* fp = feat + ln * 16;
  float a[16] = {};
  int j = b;
  for (; j + 1 < e; j += 2) {              // 2 rows in flight per group
    int s0 = col[j], s1 = col[j + 1];
    u32x4 v0 = *reinterpret_cast<const u32x4*>(fp + (size_t)s0 * D);
    u32x4 v1 = *reinterpret_cast<const u32x4*>(fp + (size_t)s1 * D);
    acc16(a, v0); acc16(a, v1);
  }
  if (j < e) {
    int s0 = col[j];
    u32x4 v0 = *reinterpret_cast<const u32x4*>(fp + (size_t)s0 * D);
    acc16(a, v0);
  }
  float inv = (e > b) ? 1.f / (float)(e - b) : 0.f;
  u16x8 o0, o1;
  #pragma unroll
  for (int k = 0; k < 8; ++k) {
    o0[k] = f2b(a[k] * inv);
    o1[k] = f2b(a[8 + k] * inv);
  }
  u16* op = out + (size_t)node * D + ln * 16;
  *reinterpret_cast<u16x8*>(op) = o0;
  *reinterpret_cast<u16x8*>(op + 8) = o1;
}

// ---------------- fused dual GEMM via MFMA; LDS-transposed epilogue ---------
// R14 counters: direct fragment stores (32B bf16 / 16B fp8 per instr per row)
// hit 64B-sector write granularity -> 110MB vs 38.4MB logical (2.86x). Fix:
// stage the 128x128 bf16 tile in the (free) weight-LDS, then store 16B/lane
// chunks: each instr covers 1KB contiguous (full sectors). fp8 copy derived
// from the same chunk (8B/lane, 128B/quarter contiguous).
// NOTE: no early-return (cross-wave epilogue) — OOB rows computed, not stored.
__global__ __launch_bounds__(256) void k_gemm_mfma(
    const u16* __restrict__ A, const u16* __restrict__ B,
    const u16* __restrict__ Wt1, const u16* __restrict__ Wt2,
    const float* __restrict__ bias, u16* __restrict__ Cout,
    u8* __restrict__ Cq)
{
  __shared__ u16 wlds[128 * WSTRIDE];
  const int t = threadIdx.x;
  const int wid = t >> 6, lane = t & 63;
  const int l15 = lane & 15, g = lane >> 4;
  const int rbase = blockIdx.x * 128 + wid * 32;

  int r0 = rbase + l15, r1 = r0 + 16;
  size_t a0 = (size_t)(r0 < NN ? r0 : NN - 1) * D + g * 8;
  size_t a1 = (size_t)(r1 < NN ? r1 : NN - 1) * D + g * 8;

  f32x4 acc0[8] = {}, acc1[8] = {};

  #pragma unroll
  for (int phase = 0; phase < 2; ++phase) {
    const u16* Act = phase ? B : A;
    const u16* Wt  = phase ? Wt2 : Wt1;
    #pragma unroll
    for (int q = 0; q < 8; ++q) {
      int i = q * 256 + t;
      int n = i >> 4, kc = i & 15;
      *reinterpret_cast<u16x8*>(&wlds[n * WSTRIDE + kc * 8]) =
          *reinterpret_cast<const u16x8*>(&Wt[n * D + kc * 8]);
    }
    __syncthreads();
    #pragma unroll
    for (int kb = 0; kb < 4; ++kb) {
      bf16x8 af0 = *reinterpret_cast<const bf16x8*>(&Act[a0 + kb * 32]);
      bf16x8 af1 = *reinterpret_cast<const bf16x8*>(&Act[a1 + kb * 32]);
      #pragma unroll
      for (int c = 0; c < 8; ++c) {
        bf16x8 wf = *reinterpret_cast<const bf16x8*>(
            &wlds[(c * 16 + l15) * WSTRIDE + kb * 32 + g * 8]);
        acc0[c] = __builtin_amdgcn_mfma_f32_16x16x32_bf16(af0, wf, acc0[c], 0, 0, 0);
        acc1[c] = __builtin_amdgcn_mfma_f32_16x16x32_bf16(af1, wf, acc1[c], 0, 0, 0);
      }
    }
    __syncthreads();   // all waves done reading before restage / epilogue
  }

  // stage bias+relu'd tile into LDS (reuse wlds as [128][WSTRIDE] u16)
  #pragma unroll
  for (int c = 0; c < 8; ++c) {
    float bv = bias[c * 16 + l15];
    #pragma unroll
    for (int r = 0; r < 4; ++r) {
      float v0 = fmaxf(acc0[c][r] + bv, 0.f);
      float v1 = fmaxf(acc1[c][r] + bv, 0.f);
      wlds[(wid * 32 + g * 4 + r) * WSTRIDE + c * 16 + l15] = f2b(v0);
      wlds[(wid * 32 + 16 + g * 4 + r) * WSTRIDE + c * 16 + l15] = f2b(v1);
    }
  }
  __syncthreads();
  // coalesced stores: 2048 x 16B chunks; thread t does chunks i*256+t
  const int rblk = blockIdx.x * 128;
  #pragma unroll
  for (int i = 0; i < 8; ++i) {
    int k = i * 256 + t;
    int row = k >> 4, kc = k & 15;
    int grow = rblk + row;
    if (grow < NN) {
      u16x8 vv = *reinterpret_cast<const u16x8*>(&wlds[row * WSTRIDE + kc * 8]);
      *reinterpret_cast<u16x8*>(&Cout[(size_t)grow * D + kc * 8]) = vv;
      int qa = __builtin_amdgcn_cvt_pk_fp8_f32(b2f((u16)vv[0]), b2f((u16)vv[1]), 0, false);
      qa = __builtin_amdgcn_cvt_pk_fp8_f32(b2f((u16)vv[2]), b2f((u16)vv[3]), qa, true);
      int qb = __builtin_amdgcn_cvt_pk_fp8_f32(b2f((u16)vv[4]), b2f((u16)vv[5]), 0, false);
      qb = __builtin_amdgcn_cvt_pk_fp8_f32(b2f((u16)vv[6]), b2f((u16)vv[7]), qb, true);
      u32x2 qo; qo[0] = (u32)qa; qo[1] = (u32)qb;
      *reinterpret_cast<u32x2*>(&Cq[(size_t)grow * D + kc * 8]) = qo;
    }
  }
}

// ---------------- layer-2 GEMM (LDS weights) + fused layer-3 projection -----
__global__ __launch_bounds__(256) void k_gemm2_zr(
    const u16* __restrict__ A, const u16* __restrict__ B,
    const u16* __restrict__ Wt1, const u16* __restrict__ Wt2,
    const float* __restrict__ bias,
    const float* __restrict__ Wl3, const float* __restrict__ Wr3,
    const float* __restrict__ b3,
    float* __restrict__ z, float* __restrict__ r)
{
  __shared__ u16 wlds[128 * WSTRIDE];
  const int t = threadIdx.x;
  const int wid = t >> 6, lane = t & 63;
  const int l15 = lane & 15, g = lane >> 4;
  const int rbase = blockIdx.x * 128 + wid * 32;

  int r0 = rbase + l15, r1 = r0 + 16;
  size_t a0 = (size_t)(r0 < NN ? r0 : NN - 1) * D + g * 8;
  size_t a1 = (size_t)(r1 < NN ? r1 : NN - 1) * D + g * 8;

  f32x4 acc0[8] = {}, acc1[8] = {};

  #pragma unroll
  for (int phase = 0; phase < 2; ++phase) {
    const u16* Act = phase ? B : A;
    const u16* Wt  = phase ? Wt2 : Wt1;
    #pragma unroll
    for (int q = 0; q < 8; ++q) {
      int i = q * 256 + t;
      int n = i >> 4, kc = i & 15;
      *reinterpret_cast<u16x8*>(&wlds[n * WSTRIDE + kc * 8]) =
          *reinterpret_cast<const u16x8*>(&Wt[n * D + kc * 8]);
    }
    __syncthreads();
    #pragma unroll
    for (int kb = 0; kb < 4; ++kb) {
      bf16x8 af0 = *reinterpret_cast<const bf16x8*>(&Act[a0 + kb * 32]);
      bf16x8 af1 = *reinterpret_cast<const bf16x8*>(&Act[a1 + kb * 32]);
      #pragma unroll
      for (int c = 0; c < 8; ++c) {
        bf16x8 wf = *reinterpret_cast<const bf16x8*>(
            &wlds[(c * 16 + l15) * WSTRIDE + kb * 32 + g * 8]);
        acc0[c] = __builtin_amdgcn_mfma_f32_16x16x32_bf16(af0, wf, acc0[c], 0, 0, 0);
        acc1[c] = __builtin_amdgcn_mfma_f32_16x16x32_bf16(af1, wf, acc1[c], 0, 0, 0);
      }
    }
    __syncthreads();
  }

  float wl[8], wr[8], bv[8];
  #pragma unroll
  for (int c = 0; c < 8; ++c) {
    wl[c] = Wl3[c * 16 + l15];
    wr[c] = Wr3[c * 16 + l15];
    bv[c] = bias[c * 16 + l15];
  }
  float bb3 = b3[0];
  #pragma unroll
  for (int rf = 0; rf < 2; ++rf) {
    #pragma unroll
    for (int rr = 0; rr < 4; ++rr) {
      float pz = 0.f, pr = 0.f;
      #pragma unroll
      for (int c = 0; c < 8; ++c) {
        float v = fmaxf((rf ? acc1[c][rr] : acc0[c][rr]) + bv[c], 0.f);
        pz += v * wl[c];
        pr += v * wr[c];
      }
      pz += __shfl_xor(pz, 1, 64); pr += __shfl_xor(pr, 1, 64);
      pz += __shfl_xor(pz, 2, 64); pr += __shfl_xor(pr, 2, 64);
      pz += __shfl_xor(pz, 4, 64); pr += __shfl_xor(pr, 4, 64);
      pz += __shfl_xor(pz, 8, 64); pr += __shfl_xor(pr, 8, 64);
      int row = rbase + rf * 16 + g * 4 + rr;
      if (l15 == 0 && row < NN) {
        z[row] = pz;
        r[row] = pr + bb3;
      }
    }
  }
}

// ---------------- final: out = r + mean(z over neighbors), 16 lanes/node ----
__global__ __launch_bounds__(256) void k_out(const float* __restrict__ z,
    const float* __restrict__ r, const int* __restrict__ rowstart,
    const int* __restrict__ col, float* __restrict__ out) {
  int t = threadIdx.x;
  int sub = t & 15;
  int node = blockIdx.x * 16 + (t >> 4);
  if (node >= NN) return;
  int b = rowstart[node], e = rowstart[node + 1];
  float s = 0.f;
  for (int j = b + sub; j < e; j += 16) s += z[col[j]];
  s += __shfl_xor(s, 1, 64);
  s += __shfl_xor(s, 2, 64);
  s += __shfl_xor(s, 4, 64);
  s += __shfl_xor(s, 8, 64);
  if (sub == 0) {
    float inv = (e > b) ? 1.f / (float)(e - b) : 0.f;
    out[node] = r[node] + s * inv;
  }
}

extern "C" void kernel_launch(void* const* d_in, const int* in_sizes, int n_in,
                              void* d_out, int out_size, void* d_ws, size_t ws_size,
                              hipStream_t stream) {
  const float* x   = (const float*)d_in[0];
  const int*   ei  = (const int*)d_in[1];
  const float* Wl1 = (const float*)d_in[2];
  const float* Wr1 = (const float*)d_in[3];
  const float* b1  = (const float*)d_in[4];
  const float* Wl2 = (const float*)d_in[5];
  const float* Wr2 = (const float*)d_in[6];
  const float* b2  = (const float*)d_in[7];
  const float* Wl3 = (const float*)d_in[8];
  const float* Wr3 = (const float*)d_in[9];
  const float* b3  = (const float*)d_in[10];
  const int* srcv = ei;
  const int* dstv = ei + NE;
  float* out = (float*)d_out;

  char* ws = (char*)d_ws;
  size_t off = 0;
  auto alloc = [&](size_t bytes) {
    size_t o = off;
    off += (bytes + 255) & ~(size_t)255;
    return o;
  };
  int* deg      = (int*)(ws + alloc((size_t)NN * 4));
  int* rowstart = (int*)(ws + alloc((size_t)(NN + 1) * 4));
  int* col      = (int*)(ws + alloc((size_t)NE * 4));
  int* hw       = (int*)(ws + alloc((size_t)NGRP * NWAVES * 4));
  u32* bkt  = (u32*)(ws + alloc((size_t)NE * 4));
  u16* ncnt = (u16*)(ws + alloc((size_t)NGRP * NSUB * GSZ * 2));
  u16* xb   = (u16*)(ws + alloc((size_t)NN * D * 2));
  u8*  xq   = (u8*)(ws + alloc((size_t)NN * D));
  u16* Ab   = (u16*)(ws + alloc((size_t)NN * D * 2));
  u16* H1b  = (u16*)(ws + alloc((size_t)NN * D * 2));
  u8*  H1q  = (u8*)(ws + alloc((size_t)NN * D));
  u16* Wt1l = (u16*)(ws + alloc((size_t)D * D * 2));
  u16* Wt1r = (u16*)(ws + alloc((size_t)D * D * 2));
  u16* Wt2l = (u16*)(ws + alloc((size_t)D * D * 2));
  u16* Wt2r = (u16*)(ws + alloc((size_t)D * D * 2));
  float* z  = (float*)(ws + alloc((size_t)NN * 4));
  float* r  = (float*)(ws + alloc((size_t)NN * 4));

  const int nb_gemm  = (NN + 127) / 128;       // 782
  const int nb_agg   = (NN + 31) / 32;         // 3125
  const int nb_out   = (NN + 15) / 16;         // 6250
  const int nb_sub   = NGRP * NSUB;            // 256
  const int nb_nscan = NGRP * ((GSZ + 255) / 256);  // 8*49

  // atomic-free CSR build (+ x->bf16 + x->fp8 fused into hist pass)
  k_hist8<<<NBLK, 256, 0, stream>>>(dstv, hw, x, xb, xq);
  k_hscan<<<1, 256, 0, stream>>>(hw, NGRP * NWAVES);
  k_part2<<<NBLK, 256, 0, stream>>>(srcv, dstv, hw, bkt);
  k_nhist<<<nb_sub, 256, 0, stream>>>(bkt, hw, ncnt);
  k_nscan<<<nb_nscan, 256, 0, stream>>>(ncnt, deg);
  k_gscan<<<NGRP, 256, 0, stream>>>(deg, hw, rowstart);
  k_scatter2<<<nb_sub, 256, 0, stream>>>(bkt, hw, ncnt, rowstart, col);

  // weight prep (transposed bf16)
  k_cvt_wt4<<<dim3(D, 4), D, 0, stream>>>(Wl1, Wr1, Wl2, Wr2, Wt1l, Wt1r, Wt2l, Wt2r);

  // layer 1: gather fp8 x, GEMM in bf16; emit H1 in bf16 + fp8
  k_agg_q<<<nb_agg, 256, 0, stream>>>(xq, rowstart, col, Ab);
  k_gemm_mfma<<<nb_gemm, 256, 0, stream>>>(Ab, xb, Wt1l, Wt1r, b1, H1b, H1q);
  // layer 2 + fused layer-3 projection: gather fp8 H1
  k_agg_q<<<nb_agg, 256, 0, stream>>>(H1q, rowstart, col, Ab);
  k_gemm2_zr<<<nb_gemm, 256, 0, stream>>>(Ab, H1b, Wt2l, Wt2r, b2, Wl3, Wr3, b3, z, r);
  // final
  k_out<<<nb_out, 256, 0, stream>>>(z, r, rowstart, col, out);
}

// Round 16
// 228.083 us; speedup vs baseline: 1.8020x; 1.1536x over previous
//
#include <hip/hip_runtime.h>
#include <hip/hip_bf16.h>

#define NN 100000
#define NE 1600000
#define D 128
#define NGRP 8
#define GSZ (NN / NGRP)          // 12500, exact
#define EPT 8                    // edges per thread in hist8/part2
#define NBLK ((NE + 2047) / 2048)   // 782 blocks for hist8/part2
#define NWAVES (NBLK * 4)        // 3128 waves
#define NSUB 32                  // sub-blocks per group in nhist/scatter2
#define WSTRIDE 136              // LDS row stride (u16): 272B -> conflict-free b128

typedef unsigned short u16;
typedef unsigned int u32;
typedef unsigned long long u64;
typedef unsigned char u8;
typedef __attribute__((ext_vector_type(8))) short bf16x8;
typedef __attribute__((ext_vector_type(4))) float f32x4;
typedef __attribute__((ext_vector_type(2))) float f32x2;
typedef __attribute__((ext_vector_type(8))) u16 u16x8;
typedef __attribute__((ext_vector_type(4))) u32 u32x4;
typedef __attribute__((ext_vector_type(2))) u32 u32x2;

__device__ inline u16 f2b(float f) {
  union { float f; u32 u; } v; v.f = f;
  u32 u = v.u;
  return (u16)((u + 0x7fffu + ((u >> 16) & 1u)) >> 16);
}
__device__ inline float b2f(u16 h) {
  union { u32 u; float f; } v; v.u = ((u32)h) << 16; return v.f;
}
// accumulate 16 fp8 (one u32x4) into 16 f32 accumulators via HW packed cvt
__device__ inline void acc16(float* a, u32x4 v) {
  #pragma unroll
  for (int w = 0; w < 4; ++w) {
    f32x2 lo = __builtin_amdgcn_cvt_pk_f32_fp8(v[w], false);
    f32x2 hi = __builtin_amdgcn_cvt_pk_f32_fp8(v[w], true);
    a[w * 4 + 0] += lo[0]; a[w * 4 + 1] += lo[1];
    a[w * 4 + 2] += hi[0]; a[w * 4 + 3] += hi[1];
  }
}

// ---------------- hist + x->bf16 + x->fp8 convert (1.6M-element streams) ----
__global__ __launch_bounds__(256) void k_hist8(const int* __restrict__ dst,
    int* __restrict__ hw, const float* __restrict__ xin, u16* __restrict__ xb,
    u8* __restrict__ xq) {
  const int t = threadIdx.x, lane = t & 63, wid = t >> 6;
  const int eb = blockIdx.x * (256 * EPT);
  const int wv = blockIdx.x * 4 + wid;
  int c0=0,c1=0,c2=0,c3=0,c4=0,c5=0,c6=0,c7=0;
  #pragma unroll
  for (int r = 0; r < EPT; ++r) {
    int e = eb + r * 256 + t;
    bool v = e < NE;
    int q = v ? __builtin_nontemporal_load(&dst[e]) / GSZ : 8;
    c0 += __popcll(__ballot(q == 0)); c1 += __popcll(__ballot(q == 1));
    c2 += __popcll(__ballot(q == 2)); c3 += __popcll(__ballot(q == 3));
    c4 += __popcll(__ballot(q == 4)); c5 += __popcll(__ballot(q == 5));
    c6 += __popcll(__ballot(q == 6)); c7 += __popcll(__ballot(q == 7));
    if (v) {
      const f32x4* p = reinterpret_cast<const f32x4*>(xin) + (size_t)e * 2;
      f32x4 a = __builtin_nontemporal_load(p);
      f32x4 b = __builtin_nontemporal_load(p + 1);
      u16x8 o;
      o[0] = f2b(a[0]); o[1] = f2b(a[1]); o[2] = f2b(a[2]); o[3] = f2b(a[3]);
      o[4] = f2b(b[0]); o[5] = f2b(b[1]); o[6] = f2b(b[2]); o[7] = f2b(b[3]);
      __builtin_nontemporal_store(o, reinterpret_cast<u16x8*>(xb + (size_t)e * 8));
      int qlo = __builtin_amdgcn_cvt_pk_fp8_f32(a[0], a[1], 0, false);
      qlo = __builtin_amdgcn_cvt_pk_fp8_f32(a[2], a[3], qlo, true);
      int qhi = __builtin_amdgcn_cvt_pk_fp8_f32(b[0], b[1], 0, false);
      qhi = __builtin_amdgcn_cvt_pk_fp8_f32(b[2], b[3], qhi, true);
      u32x2 qo; qo[0] = (u32)qlo; qo[1] = (u32)qhi;
      __builtin_nontemporal_store(qo, reinterpret_cast<u32x2*>(xq + (size_t)e * 8));
    }
  }
  if (lane == 0) {
    hw[0 * NWAVES + wv] = c0; hw[1 * NWAVES + wv] = c1;
    hw[2 * NWAVES + wv] = c2; hw[3 * NWAVES + wv] = c3;
    hw[4 * NWAVES + wv] = c4; hw[5 * NWAVES + wv] = c5;
    hw[6 * NWAVES + wv] = c6; hw[7 * NWAVES + wv] = c7;
  }
}

// ---------------- per-bucket scan: 8 parallel blocks (R15: single-block scan
// was 43.5us at 0.04% occupancy). block g scans hw[g][0..NWAVES) in place,
// emits bucket total. Global base added later via bbase.
__global__ __launch_bounds__(256) void k_hscan_a(int* __restrict__ hw,
                                                 int* __restrict__ btot) {
  __shared__ int s[256];
  int* a = hw + blockIdx.x * NWAVES;
  const int t = threadIdx.x;
  const int per = (NWAVES + 255) / 256;    // 13
  int lo = t * per, hi = lo + per; if (hi > NWAVES) hi = NWAVES;
  int sum = 0;
  for (int i = lo; i < hi; ++i) sum += a[i];
  s[t] = sum; __syncthreads();
  for (int off = 1; off < 256; off <<= 1) {
    int u = (t >= off) ? s[t - off] : 0;
    __syncthreads(); s[t] += u; __syncthreads();
  }
  int run = s[t] - sum;
  for (int i = lo; i < hi; ++i) { int v = a[i]; a[i] = run; run += v; }
  if (t == 255) btot[blockIdx.x] = s[255];
}

__global__ void k_hscan_b(const int* __restrict__ btot, int* __restrict__ bbase) {
  if (threadIdx.x == 0) {
    int run = 0;
    #pragma unroll
    for (int g = 0; g < NGRP; ++g) { bbase[g] = run; run += btot[g]; }
    bbase[NGRP] = run;     // == NE
  }
}

// ---------------- deterministic bucket write (ballot ranks, no atomics) -----
__global__ __launch_bounds__(256) void k_part2(const int* __restrict__ src,
    const int* __restrict__ dst, const int* __restrict__ hw,
    const int* __restrict__ bbase, u32* __restrict__ bkt) {
  const int t = threadIdx.x, lane = t & 63, wid = t >> 6;
  const int eb = blockIdx.x * (256 * EPT);
  const int wv = blockIdx.x * 4 + wid;
  int q[EPT]; u32 pk[EPT];
  #pragma unroll
  for (int r = 0; r < EPT; ++r) {
    int e = eb + r * 256 + t;
    bool v = e < NE;
    int d = v ? __builtin_nontemporal_load(&dst[e]) : 0;
    int s = v ? __builtin_nontemporal_load(&src[e]) : 0;
    q[r] = v ? d / GSZ : 8;
    pk[r] = v ? (((u32)(d - q[r] * GSZ) << 17) | (u32)s) : 0;
  }
  u64 below = (lane == 63) ? 0x7fffffffffffffffull : ((1ull << lane) - 1);
  int base[NGRP];
  #pragma unroll
  for (int b = 0; b < NGRP; ++b) base[b] = bbase[b] + hw[b * NWAVES + wv];
  #pragma unroll
  for (int b = 0; b < NGRP; ++b) {
    int run = 0;
    #pragma unroll
    for (int r = 0; r < EPT; ++r) {
      u64 m = __ballot(q[r] == b);
      if (q[r] == b) {
        int pos = base[b] + run + __popcll(m & below);
        if (pos < NE)
          bkt[pos] = pk[r];
      }
      run += __popcll(m);
    }
  }
}

// ---------------- per-sub-block node histogram in LDS -----------------------
__global__ __launch_bounds__(256) void k_nhist(const u32* __restrict__ bkt,
    const int* __restrict__ bbase, u16* __restrict__ ncnt) {
  __shared__ int h[GSZ];
  const int g = blockIdx.x & (NGRP - 1);
  const int sub = blockIdx.x >> 3;
  const int t = threadIdx.x;
  const int start = bbase[g];
  const int end = bbase[g + 1];
  const int cnt = end - start;
  const int chunk = (cnt + NSUB - 1) / NSUB;
  int lo = start + sub * chunk;
  int hi = lo + chunk; if (hi > end) hi = end;
  for (int i = t; i < GSZ; i += 256) h[i] = 0;
  __syncthreads();
  for (int i = lo + t; i < hi; i += 256) {
    int dl = (int)(__builtin_nontemporal_load(&bkt[i]) >> 17);
    atomicAdd(&h[dl], 1);
  }
  __syncthreads();
  u16* outp = ncnt + ((size_t)g * NSUB + sub) * GSZ;
  for (int i = t; i < GSZ; i += 256) outp[i] = (u16)h[i];
}

// ---------------- per-node scan over sub-blocks -> offsets + deg ------------
__global__ __launch_bounds__(256) void k_nscan(u16* __restrict__ ncnt,
    int* __restrict__ deg) {
  const int g = blockIdx.x & (NGRP - 1);
  const int seg = blockIdx.x >> 3;
  int d = seg * 256 + threadIdx.x;
  if (d >= GSZ) return;
  int run = 0;
  #pragma unroll
  for (int s = 0; s < NSUB; ++s) {
    size_t idx = ((size_t)g * NSUB + s) * GSZ + d;
    int v = ncnt[idx];
    ncnt[idx] = (u16)run;
    run += v;
  }
  deg[g * GSZ + d] = run;
}

// ---------------- per-group rowstart: bucket base + local scan --------------
__global__ void k_gscan(const int* __restrict__ deg, const int* __restrict__ bbase,
                        int* __restrict__ rowstart) {
  __shared__ int s[256];
  const int g = blockIdx.x;
  const int t = threadIdx.x;
  const int base = bbase[g];
  const int per = (GSZ + 255) / 256;       // 49
  int lo = t * per, hi = lo + per; if (hi > GSZ) hi = GSZ;
  int sum = 0;
  for (int i = lo; i < hi; ++i) sum += deg[g * GSZ + i];
  s[t] = sum; __syncthreads();
  for (int off = 1; off < 256; off <<= 1) {
    int u = (t >= off) ? s[t - off] : 0;
    __syncthreads(); s[t] += u; __syncthreads();
  }
  int run = base + s[t] - sum;
  for (int i = lo; i < hi; ++i) {
    int v = deg[g * GSZ + i];
    rowstart[g * GSZ + i] = run;
    run += v;
  }
  if (g == NGRP - 1 && t == 255) rowstart[NN] = NE;
}

// ---------------- scatter: LDS cursors, XCD-resident col slice --------------
__global__ __launch_bounds__(256) void k_scatter2(const u32* __restrict__ bkt,
    const int* __restrict__ bbase, const u16* __restrict__ ncnt,
    const int* __restrict__ rowstart, int* __restrict__ col) {
  __shared__ int cur[GSZ];
  const int g = blockIdx.x & (NGRP - 1);
  const int sub = blockIdx.x >> 3;
  const int t = threadIdx.x;
  const int start = bbase[g];
  const int end = bbase[g + 1];
  const int cnt = end - start;
  const int chunk = (cnt + NSUB - 1) / NSUB;
  int lo = start + sub * chunk;
  int hi = lo + chunk; if (hi > end) hi = end;
  const u16* nof = ncnt + ((size_t)g * NSUB + sub) * GSZ;
  for (int i = t; i < GSZ; i += 256)
    cur[i] = rowstart[g * GSZ + i] + (int)nof[i];
  __syncthreads();
  for (int i = lo + t; i < hi; i += 256) {
    u32 v = __builtin_nontemporal_load(&bkt[i]);
    int dl = (int)(v >> 17), s = (int)(v & 0x1ffffu);
    int pos = atomicAdd(&cur[dl], 1);
    col[pos] = s;
  }
}

// ---------------- W (k-major [k][n]) -> Wt (n-major [n][k]) bf16, 4 mats ----
__global__ void k_cvt_wt4(const float* __restrict__ W0, const float* __restrict__ W1,
                          const float* __restrict__ W2, const float* __restrict__ W3,
                          u16* __restrict__ T0, u16* __restrict__ T1,
                          u16* __restrict__ T2, u16* __restrict__ T3) {
  const float* W = blockIdx.y == 0 ? W0 : blockIdx.y == 1 ? W1 : blockIdx.y == 2 ? W2 : W3;
  u16* T = blockIdx.y == 0 ? T0 : blockIdx.y == 1 ? T1 : blockIdx.y == 2 ? T2 : T3;
  int n = blockIdx.x, k = threadIdx.x;
  T[n * D + k] = f2b(W[k * D + n]);
}

// ---------------- fp8 mean aggregation: 8-lane group per node, 4-deep -------
__global__ __launch_bounds__(256) void k_agg_q(const u8* __restrict__ feat,
    const int* __restrict__ rowstart, const int* __restrict__ col,
    u16* __restrict__ out) {
  int t = threadIdx.x;
  int node = blockIdx.x * 32 + (t >> 3);   // 32 nodes per block
  if (node >= NN) return;
  int ln = t & 7;                          // lane in group: 16B feature chunk
  int b = rowstart[node], e = rowstart[node + 1];
  const u8* fp = feat + ln * 16;
  float a[16] = {};
  int j = b;
  for (; j + 3 < e; j += 4) {              // 4 rows in flight per group (32/wave)
    int s0 = col[j], s1 = col[j + 1], s2 = col[j + 2], s3 = col[j + 3];
    u32x4 v0 = *reinterpret_cast<const u32x4*>(fp + (size_t)s0 * D);
    u32x4 v1 = *reinterpret_cast<const u32x4*>(fp + (size_t)s1 * D);
    u32x4 v2 = *reinterpret_cast<const u32x4*>(fp + (size_t)s2 * D);
    u32x4 v3 = *reinterpret_cast<const u32x4*>(fp + (size_t)s3 * D);
    acc16(a, v0); acc16(a, v1); acc16(a, v2); acc16(a, v3);
  }
  for (; j < e; ++j) {
    int s0 = col[j];
    u32x4 v0 = *reinterpret_cast<const u32x4*>(fp + (size_t)s0 * D);
    acc16(a, v0);
  }
  float inv = (e > b) ? 1.f / (float)(e - b) : 0.f;
  u16x8 o0, o1;
  #pragma unroll
  for (int k = 0; k < 8; ++k) {
    o0[k] = f2b(a[k] * inv);
    o1[k] = f2b(a[8 + k] * inv);
  }
  u16* op = out + (size_t)node * D + ln * 16;
  *reinterpret_cast<u16x8*>(op) = o0;
  *reinterpret_cast<u16x8*>(op + 8) = o1;
}

// ---------------- fused dual GEMM via MFMA; LDS-transposed epilogue ---------
__global__ __launch_bounds__(256) void k_gemm_mfma(
    const u16* __restrict__ A, const u16* __restrict__ B,
    const u16* __restrict__ Wt1, const u16* __restrict__ Wt2,
    const float* __restrict__ bias, u16* __restrict__ Cout,
    u8* __restrict__ Cq)
{
  __shared__ u16 wlds[128 * WSTRIDE];
  const int t = threadIdx.x;
  const int wid = t >> 6, lane = t & 63;
  const int l15 = lane & 15, g = lane >> 4;
  const int rbase = blockIdx.x * 128 + wid * 32;

  int r0 = rbase + l15, r1 = r0 + 16;
  size_t a0 = (size_t)(r0 < NN ? r0 : NN - 1) * D + g * 8;
  size_t a1 = (size_t)(r1 < NN ? r1 : NN - 1) * D + g * 8;

  f32x4 acc0[8] = {}, acc1[8] = {};

  #pragma unroll
  for (int phase = 0; phase < 2; ++phase) {
    const u16* Act = phase ? B : A;
    const u16* Wt  = phase ? Wt2 : Wt1;
    #pragma unroll
    for (int q = 0; q < 8; ++q) {
      int i = q * 256 + t;
      int n = i >> 4, kc = i & 15;
      *reinterpret_cast<u16x8*>(&wlds[n * WSTRIDE + kc * 8]) =
          *reinterpret_cast<const u16x8*>(&Wt[n * D + kc * 8]);
    }
    __syncthreads();
    #pragma unroll
    for (int kb = 0; kb < 4; ++kb) {
      bf16x8 af0 = *reinterpret_cast<const bf16x8*>(&Act[a0 + kb * 32]);
      bf16x8 af1 = *reinterpret_cast<const bf16x8*>(&Act[a1 + kb * 32]);
      #pragma unroll
      for (int c = 0; c < 8; ++c) {
        bf16x8 wf = *reinterpret_cast<const bf16x8*>(
            &wlds[(c * 16 + l15) * WSTRIDE + kb * 32 + g * 8]);
        acc0[c] = __builtin_amdgcn_mfma_f32_16x16x32_bf16(af0, wf, acc0[c], 0, 0, 0);
        acc1[c] = __builtin_amdgcn_mfma_f32_16x16x32_bf16(af1, wf, acc1[c], 0, 0, 0);
      }
    }
    __syncthreads();
  }

  // stage bias+relu'd tile into LDS (reuse wlds as [128][WSTRIDE] u16)
  #pragma unroll
  for (int c = 0; c < 8; ++c) {
    float bv = bias[c * 16 + l15];
    #pragma unroll
    for (int r = 0; r < 4; ++r) {
      float v0 = fmaxf(acc0[c][r] + bv, 0.f);
      float v1 = fmaxf(acc1[c][r] + bv, 0.f);
      wlds[(wid * 32 + g * 4 + r) * WSTRIDE + c * 16 + l15] = f2b(v0);
      wlds[(wid * 32 + 16 + g * 4 + r) * WSTRIDE + c * 16 + l15] = f2b(v1);
    }
  }
  __syncthreads();
  // coalesced stores: 2048 x 16B chunks; thread t does chunks i*256+t
  const int rblk = blockIdx.x * 128;
  #pragma unroll
  for (int i = 0; i < 8; ++i) {
    int k = i * 256 + t;
    int row = k >> 4, kc = k & 15;
    int grow = rblk + row;
    if (grow < NN) {
      u16x8 vv = *reinterpret_cast<const u16x8*>(&wlds[row * WSTRIDE + kc * 8]);
      *reinterpret_cast<u16x8*>(&Cout[(size_t)grow * D + kc * 8]) = vv;
      int qa = __builtin_amdgcn_cvt_pk_fp8_f32(b2f((u16)vv[0]), b2f((u16)vv[1]), 0, false);
      qa = __builtin_amdgcn_cvt_pk_fp8_f32(b2f((u16)vv[2]), b2f((u16)vv[3]), qa, true);
      int qb = __builtin_amdgcn_cvt_pk_fp8_f32(b2f((u16)vv[4]), b2f((u16)vv[5]), 0, false);
      qb = __builtin_amdgcn_cvt_pk_fp8_f32(b2f((u16)vv[6]), b2f((u16)vv[7]), qb, true);
      u32x2 qo; qo[0] = (u32)qa; qo[1] = (u32)qb;
      *reinterpret_cast<u32x2*>(&Cq[(size_t)grow * D + kc * 8]) = qo;
    }
  }
}

// ---------------- layer-2 GEMM (LDS weights) + fused layer-3 projection -----
__global__ __launch_bounds__(256) void k_gemm2_zr(
    const u16* __restrict__ A, const u16* __restrict__ B,
    const u16* __restrict__ Wt1, const u16* __restrict__ Wt2,
    const float* __restrict__ bias,
    const float* __restrict__ Wl3, const float* __restrict__ Wr3,
    const float* __restrict__ b3,
    float* __restrict__ z, float* __restrict__ r)
{
  __shared__ u16 wlds[128 * WSTRIDE];
  const int t = threadIdx.x;
  const int wid = t >> 6, lane = t & 63;
  const int l15 = lane & 15, g = lane >> 4;
  const int rbase = blockIdx.x * 128 + wid * 32;

  int r0 = rbase + l15, r1 = r0 + 16;
  size_t a0 = (size_t)(r0 < NN ? r0 : NN - 1) * D + g * 8;
  size_t a1 = (size_t)(r1 < NN ? r1 : NN - 1) * D + g * 8;

  f32x4 acc0[8] = {}, acc1[8] = {};

  #pragma unroll
  for (int phase = 0; phase < 2; ++phase) {
    const u16* Act = phase ? B : A;
    const u16* Wt  = phase ? Wt2 : Wt1;
    #pragma unroll
    for (int q = 0; q < 8; ++q) {
      int i = q * 256 + t;
      int n = i >> 4, kc = i & 15;
      *reinterpret_cast<u16x8*>(&wlds[n * WSTRIDE + kc * 8]) =
          *reinterpret_cast<const u16x8*>(&Wt[n * D + kc * 8]);
    }
    __syncthreads();
    #pragma unroll
    for (int kb = 0; kb < 4; ++kb) {
      bf16x8 af0 = *reinterpret_cast<const bf16x8*>(&Act[a0 + kb * 32]);
      bf16x8 af1 = *reinterpret_cast<const bf16x8*>(&Act[a1 + kb * 32]);
      #pragma unroll
      for (int c = 0; c < 8; ++c) {
        bf16x8 wf = *reinterpret_cast<const bf16x8*>(
            &wlds[(c * 16 + l15) * WSTRIDE + kb * 32 + g * 8]);
        acc0[c] = __builtin_amdgcn_mfma_f32_16x16x32_bf16(af0, wf, acc0[c], 0, 0, 0);
        acc1[c] = __builtin_amdgcn_mfma_f32_16x16x32_bf16(af1, wf, acc1[c], 0, 0, 0);
      }
    }
    __syncthreads();
  }

  float wl[8], wr[8], bv[8];
  #pragma unroll
  for (int c = 0; c < 8; ++c) {
    wl[c] = Wl3[c * 16 + l15];
    wr[c] = Wr3[c * 16 + l15];
    bv[c] = bias[c * 16 + l15];
  }
  float bb3 = b3[0];
  #pragma unroll
  for (int rf = 0; rf < 2; ++rf) {
    #pragma unroll
    for (int rr = 0; rr < 4; ++rr) {
      float pz = 0.f, pr = 0.f;
      #pragma unroll
      for (int c = 0; c < 8; ++c) {
        float v = fmaxf((rf ? acc1[c][rr] : acc0[c][rr]) + bv[c], 0.f);
        pz += v * wl[c];
        pr += v * wr[c];
      }
      pz += __shfl_xor(pz, 1, 64); pr += __shfl_xor(pr, 1, 64);
      pz += __shfl_xor(pz, 2, 64); pr += __shfl_xor(pr, 2, 64);
      pz += __shfl_xor(pz, 4, 64); pr += __shfl_xor(pr, 4, 64);
      pz += __shfl_xor(pz, 8, 64); pr += __shfl_xor(pr, 8, 64);
      int row = rbase + rf * 16 + g * 4 + rr;
      if (l15 == 0 && row < NN) {
        z[row] = pz;
        r[row] = pr + bb3;
      }
    }
  }
}

// ---------------- final: out = r + mean(z over neighbors), 16 lanes/node ----
__global__ __launch_bounds__(256) void k_out(const float* __restrict__ z,
    const float* __restrict__ r, const int* __restrict__ rowstart,
    const int* __restrict__ col, float* __restrict__ out) {
  int t = threadIdx.x;
  int sub = t & 15;
  int node = blockIdx.x * 16 + (t >> 4);
  if (node >= NN) return;
  int b = rowstart[node], e = rowstart[node + 1];
  float s = 0.f;
  for (int j = b + sub; j < e; j += 16) s += z[col[j]];
  s += __shfl_xor(s, 1, 64);
  s += __shfl_xor(s, 2, 64);
  s += __shfl_xor(s, 4, 64);
  s += __shfl_xor(s, 8, 64);
  if (sub == 0) {
    float inv = (e > b) ? 1.f / (float)(e - b) : 0.f;
    out[node] = r[node] + s * inv;
  }
}

extern "C" void kernel_launch(void* const* d_in, const int* in_sizes, int n_in,
                              void* d_out, int out_size, void* d_ws, size_t ws_size,
                              hipStream_t stream) {
  const float* x   = (const float*)d_in[0];
  const int*   ei  = (const int*)d_in[1];
  const float* Wl1 = (const float*)d_in[2];
  const float* Wr1 = (const float*)d_in[3];
  const float* b1  = (const float*)d_in[4];
  const float* Wl2 = (const float*)d_in[5];
  const float* Wr2 = (const float*)d_in[6];
  const float* b2  = (const float*)d_in[7];
  const float* Wl3 = (const float*)d_in[8];
  const float* Wr3 = (const float*)d_in[9];
  const float* b3  = (const float*)d_in[10];
  const int* srcv = ei;
  const int* dstv = ei + NE;
  float* out = (float*)d_out;

  char* ws = (char*)d_ws;
  size_t off = 0;
  auto alloc = [&](size_t bytes) {
    size_t o = off;
    off += (bytes + 255) & ~(size_t)255;
    return o;
  };
  int* deg      = (int*)(ws + alloc((size_t)NN * 4));
  int* rowstart = (int*)(ws + alloc((size_t)(NN + 1) * 4));
  int* col      = (int*)(ws + alloc((size_t)NE * 4));
  int* hw       = (int*)(ws + alloc((size_t)NGRP * NWAVES * 4));
  int* btot     = (int*)(ws + alloc(64 * 4));
  int* bbase    = (int*)(ws + alloc(64 * 4));
  u32* bkt  = (u32*)(ws + alloc((size_t)NE * 4));
  u16* ncnt = (u16*)(ws + alloc((size_t)NGRP * NSUB * GSZ * 2));
  u16* xb   = (u16*)(ws + alloc((size_t)NN * D * 2));
  u8*  xq   = (u8*)(ws + alloc((size_t)NN * D));
  u16* Ab   = (u16*)(ws + alloc((size_t)NN * D * 2));
  u16* H1b  = (u16*)(ws + alloc((size_t)NN * D * 2));
  u8*  H1q  = (u8*)(ws + alloc((size_t)NN * D));
  u16* Wt1l = (u16*)(ws + alloc((size_t)D * D * 2));
  u16* Wt1r = (u16*)(ws + alloc((size_t)D * D * 2));
  u16* Wt2l = (u16*)(ws + alloc((size_t)D * D * 2));
  u16* Wt2r = (u16*)(ws + alloc((size_t)D * D * 2));
  float* z  = (float*)(ws + alloc((size_t)NN * 4));
  float* r  = (float*)(ws + alloc((size_t)NN * 4));

  const int nb_gemm  = (NN + 127) / 128;       // 782
  const int nb_agg   = (NN + 31) / 32;         // 3125
  const int nb_out   = (NN + 15) / 16;         // 6250
  const int nb_sub   = NGRP * NSUB;            // 256
  const int nb_nscan = NGRP * ((GSZ + 255) / 256);  // 8*49

  // atomic-free CSR build (+ x->bf16 + x->fp8 fused into hist pass)
  k_hist8<<<NBLK, 256, 0, stream>>>(dstv, hw, x, xb, xq);
  k_hscan_a<<<NGRP, 256, 0, stream>>>(hw, btot);
  k_hscan_b<<<1, 64, 0, stream>>>(btot, bbase);
  k_part2<<<NBLK, 256, 0, stream>>>(srcv, dstv, hw, bbase, bkt);
  k_nhist<<<nb_sub, 256, 0, stream>>>(bkt, bbase, ncnt);
  k_nscan<<<nb_nscan, 256, 0, stream>>>(ncnt, deg);
  k_gscan<<<NGRP, 256, 0, stream>>>(deg, bbase, rowstart);
  k_scatter2<<<nb_sub, 256, 0, stream>>>(bkt, bbase, ncnt, rowstart, col);

  // weight prep (transposed bf16)
  k_cvt_wt4<<<dim3(D, 4), D, 0, stream>>>(Wl1, Wr1, Wl2, Wr2, Wt1l, Wt1r, Wt2l, Wt2r);

  // layer 1: gather fp8 x, GEMM in bf16; emit H1 in bf16 + fp8
  k_agg_q<<<nb_agg, 256, 0, stream>>>(xq, rowstart, col, Ab);
  k_gemm_mfma<<<nb_gemm, 256, 0, stream>>>(Ab, xb, Wt1l, Wt1r, b1, H1b, H1q);
  // layer 2 + fused layer-3 projection: gather fp8 H1
  k_agg_q<<<nb_agg, 256, 0, stream>>>(H1q, rowstart, col, Ab);
  k_gemm2_zr<<<nb_gemm, 256, 0, stream>>>(Ab, H1b, Wt2l, Wt2r, b2, Wl3, Wr3, b3, z, r);
  // final
  k_out<<<nb_out, 256, 0, stream>>>(z, r, rowstart, col, out);
}

// Round 17
// 224.807 us; speedup vs baseline: 1.8282x; 1.0146x over previous
//
#include <hip/hip_runtime.h>
#include <hip/hip_bf16.h>

#define NN 100000
#define NE 1600000
#define D 128
#define NGRP 8
#define GSZ (NN / NGRP)          // 12500, exact
#define EPT 8                    // edges per thread in hist8/part2
#define NBLK ((NE + 2047) / 2048)   // 782 blocks for hist8/part2
#define NWAVES (NBLK * 4)        // 3128 waves
#define NSUB 32                  // sub-blocks per group in nhist/scatter2
#define WSTRIDE 136              // LDS row stride (u16): 272B -> conflict-free b128

typedef unsigned short u16;
typedef unsigned int u32;
typedef unsigned long long u64;
typedef unsigned char u8;
typedef __attribute__((ext_vector_type(8))) short bf16x8;
typedef __attribute__((ext_vector_type(4))) float f32x4;
typedef __attribute__((ext_vector_type(2))) float f32x2;
typedef __attribute__((ext_vector_type(8))) u16 u16x8;
typedef __attribute__((ext_vector_type(4))) u32 u32x4;
typedef __attribute__((ext_vector_type(2))) u32 u32x2;

__device__ inline u16 f2b(float f) {
  union { float f; u32 u; } v; v.f = f;
  u32 u = v.u;
  return (u16)((u + 0x7fffu + ((u >> 16) & 1u)) >> 16);
}
__device__ inline float b2f(u16 h) {
  union { u32 u; float f; } v; v.u = ((u32)h) << 16; return v.f;
}
// accumulate 16 fp8 (one u32x4) into 16 f32 accumulators via HW packed cvt
__device__ inline void acc16(float* a, u32x4 v) {
  #pragma unroll
  for (int w = 0; w < 4; ++w) {
    f32x2 lo = __builtin_amdgcn_cvt_pk_f32_fp8(v[w], false);
    f32x2 hi = __builtin_amdgcn_cvt_pk_f32_fp8(v[w], true);
    a[w * 4 + 0] += lo[0]; a[w * 4 + 1] += lo[1];
    a[w * 4 + 2] += hi[0]; a[w * 4 + 3] += hi[1];
  }
}

// ---------------- hist + x->bf16 + x->fp8 convert (1.6M-element streams) ----
__global__ __launch_bounds__(256) void k_hist8(const int* __restrict__ dst,
    int* __restrict__ hw, const float* __restrict__ xin, u16* __restrict__ xb,
    u8* __restrict__ xq) {
  const int t = threadIdx.x, lane = t & 63, wid = t >> 6;
  const int eb = blockIdx.x * (256 * EPT);
  const int wv = blockIdx.x * 4 + wid;
  int c0=0,c1=0,c2=0,c3=0,c4=0,c5=0,c6=0,c7=0;
  #pragma unroll
  for (int r = 0; r < EPT; ++r) {
    int e = eb + r * 256 + t;
    bool v = e < NE;
    int q = v ? __builtin_nontemporal_load(&dst[e]) / GSZ : 8;
    c0 += __popcll(__ballot(q == 0)); c1 += __popcll(__ballot(q == 1));
    c2 += __popcll(__ballot(q == 2)); c3 += __popcll(__ballot(q == 3));
    c4 += __popcll(__ballot(q == 4)); c5 += __popcll(__ballot(q == 5));
    c6 += __popcll(__ballot(q == 6)); c7 += __popcll(__ballot(q == 7));
    if (v) {
      const f32x4* p = reinterpret_cast<const f32x4*>(xin) + (size_t)e * 2;
      f32x4 a = __builtin_nontemporal_load(p);
      f32x4 b = __builtin_nontemporal_load(p + 1);
      u16x8 o;
      o[0] = f2b(a[0]); o[1] = f2b(a[1]); o[2] = f2b(a[2]); o[3] = f2b(a[3]);
      o[4] = f2b(b[0]); o[5] = f2b(b[1]); o[6] = f2b(b[2]); o[7] = f2b(b[3]);
      __builtin_nontemporal_store(o, reinterpret_cast<u16x8*>(xb + (size_t)e * 8));
      int qlo = __builtin_amdgcn_cvt_pk_fp8_f32(a[0], a[1], 0, false);
      qlo = __builtin_amdgcn_cvt_pk_fp8_f32(a[2], a[3], qlo, true);
      int qhi = __builtin_amdgcn_cvt_pk_fp8_f32(b[0], b[1], 0, false);
      qhi = __builtin_amdgcn_cvt_pk_fp8_f32(b[2], b[3], qhi, true);
      u32x2 qo; qo[0] = (u32)qlo; qo[1] = (u32)qhi;
      __builtin_nontemporal_store(qo, reinterpret_cast<u32x2*>(xq + (size_t)e * 8));
    }
  }
  if (lane == 0) {
    hw[0 * NWAVES + wv] = c0; hw[1 * NWAVES + wv] = c1;
    hw[2 * NWAVES + wv] = c2; hw[3 * NWAVES + wv] = c3;
    hw[4 * NWAVES + wv] = c4; hw[5 * NWAVES + wv] = c5;
    hw[6 * NWAVES + wv] = c6; hw[7 * NWAVES + wv] = c7;
  }
}

// ---------------- per-bucket scan: 8 parallel blocks ------------------------
__global__ __launch_bounds__(256) void k_hscan_a(int* __restrict__ hw,
                                                 int* __restrict__ btot) {
  __shared__ int s[256];
  int* a = hw + blockIdx.x * NWAVES;
  const int t = threadIdx.x;
  const int per = (NWAVES + 255) / 256;    // 13
  int lo = t * per, hi = lo + per; if (hi > NWAVES) hi = NWAVES;
  int sum = 0;
  for (int i = lo; i < hi; ++i) sum += a[i];
  s[t] = sum; __syncthreads();
  for (int off = 1; off < 256; off <<= 1) {
    int u = (t >= off) ? s[t - off] : 0;
    __syncthreads(); s[t] += u; __syncthreads();
  }
  int run = s[t] - sum;
  for (int i = lo; i < hi; ++i) { int v = a[i]; a[i] = run; run += v; }
  if (t == 255) btot[blockIdx.x] = s[255];
}

__global__ void k_hscan_b(const int* __restrict__ btot, int* __restrict__ bbase) {
  if (threadIdx.x == 0) {
    int run = 0;
    #pragma unroll
    for (int g = 0; g < NGRP; ++g) { bbase[g] = run; run += btot[g]; }
    bbase[NGRP] = run;     // == NE
  }
}

// ---------------- deterministic bucket write (ballot ranks, no atomics) -----
__global__ __launch_bounds__(256) void k_part2(const int* __restrict__ src,
    const int* __restrict__ dst, const int* __restrict__ hw,
    const int* __restrict__ bbase, u32* __restrict__ bkt) {
  const int t = threadIdx.x, lane = t & 63, wid = t >> 6;
  const int eb = blockIdx.x * (256 * EPT);
  const int wv = blockIdx.x * 4 + wid;
  int q[EPT]; u32 pk[EPT];
  #pragma unroll
  for (int r = 0; r < EPT; ++r) {
    int e = eb + r * 256 + t;
    bool v = e < NE;
    int d = v ? __builtin_nontemporal_load(&dst[e]) : 0;
    int s = v ? __builtin_nontemporal_load(&src[e]) : 0;
    q[r] = v ? d / GSZ : 8;
    pk[r] = v ? (((u32)(d - q[r] * GSZ) << 17) | (u32)s) : 0;
  }
  u64 below = (lane == 63) ? 0x7fffffffffffffffull : ((1ull << lane) - 1);
  int base[NGRP];
  #pragma unroll
  for (int b = 0; b < NGRP; ++b) base[b] = bbase[b] + hw[b * NWAVES + wv];
  #pragma unroll
  for (int b = 0; b < NGRP; ++b) {
    int run = 0;
    #pragma unroll
    for (int r = 0; r < EPT; ++r) {
      u64 m = __ballot(q[r] == b);
      if (q[r] == b) {
        int pos = base[b] + run + __popcll(m & below);
        if (pos < NE)
          bkt[pos] = pk[r];
      }
      run += __popcll(m);
    }
  }
}

// ---------------- per-sub-block node histogram in LDS -----------------------
__global__ __launch_bounds__(256) void k_nhist(const u32* __restrict__ bkt,
    const int* __restrict__ bbase, u16* __restrict__ ncnt) {
  __shared__ int h[GSZ];
  const int g = blockIdx.x & (NGRP - 1);
  const int sub = blockIdx.x >> 3;
  const int t = threadIdx.x;
  const int start = bbase[g];
  const int end = bbase[g + 1];
  const int cnt = end - start;
  const int chunk = (cnt + NSUB - 1) / NSUB;
  int lo = start + sub * chunk;
  int hi = lo + chunk; if (hi > end) hi = end;
  for (int i = t; i < GSZ; i += 256) h[i] = 0;
  __syncthreads();
  for (int i = lo + t; i < hi; i += 256) {
    int dl = (int)(__builtin_nontemporal_load(&bkt[i]) >> 17);
    atomicAdd(&h[dl], 1);
  }
  __syncthreads();
  u16* outp = ncnt + ((size_t)g * NSUB + sub) * GSZ;
  for (int i = t; i < GSZ; i += 256) outp[i] = (u16)h[i];
}

// ---------------- per-node scan over sub-blocks -> offsets + deg ------------
__global__ __launch_bounds__(256) void k_nscan(u16* __restrict__ ncnt,
    int* __restrict__ deg) {
  const int g = blockIdx.x & (NGRP - 1);
  const int seg = blockIdx.x >> 3;
  int d = seg * 256 + threadIdx.x;
  if (d >= GSZ) return;
  int run = 0;
  #pragma unroll
  for (int s = 0; s < NSUB; ++s) {
    size_t idx = ((size_t)g * NSUB + s) * GSZ + d;
    int v = ncnt[idx];
    ncnt[idx] = (u16)run;
    run += v;
  }
  deg[g * GSZ + d] = run;
}

// ---------------- per-group rowstart: bucket base + local scan --------------
__global__ void k_gscan(const int* __restrict__ deg, const int* __restrict__ bbase,
                        int* __restrict__ rowstart) {
  __shared__ int s[256];
  const int g = blockIdx.x;
  const int t = threadIdx.x;
  const int base = bbase[g];
  const int per = (GSZ + 255) / 256;       // 49
  int lo = t * per, hi = lo + per; if (hi > GSZ) hi = GSZ;
  int sum = 0;
  for (int i = lo; i < hi; ++i) sum += deg[g * GSZ + i];
  s[t] = sum; __syncthreads();
  for (int off = 1; off < 256; off <<= 1) {
    int u = (t >= off) ? s[t - off] : 0;
    __syncthreads(); s[t] += u; __syncthreads();
  }
  int run = base + s[t] - sum;
  for (int i = lo; i < hi; ++i) {
    int v = deg[g * GSZ + i];
    rowstart[g * GSZ + i] = run;
    run += v;
  }
  if (g == NGRP - 1 && t == 255) rowstart[NN] = NE;
}

// ---------------- scatter: LDS cursors, XCD-resident col slice --------------
__global__ __launch_bounds__(256) void k_scatter2(const u32* __restrict__ bkt,
    const int* __restrict__ bbase, const u16* __restrict__ ncnt,
    const int* __restrict__ rowstart, int* __restrict__ col) {
  __shared__ int cur[GSZ];
  const int g = blockIdx.x & (NGRP - 1);
  const int sub = blockIdx.x >> 3;
  const int t = threadIdx.x;
  const int start = bbase[g];
  const int end = bbase[g + 1];
  const int cnt = end - start;
  const int chunk = (cnt + NSUB - 1) / NSUB;
  int lo = start + sub * chunk;
  int hi = lo + chunk; if (hi > end) hi = end;
  const u16* nof = ncnt + ((size_t)g * NSUB + sub) * GSZ;
  for (int i = t; i < GSZ; i += 256)
    cur[i] = rowstart[g * GSZ + i] + (int)nof[i];
  __syncthreads();
  for (int i = lo + t; i < hi; i += 256) {
    u32 v = __builtin_nontemporal_load(&bkt[i]);
    int dl = (int)(v >> 17), s = (int)(v & 0x1ffffu);
    int pos = atomicAdd(&cur[dl], 1);
    col[pos] = s;
  }
}

// ---------------- W (k-major [k][n]) -> Wt (n-major [n][k]) bf16, 4 mats ----
__global__ void k_cvt_wt4(const float* __restrict__ W0, const float* __restrict__ W1,
                          const float* __restrict__ W2, const float* __restrict__ W3,
                          u16* __restrict__ T0, u16* __restrict__ T1,
                          u16* __restrict__ T2, u16* __restrict__ T3) {
  const float* W = blockIdx.y == 0 ? W0 : blockIdx.y == 1 ? W1 : blockIdx.y == 2 ? W2 : W3;
  u16* T = blockIdx.y == 0 ? T0 : blockIdx.y == 1 ? T1 : blockIdx.y == 2 ? T2 : T3;
  int n = blockIdx.x, k = threadIdx.x;
  T[n * D + k] = f2b(W[k * D + n]);
}

// ---------------- fp8 mean aggregation: 8-lane group per node, 8-deep -------
__global__ __launch_bounds__(256) void k_agg_q(const u8* __restrict__ feat,
    const int* __restrict__ rowstart, const int* __restrict__ col,
    u16* __restrict__ out) {
  int t = threadIdx.x;
  int node = blockIdx.x * 32 + (t >> 3);   // 32 nodes per block
  if (node >= NN) return;
  int ln = t & 7;                          // lane in group: 16B feature chunk
  int b = rowstart[node], e = rowstart[node + 1];
  const u8* fp = feat + ln * 16;
  float a[16] = {};
  int j = b;
  for (; j + 7 < e; j += 8) {              // 8 rows in flight per group (64/wave)
    u32x4 v[8];
    #pragma unroll
    for (int u = 0; u < 8; ++u)
      v[u] = *reinterpret_cast<const u32x4*>(fp + (size_t)col[j + u] * D);
    #pragma unroll
    for (int u = 0; u < 8; ++u) acc16(a, v[u]);
  }
  if (j + 3 < e) {                         // 4-deep step
    u32x4 v0 = *reinterpret_cast<const u32x4*>(fp + (size_t)col[j] * D);
    u32x4 v1 = *reinterpret_cast<const u32x4*>(fp + (size_t)col[j + 1] * D);
    u32x4 v2 = *reinterpret_cast<const u32x4*>(fp + (size_t)col[j + 2] * D);
    u32x4 v3 = *reinterpret_cast<const u32x4*>(fp + (size_t)col[j + 3] * D);
    acc16(a, v0); acc16(a, v1); acc16(a, v2); acc16(a, v3);
    j += 4;
  }
  for (; j < e; ++j) {
    u32x4 v0 = *reinterpret_cast<const u32x4*>(fp + (size_t)col[j] * D);
    acc16(a, v0);
  }
  float inv = (e > b) ? 1.f / (float)(e - b) : 0.f;
  u16x8 o0, o1;
  #pragma unroll
  for (int k = 0; k < 8; ++k) {
    o0[k] = f2b(a[k] * inv);
    o1[k] = f2b(a[8 + k] * inv);
  }
  u16* op = out + (size_t)node * D + ln * 16;
  *reinterpret_cast<u16x8*>(op) = o0;
  *reinterpret_cast<u16x8*>(op + 8) = o1;
}

// ---------------- fused dual GEMM via MFMA; 64-row tiles --------------------
// R14 profile: 128-row tiles -> grid 782 = 3 blocks/CU, occupancy 19.7%,
// latency-bound. 64-row tiles double the grid (1563 -> 4 blocks/CU LDS-limit,
// ~50% occ). Each wave: 16 rows, single acc set (VGPR ~40).
__global__ __launch_bounds__(256) void k_gemm_mfma(
    const u16* __restrict__ A, const u16* __restrict__ B,
    const u16* __restrict__ Wt1, const u16* __restrict__ Wt2,
    const float* __restrict__ bias, u16* __restrict__ Cout,
    u8* __restrict__ Cq)
{
  __shared__ u16 wlds[128 * WSTRIDE];
  const int t = threadIdx.x;
  const int wid = t >> 6, lane = t & 63;
  const int l15 = lane & 15, g = lane >> 4;
  const int rbase = blockIdx.x * 64 + wid * 16;

  int r0 = rbase + l15;
  size_t a0 = (size_t)(r0 < NN ? r0 : NN - 1) * D + g * 8;

  f32x4 acc0[8] = {};

  #pragma unroll
  for (int phase = 0; phase < 2; ++phase) {
    const u16* Act = phase ? B : A;
    const u16* Wt  = phase ? Wt2 : Wt1;
    #pragma unroll
    for (int q = 0; q < 8; ++q) {
      int i = q * 256 + t;
      int n = i >> 4, kc = i & 15;
      *reinterpret_cast<u16x8*>(&wlds[n * WSTRIDE + kc * 8]) =
          *reinterpret_cast<const u16x8*>(&Wt[n * D + kc * 8]);
    }
    __syncthreads();
    #pragma unroll
    for (int kb = 0; kb < 4; ++kb) {
      bf16x8 af0 = *reinterpret_cast<const bf16x8*>(&Act[a0 + kb * 32]);
      #pragma unroll
      for (int c = 0; c < 8; ++c) {
        bf16x8 wf = *reinterpret_cast<const bf16x8*>(
            &wlds[(c * 16 + l15) * WSTRIDE + kb * 32 + g * 8]);
        acc0[c] = __builtin_amdgcn_mfma_f32_16x16x32_bf16(af0, wf, acc0[c], 0, 0, 0);
      }
    }
    __syncthreads();
  }

  // stage bias+relu'd 64x128 tile into LDS (reuse wlds)
  #pragma unroll
  for (int c = 0; c < 8; ++c) {
    float bv = bias[c * 16 + l15];
    #pragma unroll
    for (int r = 0; r < 4; ++r) {
      float v0 = fmaxf(acc0[c][r] + bv, 0.f);
      wlds[(wid * 16 + g * 4 + r) * WSTRIDE + c * 16 + l15] = f2b(v0);
    }
  }
  __syncthreads();
  // coalesced stores: 1024 x 16B chunks; thread t does chunks i*256+t
  const int rblk = blockIdx.x * 64;
  #pragma unroll
  for (int i = 0; i < 4; ++i) {
    int k = i * 256 + t;
    int row = k >> 4, kc = k & 15;
    int grow = rblk + row;
    if (grow < NN) {
      u16x8 vv = *reinterpret_cast<const u16x8*>(&wlds[row * WSTRIDE + kc * 8]);
      *reinterpret_cast<u16x8*>(&Cout[(size_t)grow * D + kc * 8]) = vv;
      int qa = __builtin_amdgcn_cvt_pk_fp8_f32(b2f((u16)vv[0]), b2f((u16)vv[1]), 0, false);
      qa = __builtin_amdgcn_cvt_pk_fp8_f32(b2f((u16)vv[2]), b2f((u16)vv[3]), qa, true);
      int qb = __builtin_amdgcn_cvt_pk_fp8_f32(b2f((u16)vv[4]), b2f((u16)vv[5]), 0, false);
      qb = __builtin_amdgcn_cvt_pk_fp8_f32(b2f((u16)vv[6]), b2f((u16)vv[7]), qb, true);
      u32x2 qo; qo[0] = (u32)qa; qo[1] = (u32)qb;
      *reinterpret_cast<u32x2*>(&Cq[(size_t)grow * D + kc * 8]) = qo;
    }
  }
}

// ---------------- layer-2 GEMM (64-row) + fused layer-3 projection ----------
__global__ __launch_bounds__(256) void k_gemm2_zr(
    const u16* __restrict__ A, const u16* __restrict__ B,
    const u16* __restrict__ Wt1, const u16* __restrict__ Wt2,
    const float* __restrict__ bias,
    const float* __restrict__ Wl3, const float* __restrict__ Wr3,
    const float* __restrict__ b3,
    float* __restrict__ z, float* __restrict__ r)
{
  __shared__ u16 wlds[128 * WSTRIDE];
  const int t = threadIdx.x;
  const int wid = t >> 6, lane = t & 63;
  const int l15 = lane & 15, g = lane >> 4;
  const int rbase = blockIdx.x * 64 + wid * 16;

  int r0 = rbase + l15;
  size_t a0 = (size_t)(r0 < NN ? r0 : NN - 1) * D + g * 8;

  f32x4 acc0[8] = {};

  #pragma unroll
  for (int phase = 0; phase < 2; ++phase) {
    const u16* Act = phase ? B : A;
    const u16* Wt  = phase ? Wt2 : Wt1;
    #pragma unroll
    for (int q = 0; q < 8; ++q) {
      int i = q * 256 + t;
      int n = i >> 4, kc = i & 15;
      *reinterpret_cast<u16x8*>(&wlds[n * WSTRIDE + kc * 8]) =
          *reinterpret_cast<const u16x8*>(&Wt[n * D + kc * 8]);
    }
    __syncthreads();
    #pragma unroll
    for (int kb = 0; kb < 4; ++kb) {
      bf16x8 af0 = *reinterpret_cast<const bf16x8*>(&Act[a0 + kb * 32]);
      #pragma unroll
      for (int c = 0; c < 8; ++c) {
        bf16x8 wf = *reinterpret_cast<const bf16x8*>(
            &wlds[(c * 16 + l15) * WSTRIDE + kb * 32 + g * 8]);
        acc0[c] = __builtin_amdgcn_mfma_f32_16x16x32_bf16(af0, wf, acc0[c], 0, 0, 0);
      }
    }
    __syncthreads();
  }

  float wl[8], wr[8], bv[8];
  #pragma unroll
  for (int c = 0; c < 8; ++c) {
    wl[c] = Wl3[c * 16 + l15];
    wr[c] = Wr3[c * 16 + l15];
    bv[c] = bias[c * 16 + l15];
  }
  float bb3 = b3[0];
  #pragma unroll
  for (int rr = 0; rr < 4; ++rr) {
    float pz = 0.f, pr = 0.f;
    #pragma unroll
    for (int c = 0; c < 8; ++c) {
      float v = fmaxf(acc0[c][rr] + bv[c], 0.f);
      pz += v * wl[c];
      pr += v * wr[c];
    }
    pz += __shfl_xor(pz, 1, 64); pr += __shfl_xor(pr, 1, 64);
    pz += __shfl_xor(pz, 2, 64); pr += __shfl_xor(pr, 2, 64);
    pz += __shfl_xor(pz, 4, 64); pr += __shfl_xor(pr, 4, 64);
    pz += __shfl_xor(pz, 8, 64); pr += __shfl_xor(pr, 8, 64);
    int row = rbase + g * 4 + rr;
    if (l15 == 0 && row < NN) {
      z[row] = pz;
      r[row] = pr + bb3;
    }
  }
}

// ---------------- final: out = r + mean(z over neighbors), 16 lanes/node ----
__global__ __launch_bounds__(256) void k_out(const float* __restrict__ z,
    const float* __restrict__ r, const int* __restrict__ rowstart,
    const int* __restrict__ col, float* __restrict__ out) {
  int t = threadIdx.x;
  int sub = t & 15;
  int node = blockIdx.x * 16 + (t >> 4);
  if (node >= NN) return;
  int b = rowstart[node], e = rowstart[node + 1];
  float s = 0.f;
  for (int j = b + sub; j < e; j += 16) s += z[col[j]];
  s += __shfl_xor(s, 1, 64);
  s += __shfl_xor(s, 2, 64);
  s += __shfl_xor(s, 4, 64);
  s += __shfl_xor(s, 8, 64);
  if (sub == 0) {
    float inv = (e > b) ? 1.f / (float)(e - b) : 0.f;
    out[node] = r[node] + s * inv;
  }
}

extern "C" void kernel_launch(void* const* d_in, const int* in_sizes, int n_in,
                              void* d_out, int out_size, void* d_ws, size_t ws_size,
                              hipStream_t stream) {
  const float* x   = (const float*)d_in[0];
  const int*   ei  = (const int*)d_in[1];
  const float* Wl1 = (const float*)d_in[2];
  const float* Wr1 = (const float*)d_in[3];
  const float* b1  = (const float*)d_in[4];
  const float* Wl2 = (const float*)d_in[5];
  const float* Wr2 = (const float*)d_in[6];
  const float* b2  = (const float*)d_in[7];
  const float* Wl3 = (const float*)d_in[8];
  const float* Wr3 = (const float*)d_in[9];
  const float* b3  = (const float*)d_in[10];
  const int* srcv = ei;
  const int* dstv = ei + NE;
  float* out = (float*)d_out;

  char* ws = (char*)d_ws;
  size_t off = 0;
  auto alloc = [&](size_t bytes) {
    size_t o = off;
    off += (bytes + 255) & ~(size_t)255;
    return o;
  };
  int* deg      = (int*)(ws + alloc((size_t)NN * 4));
  int* rowstart = (int*)(ws + alloc((size_t)(NN + 1) * 4));
  int* col      = (int*)(ws + alloc((size_t)NE * 4));
  int* hw       = (int*)(ws + alloc((size_t)NGRP * NWAVES * 4));
  int* btot     = (int*)(ws + alloc(64 * 4));
  int* bbase    = (int*)(ws + alloc(64 * 4));
  u32* bkt  = (u32*)(ws + alloc((size_t)NE * 4));
  u16* ncnt = (u16*)(ws + alloc((size_t)NGRP * NSUB * GSZ * 2));
  u16* xb   = (u16*)(ws + alloc((size_t)NN * D * 2));
  u8*  xq   = (u8*)(ws + alloc((size_t)NN * D));
  u16* Ab   = (u16*)(ws + alloc((size_t)NN * D * 2));
  u16* H1b  = (u16*)(ws + alloc((size_t)NN * D * 2));
  u8*  H1q  = (u8*)(ws + alloc((size_t)NN * D));
  u16* Wt1l = (u16*)(ws + alloc((size_t)D * D * 2));
  u16* Wt1r = (u16*)(ws + alloc((size_t)D * D * 2));
  u16* Wt2l = (u16*)(ws + alloc((size_t)D * D * 2));
  u16* Wt2r = (u16*)(ws + alloc((size_t)D * D * 2));
  float* z  = (float*)(ws + alloc((size_t)NN * 4));
  float* r  = (float*)(ws + alloc((size_t)NN * 4));

  const int nb_gemm  = (NN + 63) / 64;         // 1563
  const int nb_agg   = (NN + 31) / 32;         // 3125
  const int nb_out   = (NN + 15) / 16;         // 6250
  const int nb_sub   = NGRP * NSUB;            // 256
  const int nb_nscan = NGRP * ((GSZ + 255) / 256);  // 8*49

  // atomic-free CSR build (+ x->bf16 + x->fp8 fused into hist pass)
  k_hist8<<<NBLK, 256, 0, stream>>>(dstv, hw, x, xb, xq);
  k_hscan_a<<<NGRP, 256, 0, stream>>>(hw, btot);
  k_hscan_b<<<1, 64, 0, stream>>>(btot, bbase);
  k_part2<<<NBLK, 256, 0, stream>>>(srcv, dstv, hw, bbase, bkt);
  k_nhist<<<nb_sub, 256, 0, stream>>>(bkt, bbase, ncnt);
  k_nscan<<<nb_nscan, 256, 0, stream>>>(ncnt, deg);
  k_gscan<<<NGRP, 256, 0, stream>>>(deg, bbase, rowstart);
  k_scatter2<<<nb_sub, 256, 0, stream>>>(bkt, bbase, ncnt, rowstart, col);

  // weight prep (transposed bf16)
  k_cvt_wt4<<<dim3(D, 4), D, 0, stream>>>(Wl1, Wr1, Wl2, Wr2, Wt1l, Wt1r, Wt2l, Wt2r);

  // layer 1: gather fp8 x, GEMM in bf16; emit H1 in bf16 + fp8
  k_agg_q<<<nb_agg, 256, 0, stream>>>(xq, rowstart, col, Ab);
  k_gemm_mfma<<<nb_gemm, 256, 0, stream>>>(Ab, xb, Wt1l, Wt1r, b1, H1b, H1q);
  // layer 2 + fused layer-3 projection: gather fp8 H1
  k_agg_q<<<nb_agg, 256, 0, stream>>>(H1q, rowstart, col, Ab);
  k_gemm2_zr<<<nb_gemm, 256, 0, stream>>>(Ab, H1b, Wt2l, Wt2r, b2, Wl3, Wr3, b3, z, r);
  // final
  k_out<<<nb_out, 256, 0, stream>>>(z, r, rowstart, col, out);
}

// Round 18
// 218.073 us; speedup vs baseline: 1.8847x; 1.0309x over previous
//
#include <hip/hip_runtime.h>
#include <hip/hip_bf16.h>

#define NN 100000
#define NE 1600000
#define D 128
#define NGRP 8
#define GSZ (NN / NGRP)          // 12500, exact
#define EPT 8                    // edges per thread in hist8/part2
#define NBLK ((NE + 2047) / 2048)   // 782 blocks for hist8/part2
#define NWAVES (NBLK * 4)        // 3128 waves
#define NSUB 32                  // sub-blocks per group in nhist/scatter2
#define WSTRIDE 136              // LDS row stride (u16): 272B -> conflict-free b128

typedef unsigned short u16;
typedef unsigned int u32;
typedef unsigned long long u64;
typedef unsigned char u8;
typedef __attribute__((ext_vector_type(8))) short bf16x8;
typedef __attribute__((ext_vector_type(4))) float f32x4;
typedef __attribute__((ext_vector_type(2))) float f32x2;
typedef __attribute__((ext_vector_type(8))) u16 u16x8;
typedef __attribute__((ext_vector_type(4))) u32 u32x4;
typedef __attribute__((ext_vector_type(2))) u32 u32x2;

__device__ inline u16 f2b(float f) {
  union { float f; u32 u; } v; v.f = f;
  u32 u = v.u;
  return (u16)((u + 0x7fffu + ((u >> 16) & 1u)) >> 16);
}
__device__ inline float b2f(u16 h) {
  union { u32 u; float f; } v; v.u = ((u32)h) << 16; return v.f;
}
// accumulate 16 fp8 (one u32x4) into 16 f32 accumulators via HW packed cvt
__device__ inline void acc16(float* a, u32x4 v) {
  #pragma unroll
  for (int w = 0; w < 4; ++w) {
    f32x2 lo = __builtin_amdgcn_cvt_pk_f32_fp8(v[w], false);
    f32x2 hi = __builtin_amdgcn_cvt_pk_f32_fp8(v[w], true);
    a[w * 4 + 0] += lo[0]; a[w * 4 + 1] += lo[1];
    a[w * 4 + 2] += hi[0]; a[w * 4 + 3] += hi[1];
  }
}

// ---------------- hist + x->bf16 + x->fp8 convert (1.6M-element streams) ----
__global__ __launch_bounds__(256) void k_hist8(const int* __restrict__ dst,
    int* __restrict__ hw, const float* __restrict__ xin, u16* __restrict__ xb,
    u8* __restrict__ xq) {
  const int t = threadIdx.x, lane = t & 63, wid = t >> 6;
  const int eb = blockIdx.x * (256 * EPT);
  const int wv = blockIdx.x * 4 + wid;
  int c0=0,c1=0,c2=0,c3=0,c4=0,c5=0,c6=0,c7=0;
  #pragma unroll
  for (int r = 0; r < EPT; ++r) {
    int e = eb + r * 256 + t;
    bool v = e < NE;
    int q = v ? __builtin_nontemporal_load(&dst[e]) / GSZ : 8;
    c0 += __popcll(__ballot(q == 0)); c1 += __popcll(__ballot(q == 1));
    c2 += __popcll(__ballot(q == 2)); c3 += __popcll(__ballot(q == 3));
    c4 += __popcll(__ballot(q == 4)); c5 += __popcll(__ballot(q == 5));
    c6 += __popcll(__ballot(q == 6)); c7 += __popcll(__ballot(q == 7));
    if (v) {
      const f32x4* p = reinterpret_cast<const f32x4*>(xin) + (size_t)e * 2;
      f32x4 a = __builtin_nontemporal_load(p);
      f32x4 b = __builtin_nontemporal_load(p + 1);
      u16x8 o;
      o[0] = f2b(a[0]); o[1] = f2b(a[1]); o[2] = f2b(a[2]); o[3] = f2b(a[3]);
      o[4] = f2b(b[0]); o[5] = f2b(b[1]); o[6] = f2b(b[2]); o[7] = f2b(b[3]);
      __builtin_nontemporal_store(o, reinterpret_cast<u16x8*>(xb + (size_t)e * 8));
      int qlo = __builtin_amdgcn_cvt_pk_fp8_f32(a[0], a[1], 0, false);
      qlo = __builtin_amdgcn_cvt_pk_fp8_f32(a[2], a[3], qlo, true);
      int qhi = __builtin_amdgcn_cvt_pk_fp8_f32(b[0], b[1], 0, false);
      qhi = __builtin_amdgcn_cvt_pk_fp8_f32(b[2], b[3], qhi, true);
      u32x2 qo; qo[0] = (u32)qlo; qo[1] = (u32)qhi;
      __builtin_nontemporal_store(qo, reinterpret_cast<u32x2*>(xq + (size_t)e * 8));
    }
  }
  if (lane == 0) {
    hw[0 * NWAVES + wv] = c0; hw[1 * NWAVES + wv] = c1;
    hw[2 * NWAVES + wv] = c2; hw[3 * NWAVES + wv] = c3;
    hw[4 * NWAVES + wv] = c4; hw[5 * NWAVES + wv] = c5;
    hw[6 * NWAVES + wv] = c6; hw[7 * NWAVES + wv] = c7;
  }
}

// ---------------- per-bucket scan: 8 parallel blocks ------------------------
__global__ __launch_bounds__(256) void k_hscan_a(int* __restrict__ hw,
                                                 int* __restrict__ btot) {
  __shared__ int s[256];
  int* a = hw + blockIdx.x * NWAVES;
  const int t = threadIdx.x;
  const int per = (NWAVES + 255) / 256;    // 13
  int lo = t * per, hi = lo + per; if (hi > NWAVES) hi = NWAVES;
  int sum = 0;
  for (int i = lo; i < hi; ++i) sum += a[i];
  s[t] = sum; __syncthreads();
  for (int off = 1; off < 256; off <<= 1) {
    int u = (t >= off) ? s[t - off] : 0;
    __syncthreads(); s[t] += u; __syncthreads();
  }
  int run = s[t] - sum;
  for (int i = lo; i < hi; ++i) { int v = a[i]; a[i] = run; run += v; }
  if (t == 255) btot[blockIdx.x] = s[255];
}

__global__ void k_hscan_b(const int* __restrict__ btot, int* __restrict__ bbase) {
  if (threadIdx.x == 0) {
    int run = 0;
    #pragma unroll
    for (int g = 0; g < NGRP; ++g) { bbase[g] = run; run += btot[g]; }
    bbase[NGRP] = run;     // == NE
  }
}

// ---------------- deterministic bucket write (ballot ranks, no atomics) -----
__global__ __launch_bounds__(256) void k_part2(const int* __restrict__ src,
    const int* __restrict__ dst, const int* __restrict__ hw,
    const int* __restrict__ bbase, u32* __restrict__ bkt) {
  const int t = threadIdx.x, lane = t & 63, wid = t >> 6;
  const int eb = blockIdx.x * (256 * EPT);
  const int wv = blockIdx.x * 4 + wid;
  int q[EPT]; u32 pk[EPT];
  #pragma unroll
  for (int r = 0; r < EPT; ++r) {
    int e = eb + r * 256 + t;
    bool v = e < NE;
    int d = v ? __builtin_nontemporal_load(&dst[e]) : 0;
    int s = v ? __builtin_nontemporal_load(&src[e]) : 0;
    q[r] = v ? d / GSZ : 8;
    pk[r] = v ? (((u32)(d - q[r] * GSZ) << 17) | (u32)s) : 0;
  }
  u64 below = (lane == 63) ? 0x7fffffffffffffffull : ((1ull << lane) - 1);
  int base[NGRP];
  #pragma unroll
  for (int b = 0; b < NGRP; ++b) base[b] = bbase[b] + hw[b * NWAVES + wv];
  #pragma unroll
  for (int b = 0; b < NGRP; ++b) {
    int run = 0;
    #pragma unroll
    for (int r = 0; r < EPT; ++r) {
      u64 m = __ballot(q[r] == b);
      if (q[r] == b) {
        int pos = base[b] + run + __popcll(m & below);
        if (pos < NE)
          bkt[pos] = pk[r];
      }
      run += __popcll(m);
    }
  }
}

// ---------------- per-sub-block node histogram in LDS -----------------------
__global__ __launch_bounds__(256) void k_nhist(const u32* __restrict__ bkt,
    const int* __restrict__ bbase, u16* __restrict__ ncnt) {
  __shared__ int h[GSZ];
  const int g = blockIdx.x & (NGRP - 1);
  const int sub = blockIdx.x >> 3;
  const int t = threadIdx.x;
  const int start = bbase[g];
  const int end = bbase[g + 1];
  const int cnt = end - start;
  const int chunk = (cnt + NSUB - 1) / NSUB;
  int lo = start + sub * chunk;
  int hi = lo + chunk; if (hi > end) hi = end;
  for (int i = t; i < GSZ; i += 256) h[i] = 0;
  __syncthreads();
  for (int i = lo + t; i < hi; i += 256) {
    int dl = (int)(__builtin_nontemporal_load(&bkt[i]) >> 17);
    atomicAdd(&h[dl], 1);
  }
  __syncthreads();
  u16* outp = ncnt + ((size_t)g * NSUB + sub) * GSZ;
  for (int i = t; i < GSZ; i += 256) outp[i] = (u16)h[i];
}

// ---------------- per-node scan over sub-blocks -> offsets + deg ------------
__global__ __launch_bounds__(256) void k_nscan(u16* __restrict__ ncnt,
    int* __restrict__ deg) {
  const int g = blockIdx.x & (NGRP - 1);
  const int seg = blockIdx.x >> 3;
  int d = seg * 256 + threadIdx.x;
  if (d >= GSZ) return;
  int run = 0;
  #pragma unroll
  for (int s = 0; s < NSUB; ++s) {
    size_t idx = ((size_t)g * NSUB + s) * GSZ + d;
    int v = ncnt[idx];
    ncnt[idx] = (u16)run;
    run += v;
  }
  deg[g * GSZ + d] = run;
}

// ---------------- per-group rowstart: bucket base + local scan --------------
__global__ void k_gscan(const int* __restrict__ deg, const int* __restrict__ bbase,
                        int* __restrict__ rowstart) {
  __shared__ int s[256];
  const int g = blockIdx.x;
  const int t = threadIdx.x;
  const int base = bbase[g];
  const int per = (GSZ + 255) / 256;       // 49
  int lo = t * per, hi = lo + per; if (hi > GSZ) hi = GSZ;
  int sum = 0;
  for (int i = lo; i < hi; ++i) sum += deg[g * GSZ + i];
  s[t] = sum; __syncthreads();
  for (int off = 1; off < 256; off <<= 1) {
    int u = (t >= off) ? s[t - off] : 0;
    __syncthreads(); s[t] += u; __syncthreads();
  }
  int run = base + s[t] - sum;
  for (int i = lo; i < hi; ++i) {
    int v = deg[g * GSZ + i];
    rowstart[g * GSZ + i] = run;
    run += v;
  }
  if (g == NGRP - 1 && t == 255) rowstart[NN] = NE;
}

// ---------------- scatter: LDS cursors, XCD-resident col slice --------------
__global__ __launch_bounds__(256) void k_scatter2(const u32* __restrict__ bkt,
    const int* __restrict__ bbase, const u16* __restrict__ ncnt,
    const int* __restrict__ rowstart, int* __restrict__ col) {
  __shared__ int cur[GSZ];
  const int g = blockIdx.x & (NGRP - 1);
  const int sub = blockIdx.x >> 3;
  const int t = threadIdx.x;
  const int start = bbase[g];
  const int end = bbase[g + 1];
  const int cnt = end - start;
  const int chunk = (cnt + NSUB - 1) / NSUB;
  int lo = start + sub * chunk;
  int hi = lo + chunk; if (hi > end) hi = end;
  const u16* nof = ncnt + ((size_t)g * NSUB + sub) * GSZ;
  for (int i = t; i < GSZ; i += 256)
    cur[i] = rowstart[g * GSZ + i] + (int)nof[i];
  __syncthreads();
  for (int i = lo + t; i < hi; i += 256) {
    u32 v = __builtin_nontemporal_load(&bkt[i]);
    int dl = (int)(v >> 17), s = (int)(v & 0x1ffffu);
    int pos = atomicAdd(&cur[dl], 1);
    col[pos] = s;
  }
}

// ---------------- W (k-major [k][n]) -> Wt (n-major [n][k]) bf16, 4 mats ----
__global__ void k_cvt_wt4(const float* __restrict__ W0, const float* __restrict__ W1,
                          const float* __restrict__ W2, const float* __restrict__ W3,
                          u16* __restrict__ T0, u16* __restrict__ T1,
                          u16* __restrict__ T2, u16* __restrict__ T3) {
  const float* W = blockIdx.y == 0 ? W0 : blockIdx.y == 1 ? W1 : blockIdx.y == 2 ? W2 : W3;
  u16* T = blockIdx.y == 0 ? T0 : blockIdx.y == 1 ? T1 : blockIdx.y == 2 ? T2 : T3;
  int n = blockIdx.x, k = threadIdx.x;
  T[n * D + k] = f2b(W[k * D + n]);
}

// ---------------- fp8 mean aggregation: 8-lane group per node, 4-deep -------
// (R17 lesson: 8-deep staging cost 80 VGPR -> occupancy 25%, regressed.
//  4-deep stays <=64 VGPR -> 8 waves/SIMD.)
__global__ __launch_bounds__(256) void k_agg_q(const u8* __restrict__ feat,
    const int* __restrict__ rowstart, const int* __restrict__ col,
    u16* __restrict__ out) {
  int t = threadIdx.x;
  int node = blockIdx.x * 32 + (t >> 3);   // 32 nodes per block
  if (node >= NN) return;
  int ln = t & 7;                          // lane in group: 16B feature chunk
  int b = rowstart[node], e = rowstart[node + 1];
  const u8* fp = feat + ln * 16;
  float a[16] = {};
  int j = b;
  for (; j + 3 < e; j += 4) {              // 4 rows in flight per group (32/wave)
    int s0 = col[j], s1 = col[j + 1], s2 = col[j + 2], s3 = col[j + 3];
    u32x4 v0 = *reinterpret_cast<const u32x4*>(fp + (size_t)s0 * D);
    u32x4 v1 = *reinterpret_cast<const u32x4*>(fp + (size_t)s1 * D);
    u32x4 v2 = *reinterpret_cast<const u32x4*>(fp + (size_t)s2 * D);
    u32x4 v3 = *reinterpret_cast<const u32x4*>(fp + (size_t)s3 * D);
    acc16(a, v0); acc16(a, v1); acc16(a, v2); acc16(a, v3);
  }
  for (; j < e; ++j) {
    int s0 = col[j];
    u32x4 v0 = *reinterpret_cast<const u32x4*>(fp + (size_t)s0 * D);
    acc16(a, v0);
  }
  float inv = (e > b) ? 1.f / (float)(e - b) : 0.f;
  u16x8 o0, o1;
  #pragma unroll
  for (int k = 0; k < 8; ++k) {
    o0[k] = f2b(a[k] * inv);
    o1[k] = f2b(a[8 + k] * inv);
  }
  u16* op = out + (size_t)node * D + ln * 16;
  *reinterpret_cast<u16x8*>(op) = o0;
  *reinterpret_cast<u16x8*>(op + 8) = o1;
}

// ---------------- fused dual GEMM via MFMA; 64-row tiles --------------------
__global__ __launch_bounds__(256) void k_gemm_mfma(
    const u16* __restrict__ A, const u16* __restrict__ B,
    const u16* __restrict__ Wt1, const u16* __restrict__ Wt2,
    const float* __restrict__ bias, u16* __restrict__ Cout,
    u8* __restrict__ Cq)
{
  __shared__ u16 wlds[128 * WSTRIDE];
  const int t = threadIdx.x;
  const int wid = t >> 6, lane = t & 63;
  const int l15 = lane & 15, g = lane >> 4;
  const int rbase = blockIdx.x * 64 + wid * 16;

  int r0 = rbase + l15;
  size_t a0 = (size_t)(r0 < NN ? r0 : NN - 1) * D + g * 8;

  f32x4 acc0[8] = {};

  #pragma unroll
  for (int phase = 0; phase < 2; ++phase) {
    const u16* Act = phase ? B : A;
    const u16* Wt  = phase ? Wt2 : Wt1;
    #pragma unroll
    for (int q = 0; q < 8; ++q) {
      int i = q * 256 + t;
      int n = i >> 4, kc = i & 15;
      *reinterpret_cast<u16x8*>(&wlds[n * WSTRIDE + kc * 8]) =
          *reinterpret_cast<const u16x8*>(&Wt[n * D + kc * 8]);
    }
    __syncthreads();
    #pragma unroll
    for (int kb = 0; kb < 4; ++kb) {
      bf16x8 af0 = *reinterpret_cast<const bf16x8*>(&Act[a0 + kb * 32]);
      #pragma unroll
      for (int c = 0; c < 8; ++c) {
        bf16x8 wf = *reinterpret_cast<const bf16x8*>(
            &wlds[(c * 16 + l15) * WSTRIDE + kb * 32 + g * 8]);
        acc0[c] = __builtin_amdgcn_mfma_f32_16x16x32_bf16(af0, wf, acc0[c], 0, 0, 0);
      }
    }
    __syncthreads();
  }

  // stage bias+relu'd 64x128 tile into LDS (reuse wlds)
  #pragma unroll
  for (int c = 0; c < 8; ++c) {
    float bv = bias[c * 16 + l15];
    #pragma unroll
    for (int r = 0; r < 4; ++r) {
      float v0 = fmaxf(acc0[c][r] + bv, 0.f);
      wlds[(wid * 16 + g * 4 + r) * WSTRIDE + c * 16 + l15] = f2b(v0);
    }
  }
  __syncthreads();
  // coalesced stores: 1024 x 16B chunks; thread t does chunks i*256+t
  const int rblk = blockIdx.x * 64;
  #pragma unroll
  for (int i = 0; i < 4; ++i) {
    int k = i * 256 + t;
    int row = k >> 4, kc = k & 15;
    int grow = rblk + row;
    if (grow < NN) {
      u16x8 vv = *reinterpret_cast<const u16x8*>(&wlds[row * WSTRIDE + kc * 8]);
      *reinterpret_cast<u16x8*>(&Cout[(size_t)grow * D + kc * 8]) = vv;
      int qa = __builtin_amdgcn_cvt_pk_fp8_f32(b2f((u16)vv[0]), b2f((u16)vv[1]), 0, false);
      qa = __builtin_amdgcn_cvt_pk_fp8_f32(b2f((u16)vv[2]), b2f((u16)vv[3]), qa, true);
      int qb = __builtin_amdgcn_cvt_pk_fp8_f32(b2f((u16)vv[4]), b2f((u16)vv[5]), 0, false);
      qb = __builtin_amdgcn_cvt_pk_fp8_f32(b2f((u16)vv[6]), b2f((u16)vv[7]), qb, true);
      u32x2 qo; qo[0] = (u32)qa; qo[1] = (u32)qb;
      *reinterpret_cast<u32x2*>(&Cq[(size_t)grow * D + kc * 8]) = qo;
    }
  }
}

// ---------------- layer-2 GEMM (64-row) + fused layer-3 projection ----------
__global__ __launch_bounds__(256) void k_gemm2_zr(
    const u16* __restrict__ A, const u16* __restrict__ B,
    const u16* __restrict__ Wt1, const u16* __restrict__ Wt2,
    const float* __restrict__ bias,
    const float* __restrict__ Wl3, const float* __restrict__ Wr3,
    const float* __restrict__ b3,
    float* __restrict__ z, float* __restrict__ r)
{
  __shared__ u16 wlds[128 * WSTRIDE];
  const int t = threadIdx.x;
  const int wid = t >> 6, lane = t & 63;
  const int l15 = lane & 15, g = lane >> 4;
  const int rbase = blockIdx.x * 64 + wid * 16;

  int r0 = rbase + l15;
  size_t a0 = (size_t)(r0 < NN ? r0 : NN - 1) * D + g * 8;

  f32x4 acc0[8] = {};

  #pragma unroll
  for (int phase = 0; phase < 2; ++phase) {
    const u16* Act = phase ? B : A;
    const u16* Wt  = phase ? Wt2 : Wt1;
    #pragma unroll
    for (int q = 0; q < 8; ++q) {
      int i = q * 256 + t;
      int n = i >> 4, kc = i & 15;
      *reinterpret_cast<u16x8*>(&wlds[n * WSTRIDE + kc * 8]) =
          *reinterpret_cast<const u16x8*>(&Wt[n * D + kc * 8]);
    }
    __syncthreads();
    #pragma unroll
    for (int kb = 0; kb < 4; ++kb) {
      bf16x8 af0 = *reinterpret_cast<const bf16x8*>(&Act[a0 + kb * 32]);
      #pragma unroll
      for (int c = 0; c < 8; ++c) {
        bf16x8 wf = *reinterpret_cast<const bf16x8*>(
            &wlds[(c * 16 + l15) * WSTRIDE + kb * 32 + g * 8]);
        acc0[c] = __builtin_amdgcn_mfma_f32_16x16x32_bf16(af0, wf, acc0[c], 0, 0, 0);
      }
    }
    __syncthreads();
  }

  float wl[8], wr[8], bv[8];
  #pragma unroll
  for (int c = 0; c < 8; ++c) {
    wl[c] = Wl3[c * 16 + l15];
    wr[c] = Wr3[c * 16 + l15];
    bv[c] = bias[c * 16 + l15];
  }
  float bb3 = b3[0];
  #pragma unroll
  for (int rr = 0; rr < 4; ++rr) {
    float pz = 0.f, pr = 0.f;
    #pragma unroll
    for (int c = 0; c < 8; ++c) {
      float v = fmaxf(acc0[c][rr] + bv[c], 0.f);
      pz += v * wl[c];
      pr += v * wr[c];
    }
    pz += __shfl_xor(pz, 1, 64); pr += __shfl_xor(pr, 1, 64);
    pz += __shfl_xor(pz, 2, 64); pr += __shfl_xor(pr, 2, 64);
    pz += __shfl_xor(pz, 4, 64); pr += __shfl_xor(pr, 4, 64);
    pz += __shfl_xor(pz, 8, 64); pr += __shfl_xor(pr, 8, 64);
    int row = rbase + g * 4 + rr;
    if (l15 == 0 && row < NN) {
      z[row] = pz;
      r[row] = pr + bb3;
    }
  }
}

// ---------------- final: out = r + mean(z over neighbors), 16 lanes/node ----
__global__ __launch_bounds__(256) void k_out(const float* __restrict__ z,
    const float* __restrict__ r, const int* __restrict__ rowstart,
    const int* __restrict__ col, float* __restrict__ out) {
  int t = threadIdx.x;
  int sub = t & 15;
  int node = blockIdx.x * 16 + (t >> 4);
  if (node >= NN) return;
  int b = rowstart[node], e = rowstart[node + 1];
  float s = 0.f;
  for (int j = b + sub; j < e; j += 16) s += z[col[j]];
  s += __shfl_xor(s, 1, 64);
  s += __shfl_xor(s, 2, 64);
  s += __shfl_xor(s, 4, 64);
  s += __shfl_xor(s, 8, 64);
  if (sub == 0) {
    float inv = (e > b) ? 1.f / (float)(e - b) : 0.f;
    out[node] = r[node] + s * inv;
  }
}

extern "C" void kernel_launch(void* const* d_in, const int* in_sizes, int n_in,
                              void* d_out, int out_size, void* d_ws, size_t ws_size,
                              hipStream_t stream) {
  const float* x   = (const float*)d_in[0];
  const int*   ei  = (const int*)d_in[1];
  const float* Wl1 = (const float*)d_in[2];
  const float* Wr1 = (const float*)d_in[3];
  const float* b1  = (const float*)d_in[4];
  const float* Wl2 = (const float*)d_in[5];
  const float* Wr2 = (const float*)d_in[6];
  const float* b2  = (const float*)d_in[7];
  const float* Wl3 = (const float*)d_in[8];
  const float* Wr3 = (const float*)d_in[9];
  const float* b3  = (const float*)d_in[10];
  const int* srcv = ei;
  const int* dstv = ei + NE;
  float* out = (float*)d_out;

  char* ws = (char*)d_ws;
  size_t off = 0;
  auto alloc = [&](size_t bytes) {
    size_t o = off;
    off += (bytes + 255) & ~(size_t)255;
    return o;
  };
  int* deg      = (int*)(ws + alloc((size_t)NN * 4));
  int* rowstart = (int*)(ws + alloc((size_t)(NN + 1) * 4));
  int* col      = (int*)(ws + alloc((size_t)NE * 4));
  int* hw       = (int*)(ws + alloc((size_t)NGRP * NWAVES * 4));
  int* btot     = (int*)(ws + alloc(64 * 4));
  int* bbase    = (int*)(ws + alloc(64 * 4));
  u32* bkt  = (u32*)(ws + alloc((size_t)NE * 4));
  u16* ncnt = (u16*)(ws + alloc((size_t)NGRP * NSUB * GSZ * 2));
  u16* xb   = (u16*)(ws + alloc((size_t)NN * D * 2));
  u8*  xq   = (u8*)(ws + alloc((size_t)NN * D));
  u16* Ab   = (u16*)(ws + alloc((size_t)NN * D * 2));
  u16* H1b  = (u16*)(ws + alloc((size_t)NN * D * 2));
  u8*  H1q  = (u8*)(ws + alloc((size_t)NN * D));
  u16* Wt1l = (u16*)(ws + alloc((size_t)D * D * 2));
  u16* Wt1r = (u16*)(ws + alloc((size_t)D * D * 2));
  u16* Wt2l = (u16*)(ws + alloc((size_t)D * D * 2));
  u16* Wt2r = (u16*)(ws + alloc((size_t)D * D * 2));
  float* z  = (float*)(ws + alloc((size_t)NN * 4));
  float* r  = (float*)(ws + alloc((size_t)NN * 4));

  const int nb_gemm  = (NN + 63) / 64;         // 1563
  const int nb_agg   = (NN + 31) / 32;         // 3125
  const int nb_out   = (NN + 15) / 16;         // 6250
  const int nb_sub   = NGRP * NSUB;            // 256
  const int nb_nscan = NGRP * ((GSZ + 255) / 256);  // 8*49

  // atomic-free CSR build (+ x->bf16 + x->fp8 fused into hist pass)
  k_hist8<<<NBLK, 256, 0, stream>>>(dstv, hw, x, xb, xq);
  k_hscan_a<<<NGRP, 256, 0, stream>>>(hw, btot);
  k_hscan_b<<<1, 64, 0, stream>>>(btot, bbase);
  k_part2<<<NBLK, 256, 0, stream>>>(srcv, dstv, hw, bbase, bkt);
  k_nhist<<<nb_sub, 256, 0, stream>>>(bkt, bbase, ncnt);
  k_nscan<<<nb_nscan, 256, 0, stream>>>(ncnt, deg);
  k_gscan<<<NGRP, 256, 0, stream>>>(deg, bbase, rowstart);
  k_scatter2<<<nb_sub, 256, 0, stream>>>(bkt, bbase, ncnt, rowstart, col);

  // weight prep (transposed bf16)
  k_cvt_wt4<<<dim3(D, 4), D, 0, stream>>>(Wl1, Wr1, Wl2, Wr2, Wt1l, Wt1r, Wt2l, Wt2r);

  // layer 1: gather fp8 x, GEMM in bf16; emit H1 in bf16 + fp8
  k_agg_q<<<nb_agg, 256, 0, stream>>>(xq, rowstart, col, Ab);
  k_gemm_mfma<<<nb_gemm, 256, 0, stream>>>(Ab, xb, Wt1l, Wt1r, b1, H1b, H1q);
  // layer 2 + fused layer-3 projection: gather fp8 H1
  k_agg_q<<<nb_agg, 256, 0, stream>>>(H1q, rowstart, col, Ab);
  k_gemm2_zr<<<nb_gemm, 256, 0, stream>>>(Ab, H1b, Wt2l, Wt2r, b2, Wl3, Wr3, b3, z, r);
  // final
  k_out<<<nb_out, 256, 0, stream>>>(z, r, rowstart, col, out);
}